// Round 1
// baseline (1703.224 us; speedup 1.0000x reference)
//
#include <hip/hip_runtime.h>

// QKV upsampling pipeline, fp32.
// Structure: 5x (conv3d k=2 'same' + partial stats) -> finalize mean/rstd ->
// fused qk = box3(shuffle(qn)*shuffle(kn)) -> fused out = box3(sum_j vn*qk).
// Norm+ReLU applied by consumers on load (zero-pad AFTER norm, as reference).

constexpr int VOX = 32 * 32 * 32;           // 32768 voxels per channel (coarse)
constexpr float INV_VOX = 1.0f / 32768.0f;
constexpr float EPSF = 1e-5f;

// ---------------------------------------------------------------------------
// conv3d k=2 (pad lo=0, hi=1) over (CIN,32,32,32) -> (COUT,32,32,32) raw+bias,
// plus deterministic per-tile (sum,sumsq) partials for instance norm.
// grid = (COUT/OCT, 32 spatial tiles), block = 256.
// Spatial tile: 2(d) x 16(h) x 32(w). Thread owns 2(d) x 1(h) x 2(w) voxels.
// ---------------------------------------------------------------------------
template <int CIN, int OCT, bool NORM_IN>
__global__ __launch_bounds__(256) void conv_in_kernel(
    const float* __restrict__ x, const float* __restrict__ npar,
    const float* __restrict__ w, const float* __restrict__ bias,
    float* __restrict__ y, float* __restrict__ part, int COUT)
{
  __shared__ float xs[3 * 17 * 33];       // x tile + halo for one ci
  __shared__ float wlds[OCT * CIN * 8];   // weights for this oc tile
  __shared__ float redsm[4][OCT][2];      // cross-wave stat reduce

  const int t = threadIdx.x;
  const int oc0 = blockIdx.x * OCT;
  const int ty = blockIdx.y;
  const int d0 = (ty & 15) * 2;
  const int h0 = (ty >> 4) * 16;
  const int hh = t >> 4;            // 0..15
  const int ww0 = (t & 15) * 2;     // 0,2,..,30

  for (int f = t; f < OCT * CIN * 8; f += 256)
    wlds[f] = w[(size_t)oc0 * CIN * 8 + f];

  float acc[OCT][4];
#pragma unroll
  for (int o = 0; o < OCT; ++o)
#pragma unroll
    for (int k = 0; k < 4; ++k) acc[o][k] = 0.f;

  for (int ci = 0; ci < CIN; ++ci) {
    __syncthreads();
    float m = 0.f, rs = 1.f;
    if constexpr (NORM_IN) { m = npar[2 * ci]; rs = npar[2 * ci + 1]; }
    for (int f = t; f < 3 * 17 * 33; f += 256) {
      int wz = f % 33; int r = f / 33; int hz = r % 17; int dz = r / 17;
      int d = d0 + dz, h = h0 + hz;
      float v = 0.f;
      if (d < 32 && h < 32 && wz < 32) {
        v = x[(size_t)ci * VOX + d * 1024 + h * 32 + wz];
        if constexpr (NORM_IN) v = fmaxf((v - m) * rs, 0.f);
      }
      xs[f] = v;
    }
    __syncthreads();

    // thread-local x registers: d 0..2, h hh..hh+1, w ww0..ww0+2
    float xr[3][2][3];
#pragma unroll
    for (int a = 0; a < 3; ++a)
#pragma unroll
      for (int b = 0; b < 2; ++b)
#pragma unroll
        for (int c = 0; c < 3; ++c)
          xr[a][b][c] = xs[(a * 17 + hh + b) * 33 + ww0 + c];

#pragma unroll
    for (int o = 0; o < OCT; ++o) {
      const float* wp = &wlds[(o * CIN + ci) * 8];
      float wv[8];
#pragma unroll
      for (int q = 0; q < 8; ++q) wv[q] = wp[q];
#pragma unroll
      for (int dd = 0; dd < 2; ++dd)
#pragma unroll
        for (int wx = 0; wx < 2; ++wx) {
          float a = acc[o][dd * 2 + wx];
#pragma unroll
          for (int kd = 0; kd < 2; ++kd)
#pragma unroll
            for (int kh = 0; kh < 2; ++kh)
#pragma unroll
              for (int kw = 0; kw < 2; ++kw)
                a = fmaf(wv[kd * 4 + kh * 2 + kw], xr[dd + kd][kh][wx + kw], a);
          acc[o][dd * 2 + wx] = a;
        }
    }
  }

  // epilogue: bias add, store, deterministic stat partials
  const int lane = t & 63, wave = t >> 6;
#pragma unroll
  for (int o = 0; o < OCT; ++o) {
    float bo = bias[oc0 + o];
    float v0 = acc[o][0] + bo, v1 = acc[o][1] + bo;
    float v2 = acc[o][2] + bo, v3 = acc[o][3] + bo;
    size_t base = (size_t)(oc0 + o) * VOX + d0 * 1024 + (h0 + hh) * 32 + ww0;
    *reinterpret_cast<float2*>(&y[base])        = make_float2(v0, v1);
    *reinterpret_cast<float2*>(&y[base + 1024]) = make_float2(v2, v3);
    float s  = v0 + v1 + v2 + v3;
    float ss = v0 * v0 + v1 * v1 + v2 * v2 + v3 * v3;
#pragma unroll
    for (int off = 32; off; off >>= 1) {
      s  += __shfl_down(s, off);
      ss += __shfl_down(ss, off);
    }
    if (lane == 0) { redsm[wave][o][0] = s; redsm[wave][o][1] = ss; }
  }
  __syncthreads();
  if (t < OCT) {
    float s  = redsm[0][t][0] + redsm[1][t][0] + redsm[2][t][0] + redsm[3][t][0];
    float ss = redsm[0][t][1] + redsm[1][t][1] + redsm[2][t][1] + redsm[3][t][1];
    part[((size_t)ty * COUT + oc0 + t) * 2]     = s;
    part[((size_t)ty * COUT + oc0 + t) * 2 + 1] = ss;
  }
}

// ---------------------------------------------------------------------------
// mean/rstd from 32 per-tile partials. np layout: [2c]=mean, [2c+1]=rstd.
// ---------------------------------------------------------------------------
__global__ void finalize_kernel(const float* __restrict__ part, int C,
                                float* __restrict__ np)
{
  int c = blockIdx.x * 64 + threadIdx.x;
  if (c >= C) return;
  float s = 0.f, ss = 0.f;
  for (int tile = 0; tile < 32; ++tile) {
    s  += part[((size_t)tile * C + c) * 2];
    ss += part[((size_t)tile * C + c) * 2 + 1];
  }
  float m = s * INV_VOX;
  float var = ss * INV_VOX - m * m;
  np[2 * c]     = m;
  np[2 * c + 1] = rsqrtf(var + EPSF);
}

// ---------------------------------------------------------------------------
// qk[j,D,H,W] = box3( qn[j*8+par, coarse] * kn[par, coarse] ) / 27
// par = (D&1)*4 + (H&1)*2 + (W&1)   (pixel-shuffle s=2 mapping)
// grid = (512 fine tiles of 8^3, 8 j), block = 256.
// ---------------------------------------------------------------------------
__global__ __launch_bounds__(256) void qk_box_kernel(
    const float* __restrict__ qraw, const float* __restrict__ npq,
    const float* __restrict__ kraw, const float* __restrict__ npk,
    float* __restrict__ qkout)
{
  __shared__ float s[1000];   // 10^3 halo tile
  const int j = blockIdx.y;
  const int tile = blockIdx.x;
  const int W0 = (tile & 7) * 8, H0 = ((tile >> 3) & 7) * 8, D0 = (tile >> 6) * 8;
  const int t = threadIdx.x;

  for (int f = t; f < 1000; f += 256) {
    int wz = f % 10; int r = f / 10; int hz = r % 10; int dz = r / 10;
    int D = D0 - 1 + dz, H = H0 - 1 + hz, W = W0 - 1 + wz;
    float val = 0.f;
    if ((unsigned)D < 64u && (unsigned)H < 64u && (unsigned)W < 64u) {
      int par = (D & 1) * 4 + (H & 1) * 2 + (W & 1);
      int cidx = (D >> 1) * 1024 + (H >> 1) * 32 + (W >> 1);
      float qv = qraw[(size_t)(j * 8 + par) * VOX + cidx];
      qv = fmaxf((qv - npq[2 * (j * 8 + par)]) * npq[2 * (j * 8 + par) + 1], 0.f);
      float kv = kraw[(size_t)par * VOX + cidx];
      kv = fmaxf((kv - npk[2 * par]) * npk[2 * par + 1], 0.f);
      val = qv * kv;
    }
    s[f] = val;
  }
  __syncthreads();
#pragma unroll
  for (int rep = 0; rep < 2; ++rep) {
    int o = t + rep * 256;
    int wz = o & 7, hz = (o >> 3) & 7, dz = o >> 6;
    float sum = 0.f;
#pragma unroll
    for (int a = 0; a < 3; ++a)
#pragma unroll
      for (int b = 0; b < 3; ++b)
#pragma unroll
        for (int c = 0; c < 3; ++c)
          sum += s[(dz + a) * 100 + (hz + b) * 10 + (wz + c)];
    qkout[(size_t)j * 262144 + (D0 + dz) * 4096 + (H0 + hz) * 64 + (W0 + wz)] =
        sum * (1.f / 27.f);
  }
}

// ---------------------------------------------------------------------------
// out[c,D,H,W] = box3( sum_j vn[c*8+j, coarse] * qk[j,D,H,W] ) / 27
// grid = (512 fine tiles, 64 c), block = 256.
// ---------------------------------------------------------------------------
__global__ __launch_bounds__(256) void einsum_box_kernel(
    const float* __restrict__ vraw, const float* __restrict__ npv,
    const float* __restrict__ qk, float* __restrict__ out)
{
  __shared__ float s[1000];
  const int c = blockIdx.y;
  const int tile = blockIdx.x;
  const int W0 = (tile & 7) * 8, H0 = ((tile >> 3) & 7) * 8, D0 = (tile >> 6) * 8;
  const int t = threadIdx.x;

  float mj[8], rj[8];
#pragma unroll
  for (int j = 0; j < 8; ++j) {
    mj[j] = npv[2 * (c * 8 + j)];
    rj[j] = npv[2 * (c * 8 + j) + 1];
  }

  for (int f = t; f < 1000; f += 256) {
    int wz = f % 10; int r = f / 10; int hz = r % 10; int dz = r / 10;
    int D = D0 - 1 + dz, H = H0 - 1 + hz, W = W0 - 1 + wz;
    float val = 0.f;
    if ((unsigned)D < 64u && (unsigned)H < 64u && (unsigned)W < 64u) {
      int cidx = (D >> 1) * 1024 + (H >> 1) * 32 + (W >> 1);
      int fidx = D * 4096 + H * 64 + W;
#pragma unroll
      for (int j = 0; j < 8; ++j) {
        float vv = vraw[(size_t)(c * 8 + j) * VOX + cidx];
        vv = fmaxf((vv - mj[j]) * rj[j], 0.f);
        val = fmaf(vv, qk[(size_t)j * 262144 + fidx], val);
      }
    }
    s[f] = val;
  }
  __syncthreads();
#pragma unroll
  for (int rep = 0; rep < 2; ++rep) {
    int o = t + rep * 256;
    int wz = o & 7, hz = (o >> 3) & 7, dz = o >> 6;
    float sum = 0.f;
#pragma unroll
    for (int a = 0; a < 3; ++a)
#pragma unroll
      for (int b = 0; b < 3; ++b)
#pragma unroll
        for (int cc = 0; cc < 3; ++cc)
          sum += s[(dz + a) * 100 + (hz + b) * 10 + (wz + cc)];
    out[(size_t)c * 262144 + (D0 + dz) * 4096 + (H0 + hz) * 64 + (W0 + wz)] =
        sum * (1.f / 27.f);
  }
}

// ---------------------------------------------------------------------------
extern "C" void kernel_launch(void* const* d_in, const int* in_sizes, int n_in,
                              void* d_out, int out_size, void* d_ws, size_t ws_size,
                              hipStream_t stream)
{
  (void)in_sizes; (void)n_in; (void)out_size; (void)ws_size;
  const float* x   = (const float*)d_in[0];
  const float* q1w = (const float*)d_in[1];
  const float* q1b = (const float*)d_in[2];
  const float* q2w = (const float*)d_in[3];
  const float* q2b = (const float*)d_in[4];
  const float* k1w = (const float*)d_in[5];
  const float* k1b = (const float*)d_in[6];
  const float* k2w = (const float*)d_in[7];
  const float* k2b = (const float*)d_in[8];
  const float* vw  = (const float*)d_in[9];
  const float* vb  = (const float*)d_in[10];
  float* out = (float*)d_out;

  float* p = (float*)d_ws;
  float* vraw  = p; p += (size_t)512 * VOX;   // 64 MiB
  float* qraw1 = p; p += (size_t)16 * VOX;    // 2 MiB
  float* qraw2 = p; p += (size_t)64 * VOX;    // 8 MiB
  float* kraw1 = p; p += (size_t)16 * VOX;    // 2 MiB
  float* kraw2 = p; p += (size_t)8 * VOX;     // 1 MiB
  float* qkbuf = p; p += (size_t)8 * 262144;  // 8 MiB
  float* part  = p; p += (size_t)32 * 616 * 2;
  float* np    = p; p += (size_t)2 * 616;

  float* part_q1 = part;
  float* part_q2 = part + 1024;
  float* part_k1 = part + 1024 + 4096;
  float* part_k2 = part + 1024 + 4096 + 1024;
  float* part_v  = part + 1024 + 4096 + 1024 + 512;
  float* np_q1 = np;
  float* np_q2 = np + 32;
  float* np_k1 = np + 160;
  float* np_k2 = np + 192;
  float* np_v  = np + 208;

  dim3 blk(256);
  conv_in_kernel<64, 16, false><<<dim3(1, 32), blk, 0, stream>>>(
      x, nullptr, q1w, q1b, qraw1, part_q1, 16);
  finalize_kernel<<<1, 64, 0, stream>>>(part_q1, 16, np_q1);
  conv_in_kernel<16, 16, true><<<dim3(4, 32), blk, 0, stream>>>(
      qraw1, np_q1, q2w, q2b, qraw2, part_q2, 64);
  finalize_kernel<<<1, 64, 0, stream>>>(part_q2, 64, np_q2);
  conv_in_kernel<64, 16, false><<<dim3(1, 32), blk, 0, stream>>>(
      x, nullptr, k1w, k1b, kraw1, part_k1, 16);
  finalize_kernel<<<1, 64, 0, stream>>>(part_k1, 16, np_k1);
  conv_in_kernel<16, 8, true><<<dim3(1, 32), blk, 0, stream>>>(
      kraw1, np_k1, k2w, k2b, kraw2, part_k2, 8);
  finalize_kernel<<<1, 64, 0, stream>>>(part_k2, 8, np_k2);
  conv_in_kernel<64, 16, false><<<dim3(32, 32), blk, 0, stream>>>(
      x, nullptr, vw, vb, vraw, part_v, 512);
  finalize_kernel<<<8, 64, 0, stream>>>(part_v, 512, np_v);
  qk_box_kernel<<<dim3(512, 8), blk, 0, stream>>>(
      qraw2, np_q2, kraw2, np_k2, qkbuf);
  einsum_box_kernel<<<dim3(512, 64), blk, 0, stream>>>(
      vraw, np_v, qkbuf, out);
}

// Round 3
// 1161.747 us; speedup vs baseline: 1.4661x; 1.4661x over previous
//
#include <hip/hip_runtime.h>

// QKV upsampling pipeline, fp32.
// R2 (resubmit after infra failure): (a) einsum_box restructured to
// one-block-per-fine-tile with qk staged in LDS and shared across 32 channels
// (fetch 1.9GB -> ~0.3GB); (b) small convs re-tiled to 1x8x32 tiles / OCT=8
// for >=256-block occupancy.

constexpr int VOX = 32 * 32 * 32;           // 32768 voxels per channel (coarse)
constexpr float INV_VOX = 1.0f / 32768.0f;
constexpr float EPSF = 1e-5f;

// ---------------------------------------------------------------------------
// Big conv (used for v): conv3d k=2 (pad lo=0,hi=1), tile 2(d)x16(h)x32(w),
// thread owns 2d x 1h x 2w. grid = (COUT/OCT, 32 tiles), block 256.
// Emits raw conv+bias and per-tile (sum,sumsq) partials.
// ---------------------------------------------------------------------------
template <int CIN, int OCT, bool NORM_IN>
__global__ __launch_bounds__(256) void conv_in_kernel(
    const float* __restrict__ x, const float* __restrict__ npar,
    const float* __restrict__ w, const float* __restrict__ bias,
    float* __restrict__ y, float* __restrict__ part, int COUT)
{
  __shared__ float xs[3 * 17 * 33];
  __shared__ float wlds[OCT * CIN * 8];
  __shared__ float redsm[4][OCT][2];

  const int t = threadIdx.x;
  const int oc0 = blockIdx.x * OCT;
  const int ty = blockIdx.y;
  const int d0 = (ty & 15) * 2;
  const int h0 = (ty >> 4) * 16;
  const int hh = t >> 4;
  const int ww0 = (t & 15) * 2;

  for (int f = t; f < OCT * CIN * 8; f += 256)
    wlds[f] = w[(size_t)oc0 * CIN * 8 + f];

  float acc[OCT][4];
#pragma unroll
  for (int o = 0; o < OCT; ++o)
#pragma unroll
    for (int k = 0; k < 4; ++k) acc[o][k] = 0.f;

  for (int ci = 0; ci < CIN; ++ci) {
    __syncthreads();
    float m = 0.f, rs = 1.f;
    if constexpr (NORM_IN) { m = npar[2 * ci]; rs = npar[2 * ci + 1]; }
    for (int f = t; f < 3 * 17 * 33; f += 256) {
      int wz = f % 33; int r = f / 33; int hz = r % 17; int dz = r / 17;
      int d = d0 + dz, h = h0 + hz;
      float v = 0.f;
      if (d < 32 && h < 32 && wz < 32) {
        v = x[(size_t)ci * VOX + d * 1024 + h * 32 + wz];
        if constexpr (NORM_IN) v = fmaxf((v - m) * rs, 0.f);
      }
      xs[f] = v;
    }
    __syncthreads();

    float xr[3][2][3];
#pragma unroll
    for (int a = 0; a < 3; ++a)
#pragma unroll
      for (int b = 0; b < 2; ++b)
#pragma unroll
        for (int c = 0; c < 3; ++c)
          xr[a][b][c] = xs[(a * 17 + hh + b) * 33 + ww0 + c];

#pragma unroll
    for (int o = 0; o < OCT; ++o) {
      const float* wp = &wlds[(o * CIN + ci) * 8];
      float wv[8];
#pragma unroll
      for (int q = 0; q < 8; ++q) wv[q] = wp[q];
#pragma unroll
      for (int dd = 0; dd < 2; ++dd)
#pragma unroll
        for (int wx = 0; wx < 2; ++wx) {
          float a = acc[o][dd * 2 + wx];
#pragma unroll
          for (int kd = 0; kd < 2; ++kd)
#pragma unroll
            for (int kh = 0; kh < 2; ++kh)
#pragma unroll
              for (int kw = 0; kw < 2; ++kw)
                a = fmaf(wv[kd * 4 + kh * 2 + kw], xr[dd + kd][kh][wx + kw], a);
          acc[o][dd * 2 + wx] = a;
        }
    }
  }

  const int lane = t & 63, wave = t >> 6;
#pragma unroll
  for (int o = 0; o < OCT; ++o) {
    float bo = bias[oc0 + o];
    float v0 = acc[o][0] + bo, v1 = acc[o][1] + bo;
    float v2 = acc[o][2] + bo, v3 = acc[o][3] + bo;
    size_t base = (size_t)(oc0 + o) * VOX + d0 * 1024 + (h0 + hh) * 32 + ww0;
    *reinterpret_cast<float2*>(&y[base])        = make_float2(v0, v1);
    *reinterpret_cast<float2*>(&y[base + 1024]) = make_float2(v2, v3);
    float s  = v0 + v1 + v2 + v3;
    float ss = v0 * v0 + v1 * v1 + v2 * v2 + v3 * v3;
#pragma unroll
    for (int off = 32; off; off >>= 1) {
      s  += __shfl_down(s, off);
      ss += __shfl_down(ss, off);
    }
    if (lane == 0) { redsm[wave][o][0] = s; redsm[wave][o][1] = ss; }
  }
  __syncthreads();
  if (t < OCT) {
    float s  = redsm[0][t][0] + redsm[1][t][0] + redsm[2][t][0] + redsm[3][t][0];
    float ss = redsm[0][t][1] + redsm[1][t][1] + redsm[2][t][1] + redsm[3][t][1];
    part[((size_t)ty * COUT + oc0 + t) * 2]     = s;
    part[((size_t)ty * COUT + oc0 + t) * 2 + 1] = ss;
  }
}

// ---------------------------------------------------------------------------
// Small conv: tile 1(d)x8(h)x32(w) -> 128 tiles, 1 voxel/thread, OCT=8.
// grid = (COUT/8, 128), block 256.
// ---------------------------------------------------------------------------
template <int CIN, bool NORM_IN>
__global__ __launch_bounds__(256) void conv_small_kernel(
    const float* __restrict__ x, const float* __restrict__ npar,
    const float* __restrict__ w, const float* __restrict__ bias,
    float* __restrict__ y, float* __restrict__ part, int COUT)
{
  constexpr int OCT = 8;
  __shared__ float xs[2 * 9 * 33];        // 594
  __shared__ float wlds[OCT * CIN * 8];
  __shared__ float redsm[4][OCT][2];

  const int t = threadIdx.x;
  const int oc0 = blockIdx.x * OCT;
  const int ty = blockIdx.y;              // 0..127
  const int d0 = ty & 31;
  const int h0 = (ty >> 5) * 8;
  const int hh = t >> 5;                  // 0..7
  const int ww = t & 31;                  // 0..31

  for (int f = t; f < OCT * CIN * 8; f += 256)
    wlds[f] = w[(size_t)oc0 * CIN * 8 + f];

  float acc[OCT];
#pragma unroll
  for (int o = 0; o < OCT; ++o) acc[o] = 0.f;

  for (int ci = 0; ci < CIN; ++ci) {
    __syncthreads();
    float m = 0.f, rs = 1.f;
    if constexpr (NORM_IN) { m = npar[2 * ci]; rs = npar[2 * ci + 1]; }
    for (int f = t; f < 2 * 9 * 33; f += 256) {
      int wz = f % 33; int r = f / 33; int hz = r % 9; int dz = r / 9;
      int d = d0 + dz, h = h0 + hz;
      float v = 0.f;
      if (d < 32 && h < 32 && wz < 32) {
        v = x[(size_t)ci * VOX + d * 1024 + h * 32 + wz];
        if constexpr (NORM_IN) v = fmaxf((v - m) * rs, 0.f);
      }
      xs[f] = v;
    }
    __syncthreads();

    float xr[2][2][2];
#pragma unroll
    for (int a = 0; a < 2; ++a)
#pragma unroll
      for (int b = 0; b < 2; ++b)
#pragma unroll
        for (int c = 0; c < 2; ++c)
          xr[a][b][c] = xs[(a * 9 + hh + b) * 33 + ww + c];

#pragma unroll
    for (int o = 0; o < OCT; ++o) {
      const float* wp = &wlds[(o * CIN + ci) * 8];
      float a = acc[o];
#pragma unroll
      for (int kd = 0; kd < 2; ++kd)
#pragma unroll
        for (int kh = 0; kh < 2; ++kh)
#pragma unroll
          for (int kw = 0; kw < 2; ++kw)
            a = fmaf(wp[kd * 4 + kh * 2 + kw], xr[kd][kh][kw], a);
      acc[o] = a;
    }
  }

  const int lane = t & 63, wave = t >> 6;
#pragma unroll
  for (int o = 0; o < OCT; ++o) {
    float v0 = acc[o] + bias[oc0 + o];
    y[(size_t)(oc0 + o) * VOX + d0 * 1024 + (h0 + hh) * 32 + ww] = v0;
    float s = v0, ss = v0 * v0;
#pragma unroll
    for (int off = 32; off; off >>= 1) {
      s  += __shfl_down(s, off);
      ss += __shfl_down(ss, off);
    }
    if (lane == 0) { redsm[wave][o][0] = s; redsm[wave][o][1] = ss; }
  }
  __syncthreads();
  if (t < OCT) {
    float s  = redsm[0][t][0] + redsm[1][t][0] + redsm[2][t][0] + redsm[3][t][0];
    float ss = redsm[0][t][1] + redsm[1][t][1] + redsm[2][t][1] + redsm[3][t][1];
    part[((size_t)ty * COUT + oc0 + t) * 2]     = s;
    part[((size_t)ty * COUT + oc0 + t) * 2 + 1] = ss;
  }
}

// ---------------------------------------------------------------------------
__global__ void finalize_kernel(const float* __restrict__ part, int C, int NT,
                                float* __restrict__ np)
{
  int c = blockIdx.x * 64 + threadIdx.x;
  if (c >= C) return;
  float s = 0.f, ss = 0.f;
  for (int tile = 0; tile < NT; ++tile) {
    s  += part[((size_t)tile * C + c) * 2];
    ss += part[((size_t)tile * C + c) * 2 + 1];
  }
  float m = s * INV_VOX;
  float var = ss * INV_VOX - m * m;
  np[2 * c]     = m;
  np[2 * c + 1] = rsqrtf(var + EPSF);
}

// ---------------------------------------------------------------------------
// qk[j,D,H,W] = box3( qn[j*8+par] * kn[par] ) / 27 at fine res.
// grid = (512 tiles, 8 j), block 256.
// ---------------------------------------------------------------------------
__global__ __launch_bounds__(256) void qk_box_kernel(
    const float* __restrict__ qraw, const float* __restrict__ npq,
    const float* __restrict__ kraw, const float* __restrict__ npk,
    float* __restrict__ qkout)
{
  __shared__ float s[1000];
  const int j = blockIdx.y;
  const int tile = blockIdx.x;
  const int W0 = (tile & 7) * 8, H0 = ((tile >> 3) & 7) * 8, D0 = (tile >> 6) * 8;
  const int t = threadIdx.x;

  for (int f = t; f < 1000; f += 256) {
    int wz = f % 10; int r = f / 10; int hz = r % 10; int dz = r / 10;
    int D = D0 - 1 + dz, H = H0 - 1 + hz, W = W0 - 1 + wz;
    float val = 0.f;
    if ((unsigned)D < 64u && (unsigned)H < 64u && (unsigned)W < 64u) {
      int par = (D & 1) * 4 + (H & 1) * 2 + (W & 1);
      int cidx = (D >> 1) * 1024 + (H >> 1) * 32 + (W >> 1);
      float qv = qraw[(size_t)(j * 8 + par) * VOX + cidx];
      qv = fmaxf((qv - npq[2 * (j * 8 + par)]) * npq[2 * (j * 8 + par) + 1], 0.f);
      float kv = kraw[(size_t)par * VOX + cidx];
      kv = fmaxf((kv - npk[2 * par]) * npk[2 * par + 1], 0.f);
      val = qv * kv;
    }
    s[f] = val;
  }
  __syncthreads();
#pragma unroll
  for (int rep = 0; rep < 2; ++rep) {
    int o = t + rep * 256;
    int wz = o & 7, hz = (o >> 3) & 7, dz = o >> 6;
    float sum = 0.f;
#pragma unroll
    for (int a = 0; a < 3; ++a)
#pragma unroll
      for (int b = 0; b < 3; ++b)
#pragma unroll
        for (int c = 0; c < 3; ++c)
          sum += s[(dz + a) * 100 + (hz + b) * 10 + (wz + c)];
    qkout[(size_t)j * 262144 + (D0 + dz) * 4096 + (H0 + hz) * 64 + (W0 + wz)] =
        sum * (1.f / 27.f);
  }
}

// ---------------------------------------------------------------------------
// out[c,*] = box3( sum_j vn[c*8+j, coarse] * qk[j, fine] ) / 27
// One block per 8^3 fine tile x 32-channel group. qk halo staged once in LDS,
// reused by all 32 channels. grid = (512, 2), block 256.
// ---------------------------------------------------------------------------
__global__ __launch_bounds__(256) void einsum_box_kernel(
    const float* __restrict__ vraw, const float* __restrict__ npv,
    const float* __restrict__ qk, float* __restrict__ out)
{
  __shared__ float qks[1000][8];   // 32000 B, [pos][j]
  __shared__ float vs[216][8];     // 6912 B,  [coarse][j]
  __shared__ float qkvs[1000];     // 4000 B
  const int tile = blockIdx.x;
  const int c0 = blockIdx.y * 32;
  const int W0 = (tile & 7) * 8, H0 = ((tile >> 3) & 7) * 8, D0 = (tile >> 6) * 8;
  const int t = threadIdx.x;
  const int cbD = (D0 >> 1) - 1, cbH = (H0 >> 1) - 1, cbW = (W0 >> 1) - 1;

  // stage qk halo: 8 j x 1000 positions (transposed to [pos][j])
  for (int j = 0; j < 8; ++j)
    for (int f = t; f < 1000; f += 256) {
      int wz = f % 10; int r = f / 10; int hz = r % 10; int dz = r / 10;
      int D = D0 - 1 + dz, H = H0 - 1 + hz, W = W0 - 1 + wz;
      float v = 0.f;
      if ((unsigned)D < 64u && (unsigned)H < 64u && (unsigned)W < 64u)
        v = qk[(size_t)j * 262144 + D * 4096 + H * 64 + W];
      qks[f][j] = v;
    }

  for (int ci = 0; ci < 32; ++ci) {
    const int c = c0 + ci;
    __syncthreads();   // qks ready (iter0); prev box-phase done (later iters)
    // stage normalized coarse v: 8 j x 6^3
    for (int f = t; f < 1728; f += 256) {
      int j = f / 216; int idx = f % 216;
      int dz = idx / 36, hz = (idx / 6) % 6, wz = idx % 6;
      int cD = cbD + dz, cH = cbH + hz, cW = cbW + wz;
      float v = 0.f;
      if ((unsigned)cD < 32u && (unsigned)cH < 32u && (unsigned)cW < 32u) {
        int ch = c * 8 + j;
        float raw = vraw[(size_t)ch * VOX + cD * 1024 + cH * 32 + cW];
        v = fmaxf((raw - npv[2 * ch]) * npv[2 * ch + 1], 0.f);
      }
      vs[idx][j] = v;
    }
    __syncthreads();
    // qkv halo values
    for (int pos = t; pos < 1000; pos += 256) {
      int wz = pos % 10; int r = pos / 10; int hz = r % 10; int dz = r / 10;
      int D = D0 - 1 + dz, H = H0 - 1 + hz, W = W0 - 1 + wz;
      float val = 0.f;
      if ((unsigned)D < 64u && (unsigned)H < 64u && (unsigned)W < 64u) {
        int vidx = ((D >> 1) - cbD) * 36 + ((H >> 1) - cbH) * 6 + ((W >> 1) - cbW);
        float4 qa = *reinterpret_cast<const float4*>(&qks[pos][0]);
        float4 qb = *reinterpret_cast<const float4*>(&qks[pos][4]);
        float4 va = *reinterpret_cast<const float4*>(&vs[vidx][0]);
        float4 vb = *reinterpret_cast<const float4*>(&vs[vidx][4]);
        val = qa.x * va.x;
        val = fmaf(qa.y, va.y, val);
        val = fmaf(qa.z, va.z, val);
        val = fmaf(qa.w, va.w, val);
        val = fmaf(qb.x, vb.x, val);
        val = fmaf(qb.y, vb.y, val);
        val = fmaf(qb.z, vb.z, val);
        val = fmaf(qb.w, vb.w, val);
      }
      qkvs[pos] = val;
    }
    __syncthreads();
    // 27-tap box + store
#pragma unroll
    for (int rep = 0; rep < 2; ++rep) {
      int o = t + rep * 256;
      int wz = o & 7, hz = (o >> 3) & 7, dz = o >> 6;
      float sum = 0.f;
#pragma unroll
      for (int a = 0; a < 3; ++a)
#pragma unroll
        for (int b = 0; b < 3; ++b)
#pragma unroll
          for (int cc = 0; cc < 3; ++cc)
            sum += qkvs[(dz + a) * 100 + (hz + b) * 10 + (wz + cc)];
      out[(size_t)c * 262144 + (D0 + dz) * 4096 + (H0 + hz) * 64 + (W0 + wz)] =
          sum * (1.f / 27.f);
    }
  }
}

// ---------------------------------------------------------------------------
extern "C" void kernel_launch(void* const* d_in, const int* in_sizes, int n_in,
                              void* d_out, int out_size, void* d_ws, size_t ws_size,
                              hipStream_t stream)
{
  (void)in_sizes; (void)n_in; (void)out_size; (void)ws_size;
  const float* x   = (const float*)d_in[0];
  const float* q1w = (const float*)d_in[1];
  const float* q1b = (const float*)d_in[2];
  const float* q2w = (const float*)d_in[3];
  const float* q2b = (const float*)d_in[4];
  const float* k1w = (const float*)d_in[5];
  const float* k1b = (const float*)d_in[6];
  const float* k2w = (const float*)d_in[7];
  const float* k2b = (const float*)d_in[8];
  const float* vw  = (const float*)d_in[9];
  const float* vb  = (const float*)d_in[10];
  float* out = (float*)d_out;

  float* p = (float*)d_ws;
  float* vraw  = p; p += (size_t)512 * VOX;
  float* qraw1 = p; p += (size_t)16 * VOX;
  float* qraw2 = p; p += (size_t)64 * VOX;
  float* kraw1 = p; p += (size_t)16 * VOX;
  float* kraw2 = p; p += (size_t)8 * VOX;
  float* qkbuf = p; p += (size_t)8 * 262144;
  float* part_q1 = p; p += 128 * 16 * 2;
  float* part_q2 = p; p += 128 * 64 * 2;
  float* part_k1 = p; p += 128 * 16 * 2;
  float* part_k2 = p; p += 128 * 8 * 2;
  float* part_v  = p; p += 32 * 512 * 2;
  float* np_q1 = p; p += 2 * 16;
  float* np_q2 = p; p += 2 * 64;
  float* np_k1 = p; p += 2 * 16;
  float* np_k2 = p; p += 2 * 8;
  float* np_v  = p; p += 2 * 512;

  dim3 blk(256);
  conv_small_kernel<64, false><<<dim3(2, 128), blk, 0, stream>>>(
      x, nullptr, q1w, q1b, qraw1, part_q1, 16);
  finalize_kernel<<<1, 64, 0, stream>>>(part_q1, 16, 128, np_q1);
  conv_small_kernel<16, true><<<dim3(8, 128), blk, 0, stream>>>(
      qraw1, np_q1, q2w, q2b, qraw2, part_q2, 64);
  finalize_kernel<<<1, 64, 0, stream>>>(part_q2, 64, 128, np_q2);
  conv_small_kernel<64, false><<<dim3(2, 128), blk, 0, stream>>>(
      x, nullptr, k1w, k1b, kraw1, part_k1, 16);
  finalize_kernel<<<1, 64, 0, stream>>>(part_k1, 16, 128, np_k1);
  conv_small_kernel<16, true><<<dim3(1, 128), blk, 0, stream>>>(
      kraw1, np_k1, k2w, k2b, kraw2, part_k2, 8);
  finalize_kernel<<<1, 64, 0, stream>>>(part_k2, 8, 128, np_k2);
  conv_in_kernel<64, 16, false><<<dim3(32, 32), blk, 0, stream>>>(
      x, nullptr, vw, vb, vraw, part_v, 512);
  finalize_kernel<<<8, 64, 0, stream>>>(part_v, 512, 32, np_v);
  qk_box_kernel<<<dim3(512, 8), blk, 0, stream>>>(
      qraw2, np_q2, kraw2, np_k2, qkbuf);
  einsum_box_kernel<<<dim3(512, 2), blk, 0, stream>>>(
      vraw, np_v, qkbuf, out);
}

// Round 4
// 893.673 us; speedup vs baseline: 1.9059x; 1.3000x over previous
//
#include <hip/hip_runtime.h>
#include <hip/hip_bf16.h>

// QKV upsampling pipeline.
// R4: v-conv (512x64 k=2 conv = GEMM M=512,N=32768,K=512) moved to MFMA
// bf16 hi/lo 3-term split. W prepacked to fragment order; x pre-transposed to
// [vox][ci] bf16 hi/lo (aliased into qkbuf region); LDS halo XOR-swizzled.
// Small convs / qk_box / einsum unchanged from R3.

constexpr int VOX = 32 * 32 * 32;
constexpr float INV_VOX = 1.0f / 32768.0f;
constexpr float EPSF = 1e-5f;

typedef __attribute__((ext_vector_type(8))) short s16x8;
typedef __attribute__((ext_vector_type(4))) float f32x4;

static __device__ __forceinline__ ushort bf16_bits(float v) {
  __hip_bfloat16 h = __float2bfloat16(v);
  return *reinterpret_cast<ushort*>(&h);
}

// ---------------------------------------------------------------------------
// Weight prepack: vw fp32 [512][64][8] -> Wf hi/lo bf16, fragment order:
// chunk((tap*2+khalf)*4+g, oc) holds 8 ci (= khalf*32+g*8+j) for that oc.
// ---------------------------------------------------------------------------
__global__ void wprep_kernel(const float* __restrict__ vw,
                             ushort* __restrict__ wh, ushort* __restrict__ wl)
{
  int tid = blockIdx.x * 256 + threadIdx.x;       // 32768 total
  if (tid >= 32768) return;
  int oc = tid & 511;
  int g = (tid >> 9) & 3;
  int khalf = (tid >> 11) & 1;
  int tap = tid >> 12;
  uint h[4], l[4];
#pragma unroll
  for (int p = 0; p < 4; ++p) {
    int ci0 = khalf * 32 + g * 8 + 2 * p;
    float v0 = vw[oc * 512 + ci0 * 8 + tap];
    float v1 = vw[oc * 512 + (ci0 + 1) * 8 + tap];
    ushort h0 = bf16_bits(v0), h1 = bf16_bits(v1);
    float r0 = v0 - __bfloat162float(*reinterpret_cast<__hip_bfloat16*>(&h0));
    float r1 = v1 - __bfloat162float(*reinterpret_cast<__hip_bfloat16*>(&h1));
    h[p] = (uint)h0 | ((uint)h1 << 16);
    l[p] = (uint)bf16_bits(r0) | ((uint)bf16_bits(r1) << 16);
  }
  size_t base = (size_t)tid * 8;
  *reinterpret_cast<uint4*>(wh + base) = make_uint4(h[0], h[1], h[2], h[3]);
  *reinterpret_cast<uint4*>(wl + base) = make_uint4(l[0], l[1], l[2], l[3]);
}

// ---------------------------------------------------------------------------
// x transpose: x fp32 [64][32768] -> xT hi/lo bf16 [32768][64].
// grid 512 (64-vox tiles), block 256.
// ---------------------------------------------------------------------------
__global__ __launch_bounds__(256) void xprep_kernel(
    const float* __restrict__ x, ushort* __restrict__ xh, ushort* __restrict__ xl)
{
  __shared__ float ts[64][65];
  const int t = threadIdx.x;
  const int vox0 = blockIdx.x * 64;
#pragma unroll
  for (int i = 0; i < 16; ++i) {
    int e = i * 256 + t;
    int ci = e >> 6, vl = e & 63;
    ts[ci][vl] = x[(size_t)ci * VOX + vox0 + vl];
  }
  __syncthreads();
  const int vl = t >> 2, cig = t & 3;
  uint h[8], l[8];
#pragma unroll
  for (int p = 0; p < 8; ++p) {
    float v0 = ts[cig * 16 + 2 * p][vl];
    float v1 = ts[cig * 16 + 2 * p + 1][vl];
    ushort h0 = bf16_bits(v0), h1 = bf16_bits(v1);
    float r0 = v0 - __bfloat162float(*reinterpret_cast<__hip_bfloat16*>(&h0));
    float r1 = v1 - __bfloat162float(*reinterpret_cast<__hip_bfloat16*>(&h1));
    h[p] = (uint)h0 | ((uint)h1 << 16);
    l[p] = (uint)bf16_bits(r0) | ((uint)bf16_bits(r1) << 16);
  }
  size_t base = (size_t)(vox0 + vl) * 64 + cig * 16;
  *reinterpret_cast<uint4*>(xh + base)     = make_uint4(h[0], h[1], h[2], h[3]);
  *reinterpret_cast<uint4*>(xh + base + 8) = make_uint4(h[4], h[5], h[6], h[7]);
  *reinterpret_cast<uint4*>(xl + base)     = make_uint4(l[0], l[1], l[2], l[3]);
  *reinterpret_cast<uint4*>(xl + base + 8) = make_uint4(l[4], l[5], l[6], l[7]);
}

// ---------------------------------------------------------------------------
// MFMA v-conv. Block: M=256 oc x N=128 vox (tile d2 x h4 x w16).
// 4 waves = 2M x 2N (wn = dd). K = 8 taps x 64 ci. bf16 3-term split.
// LDS: x halo (3x5x17 pos) x 64 ci x {hi,lo}, XOR-swizzled.
// grid = (2, 256).
// ---------------------------------------------------------------------------
__global__ __launch_bounds__(256) void conv_v_mfma(
    const ushort* __restrict__ xh, const ushort* __restrict__ xl,
    const ushort* __restrict__ wh, const ushort* __restrict__ wl,
    const float* __restrict__ bias, float* __restrict__ y,
    float* __restrict__ part)
{
  __shared__ ushort Bs[2 * 255 * 64];   // 65280 B

  const int t = threadIdx.x;
  const int wave = t >> 6, lane = t & 63;
  const int wm = wave >> 1, wn = wave & 1;
  const int g = lane >> 4, ww = lane & 15;
  const int m0 = blockIdx.x * 256;
  const int nt = blockIdx.y;
  const int td = nt >> 4, th = (nt >> 1) & 7, tw = nt & 1;
  const int d0 = td * 2, h0 = th * 4, w0 = tw * 16;

  // stage halo: 2 splits x 255 pos x 8 cig 16B chunks
  for (int i = 0; i < 16; ++i) {
    int c = i * 256 + t;
    if (c < 4080) {
      int split = (c >= 2040) ? 1 : 0;
      int c2 = c - split * 2040;
      int pos = c2 >> 3, cig = c2 & 7;
      int dz = pos / 85, rem = pos - dz * 85;
      int hz = rem / 17, wz = rem - hz * 17;
      int d = d0 + dz, h = h0 + hz, w = w0 + wz;
      uint4 val = make_uint4(0, 0, 0, 0);
      if (d < 32 && h < 32 && w < 32) {
        const ushort* src = split ? xl : xh;
        val = *reinterpret_cast<const uint4*>(
            src + (size_t)(d * 1024 + h * 32 + w) * 64 + cig * 8);
      }
      int addr = (pos << 7) + cig * 16;
      addr ^= (pos & 7) << 4;
      *reinterpret_cast<uint4*>(
          reinterpret_cast<char*>(Bs) + split * 32640 + addr) = val;
    }
  }
  __syncthreads();

  const int ocl = m0 + wm * 128 + ww;   // lane's oc for A frags
  f32x4 acc[8][4];
#pragma unroll
  for (int mf = 0; mf < 8; ++mf)
#pragma unroll
    for (int hh = 0; hh < 4; ++hh) acc[mf][hh] = (f32x4){0.f, 0.f, 0.f, 0.f};

  for (int tap = 0; tap < 8; ++tap) {
    const int kd = tap >> 2, kh = (tap >> 1) & 1, kw = tap & 1;
#pragma unroll
    for (int khalf = 0; khalf < 2; ++khalf) {
      const size_t abase = ((size_t)((tap * 2 + khalf) * 4 + g) * 512 + ocl) * 8;
      s16x8 Ah[8], Al[8];
#pragma unroll
      for (int mf = 0; mf < 8; ++mf) {
        Ah[mf] = *reinterpret_cast<const s16x8*>(wh + abase + mf * 128);
        Al[mf] = *reinterpret_cast<const s16x8*>(wl + abase + mf * 128);
      }
      const int srow = ((wn + kd) * 5 + kh) * 17 + kw;
#pragma unroll
      for (int hh = 0; hh < 4; ++hh) {
        int pos = srow + hh * 17 + ww;
        int baddr = (pos << 7) + khalf * 64 + g * 16;
        baddr ^= (pos & 7) << 4;
        const char* bp = reinterpret_cast<const char*>(Bs) + baddr;
        s16x8 Bh = *reinterpret_cast<const s16x8*>(bp);
        s16x8 Bl = *reinterpret_cast<const s16x8*>(bp + 32640);
#pragma unroll
        for (int mf = 0; mf < 8; ++mf) {
          acc[mf][hh] = __builtin_amdgcn_mfma_f32_16x16x32_bf16(
              Ah[mf], Bh, acc[mf][hh], 0, 0, 0);
          acc[mf][hh] = __builtin_amdgcn_mfma_f32_16x16x32_bf16(
              Al[mf], Bh, acc[mf][hh], 0, 0, 0);
          acc[mf][hh] = __builtin_amdgcn_mfma_f32_16x16x32_bf16(
              Ah[mf], Bl, acc[mf][hh], 0, 0, 0);
        }
      }
    }
  }

  // epilogue: bias, store, per-oc (sum,sumsq) over this wave's 64 vox
  float bs[8][4];
#pragma unroll
  for (int mf = 0; mf < 8; ++mf)
#pragma unroll
    for (int reg = 0; reg < 4; ++reg)
      bs[mf][reg] = bias[m0 + wm * 128 + mf * 16 + g * 4 + reg];

  float ssum[8][4], ssq[8][4];
#pragma unroll
  for (int mf = 0; mf < 8; ++mf)
#pragma unroll
    for (int reg = 0; reg < 4; ++reg) { ssum[mf][reg] = 0.f; ssq[mf][reg] = 0.f; }

#pragma unroll
  for (int mf = 0; mf < 8; ++mf) {
#pragma unroll
    for (int hh = 0; hh < 4; ++hh) {
      int vox = (d0 + wn) * 1024 + (h0 + hh) * 32 + w0 + ww;
#pragma unroll
      for (int reg = 0; reg < 4; ++reg) {
        float v = acc[mf][hh][reg] + bs[mf][reg];
        int oc = m0 + wm * 128 + mf * 16 + g * 4 + reg;
        y[(size_t)oc * VOX + vox] = v;
        ssum[mf][reg] += v;
        ssq[mf][reg] += v * v;
      }
    }
  }
#pragma unroll
  for (int mf = 0; mf < 8; ++mf)
#pragma unroll
    for (int reg = 0; reg < 4; ++reg)
#pragma unroll
      for (int off = 1; off < 16; off <<= 1) {
        ssum[mf][reg] += __shfl_xor(ssum[mf][reg], off);
        ssq[mf][reg]  += __shfl_xor(ssq[mf][reg], off);
      }
  if ((lane & 15) == 0) {
    float* pp = part + (size_t)(nt * 2 + wn) * 1024;
#pragma unroll
    for (int mf = 0; mf < 8; ++mf)
#pragma unroll
      for (int reg = 0; reg < 4; ++reg) {
        int oc = m0 + wm * 128 + mf * 16 + g * 4 + reg;
        pp[oc * 2]     = ssum[mf][reg];
        pp[oc * 2 + 1] = ssq[mf][reg];
      }
  }
}

// ---------------------------------------------------------------------------
// Small conv: tile 1(d)x8(h)x32(w) -> 128 tiles, 1 voxel/thread, OCT=8.
// ---------------------------------------------------------------------------
template <int CIN, bool NORM_IN>
__global__ __launch_bounds__(256) void conv_small_kernel(
    const float* __restrict__ x, const float* __restrict__ npar,
    const float* __restrict__ w, const float* __restrict__ bias,
    float* __restrict__ y, float* __restrict__ part, int COUT)
{
  constexpr int OCT = 8;
  __shared__ float xs[2 * 9 * 33];
  __shared__ float wlds[OCT * CIN * 8];
  __shared__ float redsm[4][OCT][2];

  const int t = threadIdx.x;
  const int oc0 = blockIdx.x * OCT;
  const int ty = blockIdx.y;
  const int d0 = ty & 31;
  const int h0 = (ty >> 5) * 8;
  const int hh = t >> 5;
  const int ww = t & 31;

  for (int f = t; f < OCT * CIN * 8; f += 256)
    wlds[f] = w[(size_t)oc0 * CIN * 8 + f];

  float acc[OCT];
#pragma unroll
  for (int o = 0; o < OCT; ++o) acc[o] = 0.f;

  for (int ci = 0; ci < CIN; ++ci) {
    __syncthreads();
    float m = 0.f, rs = 1.f;
    if constexpr (NORM_IN) { m = npar[2 * ci]; rs = npar[2 * ci + 1]; }
    for (int f = t; f < 2 * 9 * 33; f += 256) {
      int wz = f % 33; int r = f / 33; int hz = r % 9; int dz = r / 9;
      int d = d0 + dz, h = h0 + hz;
      float v = 0.f;
      if (d < 32 && h < 32 && wz < 32) {
        v = x[(size_t)ci * VOX + d * 1024 + h * 32 + wz];
        if constexpr (NORM_IN) v = fmaxf((v - m) * rs, 0.f);
      }
      xs[f] = v;
    }
    __syncthreads();

    float xr[2][2][2];
#pragma unroll
    for (int a = 0; a < 2; ++a)
#pragma unroll
      for (int b = 0; b < 2; ++b)
#pragma unroll
        for (int c = 0; c < 2; ++c)
          xr[a][b][c] = xs[(a * 9 + hh + b) * 33 + ww + c];

#pragma unroll
    for (int o = 0; o < OCT; ++o) {
      const float* wp = &wlds[(o * CIN + ci) * 8];
      float a = acc[o];
#pragma unroll
      for (int kd = 0; kd < 2; ++kd)
#pragma unroll
        for (int kh = 0; kh < 2; ++kh)
#pragma unroll
          for (int kw = 0; kw < 2; ++kw)
            a = fmaf(wp[kd * 4 + kh * 2 + kw], xr[kd][kh][kw], a);
      acc[o] = a;
    }
  }

  const int lane = t & 63, wave = t >> 6;
#pragma unroll
  for (int o = 0; o < OCT; ++o) {
    float v0 = acc[o] + bias[oc0 + o];
    y[(size_t)(oc0 + o) * VOX + d0 * 1024 + (h0 + hh) * 32 + ww] = v0;
    float s = v0, ss = v0 * v0;
#pragma unroll
    for (int off = 32; off; off >>= 1) {
      s  += __shfl_down(s, off);
      ss += __shfl_down(ss, off);
    }
    if (lane == 0) { redsm[wave][o][0] = s; redsm[wave][o][1] = ss; }
  }
  __syncthreads();
  if (t < OCT) {
    float s  = redsm[0][t][0] + redsm[1][t][0] + redsm[2][t][0] + redsm[3][t][0];
    float ss = redsm[0][t][1] + redsm[1][t][1] + redsm[2][t][1] + redsm[3][t][1];
    part[((size_t)ty * COUT + oc0 + t) * 2]     = s;
    part[((size_t)ty * COUT + oc0 + t) * 2 + 1] = ss;
  }
}

// ---------------------------------------------------------------------------
__global__ void finalize_kernel(const float* __restrict__ part, int C, int NT,
                                float* __restrict__ np)
{
  int c = blockIdx.x * 64 + threadIdx.x;
  if (c >= C) return;
  float s = 0.f, ss = 0.f;
  for (int tile = 0; tile < NT; ++tile) {
    s  += part[((size_t)tile * C + c) * 2];
    ss += part[((size_t)tile * C + c) * 2 + 1];
  }
  float m = s * INV_VOX;
  float var = ss * INV_VOX - m * m;
  np[2 * c]     = m;
  np[2 * c + 1] = rsqrtf(var + EPSF);
}

// ---------------------------------------------------------------------------
__global__ __launch_bounds__(256) void qk_box_kernel(
    const float* __restrict__ qraw, const float* __restrict__ npq,
    const float* __restrict__ kraw, const float* __restrict__ npk,
    float* __restrict__ qkout)
{
  __shared__ float s[1000];
  const int j = blockIdx.y;
  const int tile = blockIdx.x;
  const int W0 = (tile & 7) * 8, H0 = ((tile >> 3) & 7) * 8, D0 = (tile >> 6) * 8;
  const int t = threadIdx.x;

  for (int f = t; f < 1000; f += 256) {
    int wz = f % 10; int r = f / 10; int hz = r % 10; int dz = r / 10;
    int D = D0 - 1 + dz, H = H0 - 1 + hz, W = W0 - 1 + wz;
    float val = 0.f;
    if ((unsigned)D < 64u && (unsigned)H < 64u && (unsigned)W < 64u) {
      int par = (D & 1) * 4 + (H & 1) * 2 + (W & 1);
      int cidx = (D >> 1) * 1024 + (H >> 1) * 32 + (W >> 1);
      float qv = qraw[(size_t)(j * 8 + par) * VOX + cidx];
      qv = fmaxf((qv - npq[2 * (j * 8 + par)]) * npq[2 * (j * 8 + par) + 1], 0.f);
      float kv = kraw[(size_t)par * VOX + cidx];
      kv = fmaxf((kv - npk[2 * par]) * npk[2 * par + 1], 0.f);
      val = qv * kv;
    }
    s[f] = val;
  }
  __syncthreads();
#pragma unroll
  for (int rep = 0; rep < 2; ++rep) {
    int o = t + rep * 256;
    int wz = o & 7, hz = (o >> 3) & 7, dz = o >> 6;
    float sum = 0.f;
#pragma unroll
    for (int a = 0; a < 3; ++a)
#pragma unroll
      for (int b = 0; b < 3; ++b)
#pragma unroll
        for (int c = 0; c < 3; ++c)
          sum += s[(dz + a) * 100 + (hz + b) * 10 + (wz + c)];
    qkout[(size_t)j * 262144 + (D0 + dz) * 4096 + (H0 + hz) * 64 + (W0 + wz)] =
        sum * (1.f / 27.f);
  }
}

// ---------------------------------------------------------------------------
__global__ __launch_bounds__(256) void einsum_box_kernel(
    const float* __restrict__ vraw, const float* __restrict__ npv,
    const float* __restrict__ qk, float* __restrict__ out)
{
  __shared__ float qks[1000][8];
  __shared__ float vs[216][8];
  __shared__ float qkvs[1000];
  const int tile = blockIdx.x;
  const int c0 = blockIdx.y * 32;
  const int W0 = (tile & 7) * 8, H0 = ((tile >> 3) & 7) * 8, D0 = (tile >> 6) * 8;
  const int t = threadIdx.x;
  const int cbD = (D0 >> 1) - 1, cbH = (H0 >> 1) - 1, cbW = (W0 >> 1) - 1;

  for (int j = 0; j < 8; ++j)
    for (int f = t; f < 1000; f += 256) {
      int wz = f % 10; int r = f / 10; int hz = r % 10; int dz = r / 10;
      int D = D0 - 1 + dz, H = H0 - 1 + hz, W = W0 - 1 + wz;
      float v = 0.f;
      if ((unsigned)D < 64u && (unsigned)H < 64u && (unsigned)W < 64u)
        v = qk[(size_t)j * 262144 + D * 4096 + H * 64 + W];
      qks[f][j] = v;
    }

  for (int ci = 0; ci < 32; ++ci) {
    const int c = c0 + ci;
    __syncthreads();
    for (int f = t; f < 1728; f += 256) {
      int j = f / 216; int idx = f % 216;
      int dz = idx / 36, hz = (idx / 6) % 6, wz = idx % 6;
      int cD = cbD + dz, cH = cbH + hz, cW = cbW + wz;
      float v = 0.f;
      if ((unsigned)cD < 32u && (unsigned)cH < 32u && (unsigned)cW < 32u) {
        int ch = c * 8 + j;
        float raw = vraw[(size_t)ch * VOX + cD * 1024 + cH * 32 + cW];
        v = fmaxf((raw - npv[2 * ch]) * npv[2 * ch + 1], 0.f);
      }
      vs[idx][j] = v;
    }
    __syncthreads();
    for (int pos = t; pos < 1000; pos += 256) {
      int wz = pos % 10; int r = pos / 10; int hz = r % 10; int dz = r / 10;
      int D = D0 - 1 + dz, H = H0 - 1 + hz, W = W0 - 1 + wz;
      float val = 0.f;
      if ((unsigned)D < 64u && (unsigned)H < 64u && (unsigned)W < 64u) {
        int vidx = ((D >> 1) - cbD) * 36 + ((H >> 1) - cbH) * 6 + ((W >> 1) - cbW);
        float4 qa = *reinterpret_cast<const float4*>(&qks[pos][0]);
        float4 qb = *reinterpret_cast<const float4*>(&qks[pos][4]);
        float4 va = *reinterpret_cast<const float4*>(&vs[vidx][0]);
        float4 vb = *reinterpret_cast<const float4*>(&vs[vidx][4]);
        val = qa.x * va.x;
        val = fmaf(qa.y, va.y, val);
        val = fmaf(qa.z, va.z, val);
        val = fmaf(qa.w, va.w, val);
        val = fmaf(qb.x, vb.x, val);
        val = fmaf(qb.y, vb.y, val);
        val = fmaf(qb.z, vb.z, val);
        val = fmaf(qb.w, vb.w, val);
      }
      qkvs[pos] = val;
    }
    __syncthreads();
#pragma unroll
    for (int rep = 0; rep < 2; ++rep) {
      int o = t + rep * 256;
      int wz = o & 7, hz = (o >> 3) & 7, dz = o >> 6;
      float sum = 0.f;
#pragma unroll
      for (int a = 0; a < 3; ++a)
#pragma unroll
        for (int b = 0; b < 3; ++b)
#pragma unroll
          for (int cc = 0; cc < 3; ++cc)
            sum += qkvs[(dz + a) * 100 + (hz + b) * 10 + (wz + cc)];
      out[(size_t)c * 262144 + (D0 + dz) * 4096 + (H0 + hz) * 64 + (W0 + wz)] =
          sum * (1.f / 27.f);
    }
  }
}

// ---------------------------------------------------------------------------
extern "C" void kernel_launch(void* const* d_in, const int* in_sizes, int n_in,
                              void* d_out, int out_size, void* d_ws, size_t ws_size,
                              hipStream_t stream)
{
  (void)in_sizes; (void)n_in; (void)out_size; (void)ws_size;
  const float* x   = (const float*)d_in[0];
  const float* q1w = (const float*)d_in[1];
  const float* q1b = (const float*)d_in[2];
  const float* q2w = (const float*)d_in[3];
  const float* q2b = (const float*)d_in[4];
  const float* k1w = (const float*)d_in[5];
  const float* k1b = (const float*)d_in[6];
  const float* k2w = (const float*)d_in[7];
  const float* k2b = (const float*)d_in[8];
  const float* vw  = (const float*)d_in[9];
  const float* vb  = (const float*)d_in[10];
  float* out = (float*)d_out;

  float* p = (float*)d_ws;
  float* vraw  = p; p += (size_t)512 * VOX;       // 64 MiB
  float* qraw1 = p; p += (size_t)16 * VOX;
  float* qraw2 = p; p += (size_t)64 * VOX;        // 8 MiB (Wf aliased here? no)
  float* kraw1 = p; p += (size_t)16 * VOX;
  float* kraw2 = p; p += (size_t)8 * VOX;
  float* qkbuf = p; p += (size_t)8 * 262144;      // 8 MiB; xT aliased here
  float* part_v  = p; p += (size_t)512 * 512 * 2; // 2 MiB
  float* part_q1 = p; p += 128 * 16 * 2;
  float* part_q2 = p; p += 128 * 64 * 2;
  float* part_k1 = p; p += 128 * 16 * 2;
  float* part_k2 = p; p += 128 * 8 * 2;
  float* np_q1 = p; p += 2 * 16;
  float* np_q2 = p; p += 2 * 64;
  float* np_k1 = p; p += 2 * 16;
  float* np_k2 = p; p += 2 * 8;
  float* np_v  = p; p += 2 * 512;

  // aliases (dead ranges during conv_v): xT in qkbuf (8 MiB exactly),
  // Wf in qraw2 (1 MiB of 8 MiB). qk_box/q2-conv write these only AFTER
  // conv_v_mfma completes (stream-ordered).
  ushort* xT_hi = (ushort*)qkbuf;                       // 4 MiB
  ushort* xT_lo = (ushort*)qkbuf + (size_t)32768 * 64;  // 4 MiB
  ushort* Wf_hi = (ushort*)qraw2;                       // 512 KiB
  ushort* Wf_lo = (ushort*)qraw2 + (size_t)262144;      // 512 KiB

  dim3 blk(256);
  // v branch via MFMA (runs first so aliased regions are free)
  wprep_kernel<<<128, blk, 0, stream>>>(vw, Wf_hi, Wf_lo);
  xprep_kernel<<<512, blk, 0, stream>>>(x, xT_hi, xT_lo);
  conv_v_mfma<<<dim3(2, 256), blk, 0, stream>>>(
      xT_hi, xT_lo, Wf_hi, Wf_lo, vb, vraw, part_v);
  finalize_kernel<<<8, 64, 0, stream>>>(part_v, 512, 512, np_v);

  // q / k branches (overwrite qraw2 etc. after conv_v done)
  conv_small_kernel<64, false><<<dim3(2, 128), blk, 0, stream>>>(
      x, nullptr, q1w, q1b, qraw1, part_q1, 16);
  finalize_kernel<<<1, 64, 0, stream>>>(part_q1, 16, 128, np_q1);
  conv_small_kernel<16, true><<<dim3(8, 128), blk, 0, stream>>>(
      qraw1, np_q1, q2w, q2b, qraw2, part_q2, 64);
  finalize_kernel<<<1, 64, 0, stream>>>(part_q2, 64, 128, np_q2);
  conv_small_kernel<64, false><<<dim3(2, 128), blk, 0, stream>>>(
      x, nullptr, k1w, k1b, kraw1, part_k1, 16);
  finalize_kernel<<<1, 64, 0, stream>>>(part_k1, 16, 128, np_k1);
  conv_small_kernel<16, true><<<dim3(1, 128), blk, 0, stream>>>(
      kraw1, np_k1, k2w, k2b, kraw2, part_k2, 8);
  finalize_kernel<<<1, 64, 0, stream>>>(part_k2, 8, 128, np_k2);

  qk_box_kernel<<<dim3(512, 8), blk, 0, stream>>>(
      qraw2, np_q2, kraw2, np_k2, qkbuf);
  einsum_box_kernel<<<dim3(512, 2), blk, 0, stream>>>(
      vraw, np_v, qkbuf, out);
}

// Round 5
// 629.584 us; speedup vs baseline: 2.7053x; 1.4195x over previous
//
#include <hip/hip_runtime.h>
#include <hip/hip_bf16.h>

// QKV upsampling pipeline.
// R5: einsum_box rewritten: qk in registers (loaded once/block), vs
// XOR-swizzled 16B chunks (kills 16-way conflicts), separable box via wsum.
// conv_small gets register-prefetch software pipeline. Rest unchanged from R4.

constexpr int VOX = 32 * 32 * 32;
constexpr float INV_VOX = 1.0f / 32768.0f;
constexpr float EPSF = 1e-5f;

typedef __attribute__((ext_vector_type(8))) short s16x8;
typedef __attribute__((ext_vector_type(4))) float f32x4;

static __device__ __forceinline__ ushort bf16_bits(float v) {
  __hip_bfloat16 h = __float2bfloat16(v);
  return *reinterpret_cast<ushort*>(&h);
}

// ---------------------------------------------------------------------------
// Weight prepack: vw fp32 [512][64][8] -> Wf hi/lo bf16, fragment order.
// ---------------------------------------------------------------------------
__global__ void wprep_kernel(const float* __restrict__ vw,
                             ushort* __restrict__ wh, ushort* __restrict__ wl)
{
  int tid = blockIdx.x * 256 + threadIdx.x;
  if (tid >= 32768) return;
  int oc = tid & 511;
  int g = (tid >> 9) & 3;
  int khalf = (tid >> 11) & 1;
  int tap = tid >> 12;
  uint h[4], l[4];
#pragma unroll
  for (int p = 0; p < 4; ++p) {
    int ci0 = khalf * 32 + g * 8 + 2 * p;
    float v0 = vw[oc * 512 + ci0 * 8 + tap];
    float v1 = vw[oc * 512 + (ci0 + 1) * 8 + tap];
    ushort h0 = bf16_bits(v0), h1 = bf16_bits(v1);
    float r0 = v0 - __bfloat162float(*reinterpret_cast<__hip_bfloat16*>(&h0));
    float r1 = v1 - __bfloat162float(*reinterpret_cast<__hip_bfloat16*>(&h1));
    h[p] = (uint)h0 | ((uint)h1 << 16);
    l[p] = (uint)bf16_bits(r0) | ((uint)bf16_bits(r1) << 16);
  }
  size_t base = (size_t)tid * 8;
  *reinterpret_cast<uint4*>(wh + base) = make_uint4(h[0], h[1], h[2], h[3]);
  *reinterpret_cast<uint4*>(wl + base) = make_uint4(l[0], l[1], l[2], l[3]);
}

// ---------------------------------------------------------------------------
// x transpose: x fp32 [64][32768] -> xT hi/lo bf16 [32768][64].
// ---------------------------------------------------------------------------
__global__ __launch_bounds__(256) void xprep_kernel(
    const float* __restrict__ x, ushort* __restrict__ xh, ushort* __restrict__ xl)
{
  __shared__ float ts[64][65];
  const int t = threadIdx.x;
  const int vox0 = blockIdx.x * 64;
#pragma unroll
  for (int i = 0; i < 16; ++i) {
    int e = i * 256 + t;
    int ci = e >> 6, vl = e & 63;
    ts[ci][vl] = x[(size_t)ci * VOX + vox0 + vl];
  }
  __syncthreads();
  const int vl = t >> 2, cig = t & 3;
  uint h[8], l[8];
#pragma unroll
  for (int p = 0; p < 8; ++p) {
    float v0 = ts[cig * 16 + 2 * p][vl];
    float v1 = ts[cig * 16 + 2 * p + 1][vl];
    ushort h0 = bf16_bits(v0), h1 = bf16_bits(v1);
    float r0 = v0 - __bfloat162float(*reinterpret_cast<__hip_bfloat16*>(&h0));
    float r1 = v1 - __bfloat162float(*reinterpret_cast<__hip_bfloat16*>(&h1));
    h[p] = (uint)h0 | ((uint)h1 << 16);
    l[p] = (uint)bf16_bits(r0) | ((uint)bf16_bits(r1) << 16);
  }
  size_t base = (size_t)(vox0 + vl) * 64 + cig * 16;
  *reinterpret_cast<uint4*>(xh + base)     = make_uint4(h[0], h[1], h[2], h[3]);
  *reinterpret_cast<uint4*>(xh + base + 8) = make_uint4(h[4], h[5], h[6], h[7]);
  *reinterpret_cast<uint4*>(xl + base)     = make_uint4(l[0], l[1], l[2], l[3]);
  *reinterpret_cast<uint4*>(xl + base + 8) = make_uint4(l[4], l[5], l[6], l[7]);
}

// ---------------------------------------------------------------------------
// MFMA v-conv (unchanged from R4).
// ---------------------------------------------------------------------------
__global__ __launch_bounds__(256) void conv_v_mfma(
    const ushort* __restrict__ xh, const ushort* __restrict__ xl,
    const ushort* __restrict__ wh, const ushort* __restrict__ wl,
    const float* __restrict__ bias, float* __restrict__ y,
    float* __restrict__ part)
{
  __shared__ ushort Bs[2 * 255 * 64];

  const int t = threadIdx.x;
  const int wave = t >> 6, lane = t & 63;
  const int wm = wave >> 1, wn = wave & 1;
  const int g = lane >> 4, ww = lane & 15;
  const int m0 = blockIdx.x * 256;
  const int nt = blockIdx.y;
  const int td = nt >> 4, th = (nt >> 1) & 7, tw = nt & 1;
  const int d0 = td * 2, h0 = th * 4, w0 = tw * 16;

  for (int i = 0; i < 16; ++i) {
    int c = i * 256 + t;
    if (c < 4080) {
      int split = (c >= 2040) ? 1 : 0;
      int c2 = c - split * 2040;
      int pos = c2 >> 3, cig = c2 & 7;
      int dz = pos / 85, rem = pos - dz * 85;
      int hz = rem / 17, wz = rem - hz * 17;
      int d = d0 + dz, h = h0 + hz, w = w0 + wz;
      uint4 val = make_uint4(0, 0, 0, 0);
      if (d < 32 && h < 32 && w < 32) {
        const ushort* src = split ? xl : xh;
        val = *reinterpret_cast<const uint4*>(
            src + (size_t)(d * 1024 + h * 32 + w) * 64 + cig * 8);
      }
      int addr = (pos << 7) + cig * 16;
      addr ^= (pos & 7) << 4;
      *reinterpret_cast<uint4*>(
          reinterpret_cast<char*>(Bs) + split * 32640 + addr) = val;
    }
  }
  __syncthreads();

  const int ocl = m0 + wm * 128 + ww;
  f32x4 acc[8][4];
#pragma unroll
  for (int mf = 0; mf < 8; ++mf)
#pragma unroll
    for (int hh = 0; hh < 4; ++hh) acc[mf][hh] = (f32x4){0.f, 0.f, 0.f, 0.f};

  for (int tap = 0; tap < 8; ++tap) {
    const int kd = tap >> 2, kh = (tap >> 1) & 1, kw = tap & 1;
#pragma unroll
    for (int khalf = 0; khalf < 2; ++khalf) {
      const size_t abase = ((size_t)((tap * 2 + khalf) * 4 + g) * 512 + ocl) * 8;
      s16x8 Ah[8], Al[8];
#pragma unroll
      for (int mf = 0; mf < 8; ++mf) {
        Ah[mf] = *reinterpret_cast<const s16x8*>(wh + abase + mf * 128);
        Al[mf] = *reinterpret_cast<const s16x8*>(wl + abase + mf * 128);
      }
      const int srow = ((wn + kd) * 5 + kh) * 17 + kw;
#pragma unroll
      for (int hh = 0; hh < 4; ++hh) {
        int pos = srow + hh * 17 + ww;
        int baddr = (pos << 7) + khalf * 64 + g * 16;
        baddr ^= (pos & 7) << 4;
        const char* bp = reinterpret_cast<const char*>(Bs) + baddr;
        s16x8 Bh = *reinterpret_cast<const s16x8*>(bp);
        s16x8 Bl = *reinterpret_cast<const s16x8*>(bp + 32640);
#pragma unroll
        for (int mf = 0; mf < 8; ++mf) {
          acc[mf][hh] = __builtin_amdgcn_mfma_f32_16x16x32_bf16(
              Ah[mf], Bh, acc[mf][hh], 0, 0, 0);
          acc[mf][hh] = __builtin_amdgcn_mfma_f32_16x16x32_bf16(
              Al[mf], Bh, acc[mf][hh], 0, 0, 0);
          acc[mf][hh] = __builtin_amdgcn_mfma_f32_16x16x32_bf16(
              Ah[mf], Bl, acc[mf][hh], 0, 0, 0);
        }
      }
    }
  }

  float bs[8][4];
#pragma unroll
  for (int mf = 0; mf < 8; ++mf)
#pragma unroll
    for (int reg = 0; reg < 4; ++reg)
      bs[mf][reg] = bias[m0 + wm * 128 + mf * 16 + g * 4 + reg];

  float ssum[8][4], ssq[8][4];
#pragma unroll
  for (int mf = 0; mf < 8; ++mf)
#pragma unroll
    for (int reg = 0; reg < 4; ++reg) { ssum[mf][reg] = 0.f; ssq[mf][reg] = 0.f; }

#pragma unroll
  for (int mf = 0; mf < 8; ++mf) {
#pragma unroll
    for (int hh = 0; hh < 4; ++hh) {
      int vox = (d0 + wn) * 1024 + (h0 + hh) * 32 + w0 + ww;
#pragma unroll
      for (int reg = 0; reg < 4; ++reg) {
        float v = acc[mf][hh][reg] + bs[mf][reg];
        int oc = m0 + wm * 128 + mf * 16 + g * 4 + reg;
        y[(size_t)oc * VOX + vox] = v;
        ssum[mf][reg] += v;
        ssq[mf][reg] += v * v;
      }
    }
  }
#pragma unroll
  for (int mf = 0; mf < 8; ++mf)
#pragma unroll
    for (int reg = 0; reg < 4; ++reg)
#pragma unroll
      for (int off = 1; off < 16; off <<= 1) {
        ssum[mf][reg] += __shfl_xor(ssum[mf][reg], off);
        ssq[mf][reg]  += __shfl_xor(ssq[mf][reg], off);
      }
  if ((lane & 15) == 0) {
    float* pp = part + (size_t)(nt * 2 + wn) * 1024;
#pragma unroll
    for (int mf = 0; mf < 8; ++mf)
#pragma unroll
      for (int reg = 0; reg < 4; ++reg) {
        int oc = m0 + wm * 128 + mf * 16 + g * 4 + reg;
        pp[oc * 2]     = ssum[mf][reg];
        pp[oc * 2 + 1] = ssq[mf][reg];
      }
  }
}

// ---------------------------------------------------------------------------
// Small conv with register-prefetch pipeline: tile 1x8x32, OCT=8.
// ---------------------------------------------------------------------------
template <int CIN, bool NORM_IN>
__global__ __launch_bounds__(256) void conv_small_kernel(
    const float* __restrict__ x, const float* __restrict__ npar,
    const float* __restrict__ w, const float* __restrict__ bias,
    float* __restrict__ y, float* __restrict__ part, int COUT)
{
  constexpr int OCT = 8;
  __shared__ float xs[2 * 9 * 33];
  __shared__ float wlds[OCT * CIN * 8];
  __shared__ float redsm[4][OCT][2];

  const int t = threadIdx.x;
  const int oc0 = blockIdx.x * OCT;
  const int ty = blockIdx.y;
  const int d0 = ty & 31;
  const int h0 = (ty >> 5) * 8;
  const int hh = t >> 5;
  const int ww = t & 31;

  for (int f = t; f < OCT * CIN * 8; f += 256)
    wlds[f] = w[(size_t)oc0 * CIN * 8 + f];

  float acc[OCT];
#pragma unroll
  for (int o = 0; o < OCT; ++o) acc[o] = 0.f;

  float pre[3];
  auto fetch = [&](int ci) {
    float m = 0.f, rs = 1.f;
    if constexpr (NORM_IN) { m = npar[2 * ci]; rs = npar[2 * ci + 1]; }
#pragma unroll
    for (int k = 0; k < 3; ++k) {
      int f = t + k * 256;
      float v = 0.f;
      if (f < 594) {
        int wz = f % 33; int r = f / 33; int hz = r % 9; int dz = r / 9;
        int d = d0 + dz, h = h0 + hz;
        if (d < 32 && h < 32 && wz < 32) {
          v = x[(size_t)ci * VOX + d * 1024 + h * 32 + wz];
          if constexpr (NORM_IN) v = fmaxf((v - m) * rs, 0.f);
        }
      }
      pre[k] = v;
    }
  };

  fetch(0);
  for (int ci = 0; ci < CIN; ++ci) {
    __syncthreads();                 // prev compute done; xs free
#pragma unroll
    for (int k = 0; k < 3; ++k) {
      int f = t + k * 256;
      if (f < 594) xs[f] = pre[k];
    }
    if (ci + 1 < CIN) fetch(ci + 1); // overlaps with this ci's compute
    __syncthreads();

    float xr[2][2][2];
#pragma unroll
    for (int a = 0; a < 2; ++a)
#pragma unroll
      for (int b = 0; b < 2; ++b)
#pragma unroll
        for (int c = 0; c < 2; ++c)
          xr[a][b][c] = xs[(a * 9 + hh + b) * 33 + ww + c];

#pragma unroll
    for (int o = 0; o < OCT; ++o) {
      const float* wp = &wlds[(o * CIN + ci) * 8];
      float a = acc[o];
#pragma unroll
      for (int kd = 0; kd < 2; ++kd)
#pragma unroll
        for (int kh = 0; kh < 2; ++kh)
#pragma unroll
          for (int kw = 0; kw < 2; ++kw)
            a = fmaf(wp[kd * 4 + kh * 2 + kw], xr[kd][kh][kw], a);
      acc[o] = a;
    }
  }

  const int lane = t & 63, wave = t >> 6;
#pragma unroll
  for (int o = 0; o < OCT; ++o) {
    float v0 = acc[o] + bias[oc0 + o];
    y[(size_t)(oc0 + o) * VOX + d0 * 1024 + (h0 + hh) * 32 + ww] = v0;
    float s = v0, ss = v0 * v0;
#pragma unroll
    for (int off = 32; off; off >>= 1) {
      s  += __shfl_down(s, off);
      ss += __shfl_down(ss, off);
    }
    if (lane == 0) { redsm[wave][o][0] = s; redsm[wave][o][1] = ss; }
  }
  __syncthreads();
  if (t < OCT) {
    float s  = redsm[0][t][0] + redsm[1][t][0] + redsm[2][t][0] + redsm[3][t][0];
    float ss = redsm[0][t][1] + redsm[1][t][1] + redsm[2][t][1] + redsm[3][t][1];
    part[((size_t)ty * COUT + oc0 + t) * 2]     = s;
    part[((size_t)ty * COUT + oc0 + t) * 2 + 1] = ss;
  }
}

// ---------------------------------------------------------------------------
__global__ void finalize_kernel(const float* __restrict__ part, int C, int NT,
                                float* __restrict__ np)
{
  int c = blockIdx.x * 64 + threadIdx.x;
  if (c >= C) return;
  float s = 0.f, ss = 0.f;
  for (int tile = 0; tile < NT; ++tile) {
    s  += part[((size_t)tile * C + c) * 2];
    ss += part[((size_t)tile * C + c) * 2 + 1];
  }
  float m = s * INV_VOX;
  float var = ss * INV_VOX - m * m;
  np[2 * c]     = m;
  np[2 * c + 1] = rsqrtf(var + EPSF);
}

// ---------------------------------------------------------------------------
__global__ __launch_bounds__(256) void qk_box_kernel(
    const float* __restrict__ qraw, const float* __restrict__ npq,
    const float* __restrict__ kraw, const float* __restrict__ npk,
    float* __restrict__ qkout)
{
  __shared__ float s[1000];
  const int j = blockIdx.y;
  const int tile = blockIdx.x;
  const int W0 = (tile & 7) * 8, H0 = ((tile >> 3) & 7) * 8, D0 = (tile >> 6) * 8;
  const int t = threadIdx.x;

  for (int f = t; f < 1000; f += 256) {
    int wz = f % 10; int r = f / 10; int hz = r % 10; int dz = r / 10;
    int D = D0 - 1 + dz, H = H0 - 1 + hz, W = W0 - 1 + wz;
    float val = 0.f;
    if ((unsigned)D < 64u && (unsigned)H < 64u && (unsigned)W < 64u) {
      int par = (D & 1) * 4 + (H & 1) * 2 + (W & 1);
      int cidx = (D >> 1) * 1024 + (H >> 1) * 32 + (W >> 1);
      float qv = qraw[(size_t)(j * 8 + par) * VOX + cidx];
      qv = fmaxf((qv - npq[2 * (j * 8 + par)]) * npq[2 * (j * 8 + par) + 1], 0.f);
      float kv = kraw[(size_t)par * VOX + cidx];
      kv = fmaxf((kv - npk[2 * par]) * npk[2 * par + 1], 0.f);
      val = qv * kv;
    }
    s[f] = val;
  }
  __syncthreads();
#pragma unroll
  for (int rep = 0; rep < 2; ++rep) {
    int o = t + rep * 256;
    int wz = o & 7, hz = (o >> 3) & 7, dz = o >> 6;
    float sum = 0.f;
#pragma unroll
    for (int a = 0; a < 3; ++a)
#pragma unroll
      for (int b = 0; b < 3; ++b)
#pragma unroll
        for (int c = 0; c < 3; ++c)
          sum += s[(dz + a) * 100 + (hz + b) * 10 + (wz + c)];
    qkout[(size_t)j * 262144 + (D0 + dz) * 4096 + (H0 + hz) * 64 + (W0 + wz)] =
        sum * (1.f / 27.f);
  }
}

// ---------------------------------------------------------------------------
// einsum_box v3: qk in registers (once/block), vs XOR-swizzled, separable box.
// grid = (512 tiles, 2 cgroups), block 256.
// ---------------------------------------------------------------------------
__global__ __launch_bounds__(256) void einsum_box_kernel(
    const float* __restrict__ vraw, const float* __restrict__ npv,
    const float* __restrict__ qk, float* __restrict__ out)
{
  __shared__ char vs_raw[6912];    // swizzled [216 idx][8 j] floats
  __shared__ float qkvs[1000];
  __shared__ float wsum[800];      // [dz 10][hz 10][wz 8]

  const int tile = blockIdx.x;
  const int c0 = blockIdx.y * 32;
  const int W0 = (tile & 7) * 8, H0 = ((tile >> 3) & 7) * 8, D0 = (tile >> 6) * 8;
  const int t = threadIdx.x;
  const int cbD = (D0 >> 1) - 1, cbH = (H0 >> 1) - 1, cbW = (W0 >> 1) - 1;

  // per-thread geometry + qk -> registers (reused for all 32 channels)
  int vbyte[4];
  float qr[4][8];
#pragma unroll
  for (int i = 0; i < 4; ++i) {
    int pos = t + i * 256;
    vbyte[i] = 0;
#pragma unroll
    for (int j = 0; j < 8; ++j) qr[i][j] = 0.f;
    if (pos < 1000) {
      int dz = pos / 100, rem = pos - dz * 100, hz = rem / 10, wz = rem - hz * 10;
      int D = D0 - 1 + dz, H = H0 - 1 + hz, W = W0 - 1 + wz;
      if ((unsigned)D < 64u && (unsigned)H < 64u && (unsigned)W < 64u) {
        int fidx = D * 4096 + H * 64 + W;
#pragma unroll
        for (int j = 0; j < 8; ++j)
          qr[i][j] = qk[(size_t)j * 262144 + fidx];
        int vidx = ((D >> 1) - cbD) * 36 + ((H >> 1) - cbH) * 6 + ((W >> 1) - cbW);
        vbyte[i] = (vidx * 32) ^ (((vidx >> 2) & 7) << 4);
      }
    }
  }

  for (int ci = 0; ci < 32; ++ci) {
    const int c = c0 + ci;
    const int chb = c * 8;
    float mj[8], rj[8];
#pragma unroll
    for (int j = 0; j < 8; ++j) {
      mj[j] = npv[2 * (chb + j)];
      rj[j] = npv[2 * (chb + j) + 1];
    }
    __syncthreads();   // prior iteration's consumers done; vs/qkvs/wsum free
    // stage normalized coarse v (swizzled)
    for (int f = t; f < 1728; f += 256) {
      int j = f / 216, idx = f - j * 216;
      int dz = idx / 36, r2 = idx - dz * 36, hz = r2 / 6, wz = r2 - hz * 6;
      int cD = cbD + dz, cH = cbH + hz, cW = cbW + wz;
      float v = 0.f;
      if ((unsigned)cD < 32u && (unsigned)cH < 32u && (unsigned)cW < 32u) {
        float raw = vraw[(size_t)(chb + j) * VOX + cD * 1024 + cH * 32 + cW];
        v = fmaxf((raw - mj[j]) * rj[j], 0.f);
      }
      int byte = idx * 32 + (j >> 2) * 16 + (j & 3) * 4;
      byte ^= ((idx >> 2) & 7) << 4;
      *reinterpret_cast<float*>(vs_raw + byte) = v;
    }
    __syncthreads();
    // qkv halo values (qk from registers, v from swizzled LDS)
#pragma unroll
    for (int i = 0; i < 4; ++i) {
      int pos = t + i * 256;
      if (pos < 1000) {
        float4 va = *reinterpret_cast<const float4*>(vs_raw + vbyte[i]);
        float4 vb = *reinterpret_cast<const float4*>(vs_raw + (vbyte[i] ^ 16));
        float val = qr[i][0] * va.x;
        val = fmaf(qr[i][1], va.y, val);
        val = fmaf(qr[i][2], va.z, val);
        val = fmaf(qr[i][3], va.w, val);
        val = fmaf(qr[i][4], vb.x, val);
        val = fmaf(qr[i][5], vb.y, val);
        val = fmaf(qr[i][6], vb.z, val);
        val = fmaf(qr[i][7], vb.w, val);
        qkvs[pos] = val;
      }
    }
    __syncthreads();
    // separable box: W-pass
#pragma unroll
    for (int i = 0; i < 4; ++i) {
      int e = t + i * 256;
      if (e < 800) {
        int dz = e / 80, r2 = e - dz * 80, hz = r2 >> 3, wz1 = r2 & 7;
        int base = dz * 100 + hz * 10 + wz1;
        wsum[e] = qkvs[base] + qkvs[base + 1] + qkvs[base + 2];
      }
    }
    __syncthreads();
    // H+D gather (9 taps) + store
#pragma unroll
    for (int rep = 0; rep < 2; ++rep) {
      int o = t + rep * 256;
      int wz = o & 7, hz = (o >> 3) & 7, dz = o >> 6;
      float sum = 0.f;
#pragma unroll
      for (int a = 0; a < 3; ++a)
#pragma unroll
        for (int b = 0; b < 3; ++b)
          sum += wsum[(dz + a) * 80 + (hz + b) * 8 + wz];
      out[(size_t)c * 262144 + (D0 + dz) * 4096 + (H0 + hz) * 64 + (W0 + wz)] =
          sum * (1.f / 27.f);
    }
  }
}

// ---------------------------------------------------------------------------
extern "C" void kernel_launch(void* const* d_in, const int* in_sizes, int n_in,
                              void* d_out, int out_size, void* d_ws, size_t ws_size,
                              hipStream_t stream)
{
  (void)in_sizes; (void)n_in; (void)out_size; (void)ws_size;
  const float* x   = (const float*)d_in[0];
  const float* q1w = (const float*)d_in[1];
  const float* q1b = (const float*)d_in[2];
  const float* q2w = (const float*)d_in[3];
  const float* q2b = (const float*)d_in[4];
  const float* k1w = (const float*)d_in[5];
  const float* k1b = (const float*)d_in[6];
  const float* k2w = (const float*)d_in[7];
  const float* k2b = (const float*)d_in[8];
  const float* vw  = (const float*)d_in[9];
  const float* vb  = (const float*)d_in[10];
  float* out = (float*)d_out;

  float* p = (float*)d_ws;
  float* vraw  = p; p += (size_t)512 * VOX;
  float* qraw1 = p; p += (size_t)16 * VOX;
  float* qraw2 = p; p += (size_t)64 * VOX;
  float* kraw1 = p; p += (size_t)16 * VOX;
  float* kraw2 = p; p += (size_t)8 * VOX;
  float* qkbuf = p; p += (size_t)8 * 262144;
  float* part_v  = p; p += (size_t)512 * 512 * 2;
  float* part_q1 = p; p += 128 * 16 * 2;
  float* part_q2 = p; p += 128 * 64 * 2;
  float* part_k1 = p; p += 128 * 16 * 2;
  float* part_k2 = p; p += 128 * 8 * 2;
  float* np_q1 = p; p += 2 * 16;
  float* np_q2 = p; p += 2 * 64;
  float* np_k1 = p; p += 2 * 16;
  float* np_k2 = p; p += 2 * 8;
  float* np_v  = p; p += 2 * 512;

  // aliases (dead during conv_v): xT in qkbuf, Wf in qraw2.
  ushort* xT_hi = (ushort*)qkbuf;
  ushort* xT_lo = (ushort*)qkbuf + (size_t)32768 * 64;
  ushort* Wf_hi = (ushort*)qraw2;
  ushort* Wf_lo = (ushort*)qraw2 + (size_t)262144;

  dim3 blk(256);
  wprep_kernel<<<128, blk, 0, stream>>>(vw, Wf_hi, Wf_lo);
  xprep_kernel<<<512, blk, 0, stream>>>(x, xT_hi, xT_lo);
  conv_v_mfma<<<dim3(2, 256), blk, 0, stream>>>(
      xT_hi, xT_lo, Wf_hi, Wf_lo, vb, vraw, part_v);
  finalize_kernel<<<8, 64, 0, stream>>>(part_v, 512, 512, np_v);

  conv_small_kernel<64, false><<<dim3(2, 128), blk, 0, stream>>>(
      x, nullptr, q1w, q1b, qraw1, part_q1, 16);
  finalize_kernel<<<1, 64, 0, stream>>>(part_q1, 16, 128, np_q1);
  conv_small_kernel<16, true><<<dim3(8, 128), blk, 0, stream>>>(
      qraw1, np_q1, q2w, q2b, qraw2, part_q2, 64);
  finalize_kernel<<<1, 64, 0, stream>>>(part_q2, 64, 128, np_q2);
  conv_small_kernel<64, false><<<dim3(2, 128), blk, 0, stream>>>(
      x, nullptr, k1w, k1b, kraw1, part_k1, 16);
  finalize_kernel<<<1, 64, 0, stream>>>(part_k1, 16, 128, np_k1);
  conv_small_kernel<16, true><<<dim3(1, 128), blk, 0, stream>>>(
      kraw1, np_k1, k2w, k2b, kraw2, part_k2, 8);
  finalize_kernel<<<1, 64, 0, stream>>>(part_k2, 8, 128, np_k2);

  qk_box_kernel<<<dim3(512, 8), blk, 0, stream>>>(
      qraw2, np_q2, kraw2, np_k2, qkbuf);
  einsum_box_kernel<<<dim3(512, 2), blk, 0, stream>>>(
      vraw, np_v, qkbuf, out);
}

// Round 6
// 463.766 us; speedup vs baseline: 3.6726x; 1.3575x over previous
//
#include <hip/hip_runtime.h>
#include <hip/hip_bf16.h>

// QKV upsampling pipeline.
// R6: einsum v4 (all addressing precomputed outside ci-loop; no runtime-
// indexed arrays -> no scratch; per-slot float2 norm params), qk_box separable
// box, q1+k1 and q2+k2 fused launches, merged finalizes.

constexpr int VOX = 32 * 32 * 32;
constexpr float INV_VOX = 1.0f / 32768.0f;
constexpr float EPSF = 1e-5f;

typedef __attribute__((ext_vector_type(8))) short s16x8;
typedef __attribute__((ext_vector_type(4))) float f32x4;

static __device__ __forceinline__ ushort bf16_bits(float v) {
  __hip_bfloat16 h = __float2bfloat16(v);
  return *reinterpret_cast<ushort*>(&h);
}

// ---------------------------------------------------------------------------
// Weight prepack (unchanged).
// ---------------------------------------------------------------------------
__global__ void wprep_kernel(const float* __restrict__ vw,
                             ushort* __restrict__ wh, ushort* __restrict__ wl)
{
  int tid = blockIdx.x * 256 + threadIdx.x;
  if (tid >= 32768) return;
  int oc = tid & 511;
  int g = (tid >> 9) & 3;
  int khalf = (tid >> 11) & 1;
  int tap = tid >> 12;
  uint h[4], l[4];
#pragma unroll
  for (int p = 0; p < 4; ++p) {
    int ci0 = khalf * 32 + g * 8 + 2 * p;
    float v0 = vw[oc * 512 + ci0 * 8 + tap];
    float v1 = vw[oc * 512 + (ci0 + 1) * 8 + tap];
    ushort h0 = bf16_bits(v0), h1 = bf16_bits(v1);
    float r0 = v0 - __bfloat162float(*reinterpret_cast<__hip_bfloat16*>(&h0));
    float r1 = v1 - __bfloat162float(*reinterpret_cast<__hip_bfloat16*>(&h1));
    h[p] = (uint)h0 | ((uint)h1 << 16);
    l[p] = (uint)bf16_bits(r0) | ((uint)bf16_bits(r1) << 16);
  }
  size_t base = (size_t)tid * 8;
  *reinterpret_cast<uint4*>(wh + base) = make_uint4(h[0], h[1], h[2], h[3]);
  *reinterpret_cast<uint4*>(wl + base) = make_uint4(l[0], l[1], l[2], l[3]);
}

// ---------------------------------------------------------------------------
// x transpose (unchanged).
// ---------------------------------------------------------------------------
__global__ __launch_bounds__(256) void xprep_kernel(
    const float* __restrict__ x, ushort* __restrict__ xh, ushort* __restrict__ xl)
{
  __shared__ float ts[64][65];
  const int t = threadIdx.x;
  const int vox0 = blockIdx.x * 64;
#pragma unroll
  for (int i = 0; i < 16; ++i) {
    int e = i * 256 + t;
    int ci = e >> 6, vl = e & 63;
    ts[ci][vl] = x[(size_t)ci * VOX + vox0 + vl];
  }
  __syncthreads();
  const int vl = t >> 2, cig = t & 3;
  uint h[8], l[8];
#pragma unroll
  for (int p = 0; p < 8; ++p) {
    float v0 = ts[cig * 16 + 2 * p][vl];
    float v1 = ts[cig * 16 + 2 * p + 1][vl];
    ushort h0 = bf16_bits(v0), h1 = bf16_bits(v1);
    float r0 = v0 - __bfloat162float(*reinterpret_cast<__hip_bfloat16*>(&h0));
    float r1 = v1 - __bfloat162float(*reinterpret_cast<__hip_bfloat16*>(&h1));
    h[p] = (uint)h0 | ((uint)h1 << 16);
    l[p] = (uint)bf16_bits(r0) | ((uint)bf16_bits(r1) << 16);
  }
  size_t base = (size_t)(vox0 + vl) * 64 + cig * 16;
  *reinterpret_cast<uint4*>(xh + base)     = make_uint4(h[0], h[1], h[2], h[3]);
  *reinterpret_cast<uint4*>(xh + base + 8) = make_uint4(h[4], h[5], h[6], h[7]);
  *reinterpret_cast<uint4*>(xl + base)     = make_uint4(l[0], l[1], l[2], l[3]);
  *reinterpret_cast<uint4*>(xl + base + 8) = make_uint4(l[4], l[5], l[6], l[7]);
}

// ---------------------------------------------------------------------------
// MFMA v-conv (unchanged).
// ---------------------------------------------------------------------------
__global__ __launch_bounds__(256) void conv_v_mfma(
    const ushort* __restrict__ xh, const ushort* __restrict__ xl,
    const ushort* __restrict__ wh, const ushort* __restrict__ wl,
    const float* __restrict__ bias, float* __restrict__ y,
    float* __restrict__ part)
{
  __shared__ ushort Bs[2 * 255 * 64];

  const int t = threadIdx.x;
  const int wave = t >> 6, lane = t & 63;
  const int wm = wave >> 1, wn = wave & 1;
  const int g = lane >> 4, ww = lane & 15;
  const int m0 = blockIdx.x * 256;
  const int nt = blockIdx.y;
  const int td = nt >> 4, th = (nt >> 1) & 7, tw = nt & 1;
  const int d0 = td * 2, h0 = th * 4, w0 = tw * 16;

  for (int i = 0; i < 16; ++i) {
    int c = i * 256 + t;
    if (c < 4080) {
      int split = (c >= 2040) ? 1 : 0;
      int c2 = c - split * 2040;
      int pos = c2 >> 3, cig = c2 & 7;
      int dz = pos / 85, rem = pos - dz * 85;
      int hz = rem / 17, wz = rem - hz * 17;
      int d = d0 + dz, h = h0 + hz, w = w0 + wz;
      uint4 val = make_uint4(0, 0, 0, 0);
      if (d < 32 && h < 32 && w < 32) {
        const ushort* src = split ? xl : xh;
        val = *reinterpret_cast<const uint4*>(
            src + (size_t)(d * 1024 + h * 32 + w) * 64 + cig * 8);
      }
      int addr = (pos << 7) + cig * 16;
      addr ^= (pos & 7) << 4;
      *reinterpret_cast<uint4*>(
          reinterpret_cast<char*>(Bs) + split * 32640 + addr) = val;
    }
  }
  __syncthreads();

  const int ocl = m0 + wm * 128 + ww;
  f32x4 acc[8][4];
#pragma unroll
  for (int mf = 0; mf < 8; ++mf)
#pragma unroll
    for (int hh = 0; hh < 4; ++hh) acc[mf][hh] = (f32x4){0.f, 0.f, 0.f, 0.f};

  for (int tap = 0; tap < 8; ++tap) {
    const int kd = tap >> 2, kh = (tap >> 1) & 1, kw = tap & 1;
#pragma unroll
    for (int khalf = 0; khalf < 2; ++khalf) {
      const size_t abase = ((size_t)((tap * 2 + khalf) * 4 + g) * 512 + ocl) * 8;
      s16x8 Ah[8], Al[8];
#pragma unroll
      for (int mf = 0; mf < 8; ++mf) {
        Ah[mf] = *reinterpret_cast<const s16x8*>(wh + abase + mf * 128);
        Al[mf] = *reinterpret_cast<const s16x8*>(wl + abase + mf * 128);
      }
      const int srow = ((wn + kd) * 5 + kh) * 17 + kw;
#pragma unroll
      for (int hh = 0; hh < 4; ++hh) {
        int pos = srow + hh * 17 + ww;
        int baddr = (pos << 7) + khalf * 64 + g * 16;
        baddr ^= (pos & 7) << 4;
        const char* bp = reinterpret_cast<const char*>(Bs) + baddr;
        s16x8 Bh = *reinterpret_cast<const s16x8*>(bp);
        s16x8 Bl = *reinterpret_cast<const s16x8*>(bp + 32640);
#pragma unroll
        for (int mf = 0; mf < 8; ++mf) {
          acc[mf][hh] = __builtin_amdgcn_mfma_f32_16x16x32_bf16(
              Ah[mf], Bh, acc[mf][hh], 0, 0, 0);
          acc[mf][hh] = __builtin_amdgcn_mfma_f32_16x16x32_bf16(
              Al[mf], Bh, acc[mf][hh], 0, 0, 0);
          acc[mf][hh] = __builtin_amdgcn_mfma_f32_16x16x32_bf16(
              Ah[mf], Bl, acc[mf][hh], 0, 0, 0);
        }
      }
    }
  }

  float bs[8][4];
#pragma unroll
  for (int mf = 0; mf < 8; ++mf)
#pragma unroll
    for (int reg = 0; reg < 4; ++reg)
      bs[mf][reg] = bias[m0 + wm * 128 + mf * 16 + g * 4 + reg];

  float ssum[8][4], ssq[8][4];
#pragma unroll
  for (int mf = 0; mf < 8; ++mf)
#pragma unroll
    for (int reg = 0; reg < 4; ++reg) { ssum[mf][reg] = 0.f; ssq[mf][reg] = 0.f; }

#pragma unroll
  for (int mf = 0; mf < 8; ++mf) {
#pragma unroll
    for (int hh = 0; hh < 4; ++hh) {
      int vox = (d0 + wn) * 1024 + (h0 + hh) * 32 + w0 + ww;
#pragma unroll
      for (int reg = 0; reg < 4; ++reg) {
        float v = acc[mf][hh][reg] + bs[mf][reg];
        int oc = m0 + wm * 128 + mf * 16 + g * 4 + reg;
        y[(size_t)oc * VOX + vox] = v;
        ssum[mf][reg] += v;
        ssq[mf][reg] += v * v;
      }
    }
  }
#pragma unroll
  for (int mf = 0; mf < 8; ++mf)
#pragma unroll
    for (int reg = 0; reg < 4; ++reg)
#pragma unroll
      for (int off = 1; off < 16; off <<= 1) {
        ssum[mf][reg] += __shfl_xor(ssum[mf][reg], off);
        ssq[mf][reg]  += __shfl_xor(ssq[mf][reg], off);
      }
  if ((lane & 15) == 0) {
    float* pp = part + (size_t)(nt * 2 + wn) * 1024;
#pragma unroll
    for (int mf = 0; mf < 8; ++mf)
#pragma unroll
      for (int reg = 0; reg < 4; ++reg) {
        int oc = m0 + wm * 128 + mf * 16 + g * 4 + reg;
        pp[oc * 2]     = ssum[mf][reg];
        pp[oc * 2 + 1] = ssq[mf][reg];
      }
  }
}

// ---------------------------------------------------------------------------
// Fused pair of small convs (branch A: blockIdx.x < SPLIT, else branch B).
// Tile 1x8x32, OCT=8, register-prefetch pipeline.
// ---------------------------------------------------------------------------
template <int CIN, bool NORM_IN, int SPLIT>
__global__ __launch_bounds__(256) void conv_small2_kernel(
    const float* __restrict__ xA, const float* __restrict__ npA,
    const float* __restrict__ wA, const float* __restrict__ bA,
    float* __restrict__ yA, float* __restrict__ pA, int CA,
    const float* __restrict__ xB, const float* __restrict__ npB,
    const float* __restrict__ wB, const float* __restrict__ bB,
    float* __restrict__ yB, float* __restrict__ pB, int CB)
{
  constexpr int OCT = 8;
  __shared__ float xs[2 * 9 * 33];
  __shared__ float wlds[OCT * CIN * 8];
  __shared__ float redsm[4][OCT][2];

  const bool isA = (int)blockIdx.x < SPLIT;
  const float* x    = isA ? xA : xB;
  const float* npar = isA ? npA : npB;
  const float* w    = isA ? wA : wB;
  const float* bias = isA ? bA : bB;
  float* y    = isA ? yA : yB;
  float* part = isA ? pA : pB;
  const int COUT = isA ? CA : CB;
  const int bx = isA ? blockIdx.x : blockIdx.x - SPLIT;

  const int t = threadIdx.x;
  const int oc0 = bx * OCT;
  const int ty = blockIdx.y;
  const int d0 = ty & 31;
  const int h0 = (ty >> 5) * 8;
  const int hh = t >> 5;
  const int ww = t & 31;

  for (int f = t; f < OCT * CIN * 8; f += 256)
    wlds[f] = w[(size_t)oc0 * CIN * 8 + f];

  float acc[OCT];
#pragma unroll
  for (int o = 0; o < OCT; ++o) acc[o] = 0.f;

  float pre[3];
  auto fetch = [&](int ci) {
    float m = 0.f, rs = 1.f;
    if constexpr (NORM_IN) { m = npar[2 * ci]; rs = npar[2 * ci + 1]; }
#pragma unroll
    for (int k = 0; k < 3; ++k) {
      int f = t + k * 256;
      float v = 0.f;
      if (f < 594) {
        int wz = f % 33; int r = f / 33; int hz = r % 9; int dz = r / 9;
        int d = d0 + dz, h = h0 + hz;
        if (d < 32 && h < 32 && wz < 32) {
          v = x[(size_t)ci * VOX + d * 1024 + h * 32 + wz];
          if constexpr (NORM_IN) v = fmaxf((v - m) * rs, 0.f);
        }
      }
      pre[k] = v;
    }
  };

  fetch(0);
  for (int ci = 0; ci < CIN; ++ci) {
    __syncthreads();
#pragma unroll
    for (int k = 0; k < 3; ++k) {
      int f = t + k * 256;
      if (f < 594) xs[f] = pre[k];
    }
    if (ci + 1 < CIN) fetch(ci + 1);
    __syncthreads();

    float xr[2][2][2];
#pragma unroll
    for (int a = 0; a < 2; ++a)
#pragma unroll
      for (int b = 0; b < 2; ++b)
#pragma unroll
        for (int c = 0; c < 2; ++c)
          xr[a][b][c] = xs[(a * 9 + hh + b) * 33 + ww + c];

#pragma unroll
    for (int o = 0; o < OCT; ++o) {
      const float* wp = &wlds[(o * CIN + ci) * 8];
      float a = acc[o];
#pragma unroll
      for (int kd = 0; kd < 2; ++kd)
#pragma unroll
        for (int kh = 0; kh < 2; ++kh)
#pragma unroll
          for (int kw = 0; kw < 2; ++kw)
            a = fmaf(wp[kd * 4 + kh * 2 + kw], xr[kd][kh][kw], a);
      acc[o] = a;
    }
  }

  const int lane = t & 63, wave = t >> 6;
#pragma unroll
  for (int o = 0; o < OCT; ++o) {
    float v0 = acc[o] + bias[oc0 + o];
    y[(size_t)(oc0 + o) * VOX + d0 * 1024 + (h0 + hh) * 32 + ww] = v0;
    float s = v0, ss = v0 * v0;
#pragma unroll
    for (int off = 32; off; off >>= 1) {
      s  += __shfl_down(s, off);
      ss += __shfl_down(ss, off);
    }
    if (lane == 0) { redsm[wave][o][0] = s; redsm[wave][o][1] = ss; }
  }
  __syncthreads();
  if (t < OCT) {
    float s  = redsm[0][t][0] + redsm[1][t][0] + redsm[2][t][0] + redsm[3][t][0];
    float ss = redsm[0][t][1] + redsm[1][t][1] + redsm[2][t][1] + redsm[3][t][1];
    part[((size_t)ty * COUT + oc0 + t) * 2]     = s;
    part[((size_t)ty * COUT + oc0 + t) * 2 + 1] = ss;
  }
}

// ---------------------------------------------------------------------------
// Combined finalize for up to 3 (part,C,NT,np) sets.
// ---------------------------------------------------------------------------
__global__ void finalize3_kernel(
    const float* __restrict__ p1, int C1, int NT1, float* __restrict__ n1,
    const float* __restrict__ p2, int C2, int NT2, float* __restrict__ n2,
    const float* __restrict__ p3, int C3, int NT3, float* __restrict__ n3)
{
  int g = blockIdx.x * 64 + threadIdx.x;
  const float* part; float* np; int C, NT, c;
  if (g < C1)                { part = p1; np = n1; C = C1; NT = NT1; c = g; }
  else if (g < C1 + C2)      { part = p2; np = n2; C = C2; NT = NT2; c = g - C1; }
  else if (g < C1 + C2 + C3) { part = p3; np = n3; C = C3; NT = NT3; c = g - C1 - C2; }
  else return;
  float s = 0.f, ss = 0.f;
  for (int tile = 0; tile < NT; ++tile) {
    s  += part[((size_t)tile * C + c) * 2];
    ss += part[((size_t)tile * C + c) * 2 + 1];
  }
  float m = s * INV_VOX;
  float var = ss * INV_VOX - m * m;
  np[2 * c]     = m;
  np[2 * c + 1] = rsqrtf(var + EPSF);
}

// ---------------------------------------------------------------------------
// qk = box3(qn*kn) at fine res, separable box. grid (512, 8).
// ---------------------------------------------------------------------------
__global__ __launch_bounds__(256) void qk_box_kernel(
    const float* __restrict__ qraw, const float* __restrict__ npq,
    const float* __restrict__ kraw, const float* __restrict__ npk,
    float* __restrict__ qkout)
{
  __shared__ float s[1000];
  __shared__ float ws2[800];
  const int j = blockIdx.y;
  const int tile = blockIdx.x;
  const int W0 = (tile & 7) * 8, H0 = ((tile >> 3) & 7) * 8, D0 = (tile >> 6) * 8;
  const int t = threadIdx.x;

  for (int f = t; f < 1000; f += 256) {
    int wz = f % 10; int r = f / 10; int hz = r % 10; int dz = r / 10;
    int D = D0 - 1 + dz, H = H0 - 1 + hz, W = W0 - 1 + wz;
    float val = 0.f;
    if ((unsigned)D < 64u && (unsigned)H < 64u && (unsigned)W < 64u) {
      int par = (D & 1) * 4 + (H & 1) * 2 + (W & 1);
      int cidx = (D >> 1) * 1024 + (H >> 1) * 32 + (W >> 1);
      float qv = qraw[(size_t)(j * 8 + par) * VOX + cidx];
      qv = fmaxf((qv - npq[2 * (j * 8 + par)]) * npq[2 * (j * 8 + par) + 1], 0.f);
      float kv = kraw[(size_t)par * VOX + cidx];
      kv = fmaxf((kv - npk[2 * par]) * npk[2 * par + 1], 0.f);
      val = qv * kv;
    }
    s[f] = val;
  }
  __syncthreads();
#pragma unroll
  for (int i = 0; i < 4; ++i) {
    int e = t + i * 256;
    if (e < 800) {
      int dz = e / 80, r2 = e - dz * 80, hz = r2 >> 3, wz1 = r2 & 7;
      int base = dz * 100 + hz * 10 + wz1;
      ws2[e] = s[base] + s[base + 1] + s[base + 2];
    }
  }
  __syncthreads();
#pragma unroll
  for (int rep = 0; rep < 2; ++rep) {
    int o = t + rep * 256;
    int wz = o & 7, hz = (o >> 3) & 7, dz = o >> 6;
    int wb = dz * 80 + hz * 8 + wz;
    float sum = 0.f;
#pragma unroll
    for (int a = 0; a < 3; ++a)
      sum += ws2[wb + a * 80] + ws2[wb + a * 80 + 8] + ws2[wb + a * 80 + 16];
    qkout[(size_t)j * 262144 + (D0 + dz) * 4096 + (H0 + hz) * 64 + (W0 + wz)] =
        sum * (1.f / 27.f);
  }
}

// ---------------------------------------------------------------------------
// einsum_box v4: all addressing precomputed before the ci loop; qk in regs;
// vs XOR-swizzled; separable box. grid (512, 2), block 256.
// ---------------------------------------------------------------------------
__global__ __launch_bounds__(256) void einsum_box_kernel(
    const float* __restrict__ vraw, const float* __restrict__ npv,
    const float* __restrict__ qk, float* __restrict__ out)
{
  __shared__ char vs_raw[6912];
  __shared__ float qkvs[1000];
  __shared__ float wsum[800];

  const int tile = blockIdx.x;
  const int c0 = blockIdx.y * 32;
  const int W0 = (tile & 7) * 8, H0 = ((tile >> 3) & 7) * 8, D0 = (tile >> 6) * 8;
  const int t = threadIdx.x;
  const int cbD = (D0 >> 1) - 1, cbH = (H0 >> 1) - 1, cbW = (W0 >> 1) - 1;
  const float2* npv2 = reinterpret_cast<const float2*>(npv);

  // ---- stage-slot precompute (k=0..6; slot 6 active only for t<192)
  uint soff[7]; int sbyte[7]; int snidx[7]; bool svalid[7];
#pragma unroll
  for (int k = 0; k < 7; ++k) {
    int f = t + k * 256;
    int j = f / 216, idx = f - j * 216;
    int dz = idx / 36, r2 = idx - dz * 36, hz = r2 / 6, wz = r2 - hz * 6;
    int cD = cbD + dz, cH = cbH + hz, cW = cbW + wz;
    bool vld = (f < 1728) && (unsigned)cD < 32u && (unsigned)cH < 32u &&
               (unsigned)cW < 32u;
    svalid[k] = vld;
    soff[k] = vld ? (uint)((c0 * 8 + j) * VOX + cD * 1024 + cH * 32 + cW) : 0u;
    snidx[k] = (f < 1728) ? (c0 * 8 + j) : 0;
    int byte = idx * 32 + (j >> 2) * 16 + (j & 3) * 4;
    sbyte[k] = byte ^ (((idx >> 2) & 7) << 4);
  }

  // ---- qkv-slot precompute + qk -> registers
  int vbyte[4]; float qr[4][8];
#pragma unroll
  for (int i = 0; i < 4; ++i) {
    int pos = t + i * 256;
    vbyte[i] = 0;
#pragma unroll
    for (int j = 0; j < 8; ++j) qr[i][j] = 0.f;
    if (pos < 1000) {
      int dz = pos / 100, rem = pos - dz * 100, hz = rem / 10, wz = rem - hz * 10;
      int D = D0 - 1 + dz, H = H0 - 1 + hz, W = W0 - 1 + wz;
      if ((unsigned)D < 64u && (unsigned)H < 64u && (unsigned)W < 64u) {
        int fidx = D * 4096 + H * 64 + W;
#pragma unroll
        for (int j = 0; j < 8; ++j)
          qr[i][j] = qk[(size_t)j * 262144 + fidx];
        int vidx = ((D >> 1) - cbD) * 36 + ((H >> 1) - cbH) * 6 + ((W >> 1) - cbW);
        vbyte[i] = (vidx * 32) ^ (((vidx >> 2) & 7) << 4);
      }
    }
  }

  // ---- wsum-slot precompute (i=0..3; slot 3 active only for t<32)
  int wb[4];
#pragma unroll
  for (int i = 0; i < 4; ++i) {
    int e = t + i * 256;
    int dz = e / 80, r2 = e - dz * 80, hz = r2 >> 3, wz1 = r2 & 7;
    wb[i] = dz * 100 + hz * 10 + wz1;
  }

  // ---- out-slot precompute
  int wb2[2]; float* op[2];
#pragma unroll
  for (int rep = 0; rep < 2; ++rep) {
    int o = t + rep * 256;
    int wz = o & 7, hz = (o >> 3) & 7, dz = o >> 6;
    wb2[rep] = dz * 80 + hz * 8 + wz;
    op[rep] = out + (size_t)c0 * 262144 +
              (D0 + dz) * 4096 + (H0 + hz) * 64 + (W0 + wz);
  }

  for (int ci = 0; ci < 32; ++ci) {
    __syncthreads();   // prior iteration's consumers done
    const uint cio = (uint)(ci * 8 * VOX);
    const int cin8 = ci * 8;
    // stage normalized v
#pragma unroll
    for (int k = 0; k < 7; ++k) {
      if (k < 6 || t < 192) {
        float2 mr = npv2[snidx[k] + cin8];
        float raw = vraw[soff[k] + cio];
        float v = svalid[k] ? fmaxf((raw - mr.x) * mr.y, 0.f) : 0.f;
        *reinterpret_cast<float*>(vs_raw + sbyte[k]) = v;
      }
    }
    __syncthreads();
    // qkv halo
#pragma unroll
    for (int i = 0; i < 4; ++i) {
      int pos = t + i * 256;
      if (pos < 1000) {
        float4 va = *reinterpret_cast<const float4*>(vs_raw + vbyte[i]);
        float4 vb = *reinterpret_cast<const float4*>(vs_raw + (vbyte[i] ^ 16));
        float val = qr[i][0] * va.x;
        val = fmaf(qr[i][1], va.y, val);
        val = fmaf(qr[i][2], va.z, val);
        val = fmaf(qr[i][3], va.w, val);
        val = fmaf(qr[i][4], vb.x, val);
        val = fmaf(qr[i][5], vb.y, val);
        val = fmaf(qr[i][6], vb.z, val);
        val = fmaf(qr[i][7], vb.w, val);
        qkvs[pos] = val;
      }
    }
    __syncthreads();
    // W-pass
#pragma unroll
    for (int i = 0; i < 4; ++i) {
      if (i < 3 || t < 32) {
        int b = wb[i];
        wsum[t + i * 256] = qkvs[b] + qkvs[b + 1] + qkvs[b + 2];
      }
    }
    __syncthreads();
    // H+D gather + store
#pragma unroll
    for (int rep = 0; rep < 2; ++rep) {
      float sum = 0.f;
#pragma unroll
      for (int a = 0; a < 3; ++a)
        sum += wsum[wb2[rep] + a * 80] + wsum[wb2[rep] + a * 80 + 8] +
               wsum[wb2[rep] + a * 80 + 16];
      op[rep][(size_t)ci << 18] = sum * (1.f / 27.f);
    }
  }
}

// ---------------------------------------------------------------------------
extern "C" void kernel_launch(void* const* d_in, const int* in_sizes, int n_in,
                              void* d_out, int out_size, void* d_ws, size_t ws_size,
                              hipStream_t stream)
{
  (void)in_sizes; (void)n_in; (void)out_size; (void)ws_size;
  const float* x   = (const float*)d_in[0];
  const float* q1w = (const float*)d_in[1];
  const float* q1b = (const float*)d_in[2];
  const float* q2w = (const float*)d_in[3];
  const float* q2b = (const float*)d_in[4];
  const float* k1w = (const float*)d_in[5];
  const float* k1b = (const float*)d_in[6];
  const float* k2w = (const float*)d_in[7];
  const float* k2b = (const float*)d_in[8];
  const float* vw  = (const float*)d_in[9];
  const float* vb  = (const float*)d_in[10];
  float* out = (float*)d_out;

  float* p = (float*)d_ws;
  float* vraw  = p; p += (size_t)512 * VOX;
  float* qraw1 = p; p += (size_t)16 * VOX;
  float* qraw2 = p; p += (size_t)64 * VOX;
  float* kraw1 = p; p += (size_t)16 * VOX;
  float* kraw2 = p; p += (size_t)8 * VOX;
  float* qkbuf = p; p += (size_t)8 * 262144;
  float* part_v  = p; p += (size_t)512 * 512 * 2;
  float* part_q1 = p; p += 128 * 16 * 2;
  float* part_q2 = p; p += 128 * 64 * 2;
  float* part_k1 = p; p += 128 * 16 * 2;
  float* part_k2 = p; p += 128 * 8 * 2;
  float* np_q1 = p; p += 2 * 16;
  float* np_q2 = p; p += 2 * 64;
  float* np_k1 = p; p += 2 * 16;
  float* np_k2 = p; p += 2 * 8;
  float* np_v  = p; p += 2 * 512;

  // aliases (dead during conv_v): xT in qkbuf, Wf in qraw2.
  ushort* xT_hi = (ushort*)qkbuf;
  ushort* xT_lo = (ushort*)qkbuf + (size_t)32768 * 64;
  ushort* Wf_hi = (ushort*)qraw2;
  ushort* Wf_lo = (ushort*)qraw2 + (size_t)262144;

  dim3 blk(256);
  wprep_kernel<<<128, blk, 0, stream>>>(vw, Wf_hi, Wf_lo);
  xprep_kernel<<<512, blk, 0, stream>>>(x, xT_hi, xT_lo);
  conv_v_mfma<<<dim3(2, 256), blk, 0, stream>>>(
      xT_hi, xT_lo, Wf_hi, Wf_lo, vb, vraw, part_v);

  conv_small2_kernel<64, false, 2><<<dim3(4, 128), blk, 0, stream>>>(
      x, nullptr, q1w, q1b, qraw1, part_q1, 16,
      x, nullptr, k1w, k1b, kraw1, part_k1, 16);
  finalize3_kernel<<<9, 64, 0, stream>>>(
      part_v, 512, 512, np_v,
      part_q1, 16, 128, np_q1,
      part_k1, 16, 128, np_k1);

  conv_small2_kernel<16, true, 8><<<dim3(9, 128), blk, 0, stream>>>(
      qraw1, np_q1, q2w, q2b, qraw2, part_q2, 64,
      kraw1, np_k1, k2w, k2b, kraw2, part_k2, 8);
  finalize3_kernel<<<2, 64, 0, stream>>>(
      part_q2, 64, 128, np_q2,
      part_k2, 8, 128, np_k2,
      nullptr, 0, 0, nullptr);

  qk_box_kernel<<<dim3(512, 8), blk, 0, stream>>>(
      qraw2, np_q2, kraw2, np_k2, qkbuf);
  einsum_box_kernel<<<dim3(512, 2), blk, 0, stream>>>(
      vraw, np_v, qkbuf, out);
}

// Round 7
// 352.276 us; speedup vs baseline: 4.8349x; 1.3165x over previous
//
#include <hip/hip_runtime.h>
#include <hip/hip_bf16.h>

// QKV upsampling pipeline.
// R7: einsum gets T14 async-STAGE (prefetch ci+1 v into regs during compute);
// qk_box v2 stages coarse-order product directly into fine halo (coalesced
// reads, one fewer phase); finalize3 4-way parallel + float2.

constexpr int VOX = 32 * 32 * 32;
constexpr float INV_VOX = 1.0f / 32768.0f;
constexpr float EPSF = 1e-5f;

typedef __attribute__((ext_vector_type(8))) short s16x8;
typedef __attribute__((ext_vector_type(4))) float f32x4;

static __device__ __forceinline__ ushort bf16_bits(float v) {
  __hip_bfloat16 h = __float2bfloat16(v);
  return *reinterpret_cast<ushort*>(&h);
}

// ---------------------------------------------------------------------------
// Weight prepack (unchanged).
// ---------------------------------------------------------------------------
__global__ void wprep_kernel(const float* __restrict__ vw,
                             ushort* __restrict__ wh, ushort* __restrict__ wl)
{
  int tid = blockIdx.x * 256 + threadIdx.x;
  if (tid >= 32768) return;
  int oc = tid & 511;
  int g = (tid >> 9) & 3;
  int khalf = (tid >> 11) & 1;
  int tap = tid >> 12;
  uint h[4], l[4];
#pragma unroll
  for (int p = 0; p < 4; ++p) {
    int ci0 = khalf * 32 + g * 8 + 2 * p;
    float v0 = vw[oc * 512 + ci0 * 8 + tap];
    float v1 = vw[oc * 512 + (ci0 + 1) * 8 + tap];
    ushort h0 = bf16_bits(v0), h1 = bf16_bits(v1);
    float r0 = v0 - __bfloat162float(*reinterpret_cast<__hip_bfloat16*>(&h0));
    float r1 = v1 - __bfloat162float(*reinterpret_cast<__hip_bfloat16*>(&h1));
    h[p] = (uint)h0 | ((uint)h1 << 16);
    l[p] = (uint)bf16_bits(r0) | ((uint)bf16_bits(r1) << 16);
  }
  size_t base = (size_t)tid * 8;
  *reinterpret_cast<uint4*>(wh + base) = make_uint4(h[0], h[1], h[2], h[3]);
  *reinterpret_cast<uint4*>(wl + base) = make_uint4(l[0], l[1], l[2], l[3]);
}

// ---------------------------------------------------------------------------
// x transpose (unchanged).
// ---------------------------------------------------------------------------
__global__ __launch_bounds__(256) void xprep_kernel(
    const float* __restrict__ x, ushort* __restrict__ xh, ushort* __restrict__ xl)
{
  __shared__ float ts[64][65];
  const int t = threadIdx.x;
  const int vox0 = blockIdx.x * 64;
#pragma unroll
  for (int i = 0; i < 16; ++i) {
    int e = i * 256 + t;
    int ci = e >> 6, vl = e & 63;
    ts[ci][vl] = x[(size_t)ci * VOX + vox0 + vl];
  }
  __syncthreads();
  const int vl = t >> 2, cig = t & 3;
  uint h[8], l[8];
#pragma unroll
  for (int p = 0; p < 8; ++p) {
    float v0 = ts[cig * 16 + 2 * p][vl];
    float v1 = ts[cig * 16 + 2 * p + 1][vl];
    ushort h0 = bf16_bits(v0), h1 = bf16_bits(v1);
    float r0 = v0 - __bfloat162float(*reinterpret_cast<__hip_bfloat16*>(&h0));
    float r1 = v1 - __bfloat162float(*reinterpret_cast<__hip_bfloat16*>(&h1));
    h[p] = (uint)h0 | ((uint)h1 << 16);
    l[p] = (uint)bf16_bits(r0) | ((uint)bf16_bits(r1) << 16);
  }
  size_t base = (size_t)(vox0 + vl) * 64 + cig * 16;
  *reinterpret_cast<uint4*>(xh + base)     = make_uint4(h[0], h[1], h[2], h[3]);
  *reinterpret_cast<uint4*>(xh + base + 8) = make_uint4(h[4], h[5], h[6], h[7]);
  *reinterpret_cast<uint4*>(xl + base)     = make_uint4(l[0], l[1], l[2], l[3]);
  *reinterpret_cast<uint4*>(xl + base + 8) = make_uint4(l[4], l[5], l[6], l[7]);
}

// ---------------------------------------------------------------------------
// MFMA v-conv (unchanged).
// ---------------------------------------------------------------------------
__global__ __launch_bounds__(256) void conv_v_mfma(
    const ushort* __restrict__ xh, const ushort* __restrict__ xl,
    const ushort* __restrict__ wh, const ushort* __restrict__ wl,
    const float* __restrict__ bias, float* __restrict__ y,
    float* __restrict__ part)
{
  __shared__ ushort Bs[2 * 255 * 64];

  const int t = threadIdx.x;
  const int wave = t >> 6, lane = t & 63;
  const int wm = wave >> 1, wn = wave & 1;
  const int g = lane >> 4, ww = lane & 15;
  const int m0 = blockIdx.x * 256;
  const int nt = blockIdx.y;
  const int td = nt >> 4, th = (nt >> 1) & 7, tw = nt & 1;
  const int d0 = td * 2, h0 = th * 4, w0 = tw * 16;

  for (int i = 0; i < 16; ++i) {
    int c = i * 256 + t;
    if (c < 4080) {
      int split = (c >= 2040) ? 1 : 0;
      int c2 = c - split * 2040;
      int pos = c2 >> 3, cig = c2 & 7;
      int dz = pos / 85, rem = pos - dz * 85;
      int hz = rem / 17, wz = rem - hz * 17;
      int d = d0 + dz, h = h0 + hz, w = w0 + wz;
      uint4 val = make_uint4(0, 0, 0, 0);
      if (d < 32 && h < 32 && w < 32) {
        const ushort* src = split ? xl : xh;
        val = *reinterpret_cast<const uint4*>(
            src + (size_t)(d * 1024 + h * 32 + w) * 64 + cig * 8);
      }
      int addr = (pos << 7) + cig * 16;
      addr ^= (pos & 7) << 4;
      *reinterpret_cast<uint4*>(
          reinterpret_cast<char*>(Bs) + split * 32640 + addr) = val;
    }
  }
  __syncthreads();

  const int ocl = m0 + wm * 128 + ww;
  f32x4 acc[8][4];
#pragma unroll
  for (int mf = 0; mf < 8; ++mf)
#pragma unroll
    for (int hh = 0; hh < 4; ++hh) acc[mf][hh] = (f32x4){0.f, 0.f, 0.f, 0.f};

  for (int tap = 0; tap < 8; ++tap) {
    const int kd = tap >> 2, kh = (tap >> 1) & 1, kw = tap & 1;
#pragma unroll
    for (int khalf = 0; khalf < 2; ++khalf) {
      const size_t abase = ((size_t)((tap * 2 + khalf) * 4 + g) * 512 + ocl) * 8;
      s16x8 Ah[8], Al[8];
#pragma unroll
      for (int mf = 0; mf < 8; ++mf) {
        Ah[mf] = *reinterpret_cast<const s16x8*>(wh + abase + mf * 128);
        Al[mf] = *reinterpret_cast<const s16x8*>(wl + abase + mf * 128);
      }
      const int srow = ((wn + kd) * 5 + kh) * 17 + kw;
#pragma unroll
      for (int hh = 0; hh < 4; ++hh) {
        int pos = srow + hh * 17 + ww;
        int baddr = (pos << 7) + khalf * 64 + g * 16;
        baddr ^= (pos & 7) << 4;
        const char* bp = reinterpret_cast<const char*>(Bs) + baddr;
        s16x8 Bh = *reinterpret_cast<const s16x8*>(bp);
        s16x8 Bl = *reinterpret_cast<const s16x8*>(bp + 32640);
#pragma unroll
        for (int mf = 0; mf < 8; ++mf) {
          acc[mf][hh] = __builtin_amdgcn_mfma_f32_16x16x32_bf16(
              Ah[mf], Bh, acc[mf][hh], 0, 0, 0);
          acc[mf][hh] = __builtin_amdgcn_mfma_f32_16x16x32_bf16(
              Al[mf], Bh, acc[mf][hh], 0, 0, 0);
          acc[mf][hh] = __builtin_amdgcn_mfma_f32_16x16x32_bf16(
              Ah[mf], Bl, acc[mf][hh], 0, 0, 0);
        }
      }
    }
  }

  float bs[8][4];
#pragma unroll
  for (int mf = 0; mf < 8; ++mf)
#pragma unroll
    for (int reg = 0; reg < 4; ++reg)
      bs[mf][reg] = bias[m0 + wm * 128 + mf * 16 + g * 4 + reg];

  float ssum[8][4], ssq[8][4];
#pragma unroll
  for (int mf = 0; mf < 8; ++mf)
#pragma unroll
    for (int reg = 0; reg < 4; ++reg) { ssum[mf][reg] = 0.f; ssq[mf][reg] = 0.f; }

#pragma unroll
  for (int mf = 0; mf < 8; ++mf) {
#pragma unroll
    for (int hh = 0; hh < 4; ++hh) {
      int vox = (d0 + wn) * 1024 + (h0 + hh) * 32 + w0 + ww;
#pragma unroll
      for (int reg = 0; reg < 4; ++reg) {
        float v = acc[mf][hh][reg] + bs[mf][reg];
        int oc = m0 + wm * 128 + mf * 16 + g * 4 + reg;
        y[(size_t)oc * VOX + vox] = v;
        ssum[mf][reg] += v;
        ssq[mf][reg] += v * v;
      }
    }
  }
#pragma unroll
  for (int mf = 0; mf < 8; ++mf)
#pragma unroll
    for (int reg = 0; reg < 4; ++reg)
#pragma unroll
      for (int off = 1; off < 16; off <<= 1) {
        ssum[mf][reg] += __shfl_xor(ssum[mf][reg], off);
        ssq[mf][reg]  += __shfl_xor(ssq[mf][reg], off);
      }
  if ((lane & 15) == 0) {
    float* pp = part + (size_t)(nt * 2 + wn) * 1024;
#pragma unroll
    for (int mf = 0; mf < 8; ++mf)
#pragma unroll
      for (int reg = 0; reg < 4; ++reg) {
        int oc = m0 + wm * 128 + mf * 16 + g * 4 + reg;
        pp[oc * 2]     = ssum[mf][reg];
        pp[oc * 2 + 1] = ssq[mf][reg];
      }
  }
}

// ---------------------------------------------------------------------------
// Fused pair of small convs (unchanged from R6).
// ---------------------------------------------------------------------------
template <int CIN, bool NORM_IN, int SPLIT>
__global__ __launch_bounds__(256) void conv_small2_kernel(
    const float* __restrict__ xA, const float* __restrict__ npA,
    const float* __restrict__ wA, const float* __restrict__ bA,
    float* __restrict__ yA, float* __restrict__ pA, int CA,
    const float* __restrict__ xB, const float* __restrict__ npB,
    const float* __restrict__ wB, const float* __restrict__ bB,
    float* __restrict__ yB, float* __restrict__ pB, int CB)
{
  constexpr int OCT = 8;
  __shared__ float xs[2 * 9 * 33];
  __shared__ float wlds[OCT * CIN * 8];
  __shared__ float redsm[4][OCT][2];

  const bool isA = (int)blockIdx.x < SPLIT;
  const float* x    = isA ? xA : xB;
  const float* npar = isA ? npA : npB;
  const float* w    = isA ? wA : wB;
  const float* bias = isA ? bA : bB;
  float* y    = isA ? yA : yB;
  float* part = isA ? pA : pB;
  const int COUT = isA ? CA : CB;
  const int bx = isA ? blockIdx.x : blockIdx.x - SPLIT;

  const int t = threadIdx.x;
  const int oc0 = bx * OCT;
  const int ty = blockIdx.y;
  const int d0 = ty & 31;
  const int h0 = (ty >> 5) * 8;
  const int hh = t >> 5;
  const int ww = t & 31;

  for (int f = t; f < OCT * CIN * 8; f += 256)
    wlds[f] = w[(size_t)oc0 * CIN * 8 + f];

  float acc[OCT];
#pragma unroll
  for (int o = 0; o < OCT; ++o) acc[o] = 0.f;

  float pre[3];
  auto fetch = [&](int ci) {
    float m = 0.f, rs = 1.f;
    if constexpr (NORM_IN) { m = npar[2 * ci]; rs = npar[2 * ci + 1]; }
#pragma unroll
    for (int k = 0; k < 3; ++k) {
      int f = t + k * 256;
      float v = 0.f;
      if (f < 594) {
        int wz = f % 33; int r = f / 33; int hz = r % 9; int dz = r / 9;
        int d = d0 + dz, h = h0 + hz;
        if (d < 32 && h < 32 && wz < 32) {
          v = x[(size_t)ci * VOX + d * 1024 + h * 32 + wz];
          if constexpr (NORM_IN) v = fmaxf((v - m) * rs, 0.f);
        }
      }
      pre[k] = v;
    }
  };

  fetch(0);
  for (int ci = 0; ci < CIN; ++ci) {
    __syncthreads();
#pragma unroll
    for (int k = 0; k < 3; ++k) {
      int f = t + k * 256;
      if (f < 594) xs[f] = pre[k];
    }
    if (ci + 1 < CIN) fetch(ci + 1);
    __syncthreads();

    float xr[2][2][2];
#pragma unroll
    for (int a = 0; a < 2; ++a)
#pragma unroll
      for (int b = 0; b < 2; ++b)
#pragma unroll
        for (int c = 0; c < 2; ++c)
          xr[a][b][c] = xs[(a * 9 + hh + b) * 33 + ww + c];

#pragma unroll
    for (int o = 0; o < OCT; ++o) {
      const float* wp = &wlds[(o * CIN + ci) * 8];
      float a = acc[o];
#pragma unroll
      for (int kd = 0; kd < 2; ++kd)
#pragma unroll
        for (int kh = 0; kh < 2; ++kh)
#pragma unroll
          for (int kw = 0; kw < 2; ++kw)
            a = fmaf(wp[kd * 4 + kh * 2 + kw], xr[kd][kh][kw], a);
      acc[o] = a;
    }
  }

  const int lane = t & 63, wave = t >> 6;
#pragma unroll
  for (int o = 0; o < OCT; ++o) {
    float v0 = acc[o] + bias[oc0 + o];
    y[(size_t)(oc0 + o) * VOX + d0 * 1024 + (h0 + hh) * 32 + ww] = v0;
    float s = v0, ss = v0 * v0;
#pragma unroll
    for (int off = 32; off; off >>= 1) {
      s  += __shfl_down(s, off);
      ss += __shfl_down(ss, off);
    }
    if (lane == 0) { redsm[wave][o][0] = s; redsm[wave][o][1] = ss; }
  }
  __syncthreads();
  if (t < OCT) {
    float s  = redsm[0][t][0] + redsm[1][t][0] + redsm[2][t][0] + redsm[3][t][0];
    float ss = redsm[0][t][1] + redsm[1][t][1] + redsm[2][t][1] + redsm[3][t][1];
    part[((size_t)ty * COUT + oc0 + t) * 2]     = s;
    part[((size_t)ty * COUT + oc0 + t) * 2 + 1] = ss;
  }
}

// ---------------------------------------------------------------------------
// Combined finalize, 256 threads: 4-way tile split per channel + float2.
// ---------------------------------------------------------------------------
__global__ __launch_bounds__(256) void finalize3_kernel(
    const float* __restrict__ p1, int C1, int NT1, float* __restrict__ n1,
    const float* __restrict__ p2, int C2, int NT2, float* __restrict__ n2,
    const float* __restrict__ p3, int C3, int NT3, float* __restrict__ n3)
{
  __shared__ float red[4][64][2];
  const int t = threadIdx.x;
  const int qq = t >> 6, cl = t & 63;
  const int g = blockIdx.x * 64 + cl;

  const float* part = nullptr; float* np = nullptr; int C = 0, NT = 0, c = 0;
  if (g < C1)                { part = p1; np = n1; C = C1; NT = NT1; c = g; }
  else if (g < C1 + C2)      { part = p2; np = n2; C = C2; NT = NT2; c = g - C1; }
  else if (g < C1 + C2 + C3) { part = p3; np = n3; C = C3; NT = NT3; c = g - C1 - C2; }

  float s = 0.f, ss = 0.f;
  if (part)
    for (int tile = qq; tile < NT; tile += 4) {
      float2 v = *reinterpret_cast<const float2*>(&part[((size_t)tile * C + c) * 2]);
      s += v.x; ss += v.y;
    }
  red[qq][cl][0] = s; red[qq][cl][1] = ss;
  __syncthreads();
  if (qq == 0 && part) {
    s  = red[0][cl][0] + red[1][cl][0] + red[2][cl][0] + red[3][cl][0];
    ss = red[0][cl][1] + red[1][cl][1] + red[2][cl][1] + red[3][cl][1];
    float m = s * INV_VOX;
    float var = ss * INV_VOX - m * m;
    np[2 * c]     = m;
    np[2 * c + 1] = rsqrtf(var + EPSF);
  }
}

// ---------------------------------------------------------------------------
// qk_box v2: stage in (coarse idx, par) order, writing normalized q*k product
// DIRECTLY into the fine halo s[1000] (each (idx,par) is a unique fine pos).
// Then separable box. grid (512, 8), block 256.
// ---------------------------------------------------------------------------
__global__ __launch_bounds__(256) void qk_box_kernel(
    const float* __restrict__ qraw, const float* __restrict__ npq,
    const float* __restrict__ kraw, const float* __restrict__ npk,
    float* __restrict__ qkout)
{
  __shared__ float s[1000];
  __shared__ float ws2[800];
  const int j = blockIdx.y;
  const int tile = blockIdx.x;
  const int W0 = (tile & 7) * 8, H0 = ((tile >> 3) & 7) * 8, D0 = (tile >> 6) * 8;
  const int t = threadIdx.x;
  const int cbD = (D0 >> 1) - 1, cbH = (H0 >> 1) - 1, cbW = (W0 >> 1) - 1;
  const float2* npq2 = reinterpret_cast<const float2*>(npq);
  const float2* npk2 = reinterpret_cast<const float2*>(npk);

  // stage: f = par*216 + idx (idx varies fastest within a slot -> 6-float rows)
#pragma unroll
  for (int kk = 0; kk < 7; ++kk) {
    int f = t + kk * 256;
    if (f < 1728) {
      int par = f / 216, idx = f - par * 216;
      int dz = idx / 36, r2 = idx - dz * 36, hz = r2 / 6, wz = r2 - hz * 6;
      int pd = (par >> 2) & 1, ph = (par >> 1) & 1, pw = par & 1;
      int dzf = 2 * dz + pd - 1, hzf = 2 * hz + ph - 1, wzf = 2 * wz + pw - 1;
      if ((unsigned)dzf < 10u && (unsigned)hzf < 10u && (unsigned)wzf < 10u) {
        int cD = cbD + dz, cH = cbH + hz, cW = cbW + wz;
        float prod = 0.f;
        if ((unsigned)cD < 32u && (unsigned)cH < 32u && (unsigned)cW < 32u) {
          int cidx = cD * 1024 + cH * 32 + cW;
          int qc = j * 8 + par;
          float2 nq = npq2[qc];
          float2 nk = npk2[par];
          float qv = fmaxf((qraw[(size_t)qc * VOX + cidx] - nq.x) * nq.y, 0.f);
          float kv = fmaxf((kraw[(size_t)par * VOX + cidx] - nk.x) * nk.y, 0.f);
          prod = qv * kv;
        }
        s[dzf * 100 + hzf * 10 + wzf] = prod;
      }
    }
  }
  __syncthreads();
#pragma unroll
  for (int i = 0; i < 4; ++i) {
    int e = t + i * 256;
    if (e < 800) {
      int dz = e / 80, r2 = e - dz * 80, hz = r2 >> 3, wz1 = r2 & 7;
      int base = dz * 100 + hz * 10 + wz1;
      ws2[e] = s[base] + s[base + 1] + s[base + 2];
    }
  }
  __syncthreads();
#pragma unroll
  for (int rep = 0; rep < 2; ++rep) {
    int o = t + rep * 256;
    int wz = o & 7, hz = (o >> 3) & 7, dz = o >> 6;
    int wb = dz * 80 + hz * 8 + wz;
    float sum = 0.f;
#pragma unroll
    for (int a = 0; a < 3; ++a)
      sum += ws2[wb + a * 80] + ws2[wb + a * 80 + 8] + ws2[wb + a * 80 + 16];
    qkout[(size_t)j * 262144 + (D0 + dz) * 4096 + (H0 + hz) * 64 + (W0 + wz)] =
        sum * (1.f / 27.f);
  }
}

// ---------------------------------------------------------------------------
// einsum_box v5: v4 + async-STAGE prefetch of ci+1's v into registers.
// grid (512, 2), block 256.
// ---------------------------------------------------------------------------
__global__ __launch_bounds__(256) void einsum_box_kernel(
    const float* __restrict__ vraw, const float* __restrict__ npv,
    const float* __restrict__ qk, float* __restrict__ out)
{
  __shared__ char vs_raw[6912];
  __shared__ float qkvs[1000];
  __shared__ float wsum[800];

  const int tile = blockIdx.x;
  const int c0 = blockIdx.y * 32;
  const int W0 = (tile & 7) * 8, H0 = ((tile >> 3) & 7) * 8, D0 = (tile >> 6) * 8;
  const int t = threadIdx.x;
  const int cbD = (D0 >> 1) - 1, cbH = (H0 >> 1) - 1, cbW = (W0 >> 1) - 1;
  const float2* npv2 = reinterpret_cast<const float2*>(npv);

  // ---- stage-slot precompute
  uint soff[7]; int sbyte[7]; int snidx[7]; bool svalid[7];
#pragma unroll
  for (int k = 0; k < 7; ++k) {
    int f = t + k * 256;
    int j = f / 216, idx = f - j * 216;
    int dz = idx / 36, r2 = idx - dz * 36, hz = r2 / 6, wz = r2 - hz * 6;
    int cD = cbD + dz, cH = cbH + hz, cW = cbW + wz;
    bool vld = (f < 1728) && (unsigned)cD < 32u && (unsigned)cH < 32u &&
               (unsigned)cW < 32u;
    svalid[k] = vld;
    soff[k] = vld ? (uint)((c0 * 8 + j) * VOX + cD * 1024 + cH * 32 + cW) : 0u;
    snidx[k] = (f < 1728) ? (c0 * 8 + j) : 0;
    int byte = idx * 32 + (j >> 2) * 16 + (j & 3) * 4;
    sbyte[k] = byte ^ (((idx >> 2) & 7) << 4);
  }

  // ---- qkv-slot precompute + qk -> registers
  int vbyte[4]; float qr[4][8];
#pragma unroll
  for (int i = 0; i < 4; ++i) {
    int pos = t + i * 256;
    vbyte[i] = 0;
#pragma unroll
    for (int j = 0; j < 8; ++j) qr[i][j] = 0.f;
    if (pos < 1000) {
      int dz = pos / 100, rem = pos - dz * 100, hz = rem / 10, wz = rem - hz * 10;
      int D = D0 - 1 + dz, H = H0 - 1 + hz, W = W0 - 1 + wz;
      if ((unsigned)D < 64u && (unsigned)H < 64u && (unsigned)W < 64u) {
        int fidx = D * 4096 + H * 64 + W;
#pragma unroll
        for (int j = 0; j < 8; ++j)
          qr[i][j] = qk[(size_t)j * 262144 + fidx];
        int vidx = ((D >> 1) - cbD) * 36 + ((H >> 1) - cbH) * 6 + ((W >> 1) - cbW);
        vbyte[i] = (vidx * 32) ^ (((vidx >> 2) & 7) << 4);
      }
    }
  }

  // ---- wsum/out-slot precompute
  int wb[4];
#pragma unroll
  for (int i = 0; i < 4; ++i) {
    int e = t + i * 256;
    int dz = e / 80, r2 = e - dz * 80, hz = r2 >> 3, wz1 = r2 & 7;
    wb[i] = dz * 100 + hz * 10 + wz1;
  }
  int wb2[2]; float* op[2];
#pragma unroll
  for (int rep = 0; rep < 2; ++rep) {
    int o = t + rep * 256;
    int wz = o & 7, hz = (o >> 3) & 7, dz = o >> 6;
    wb2[rep] = dz * 80 + hz * 8 + wz;
    op[rep] = out + (size_t)c0 * 262144 +
              (D0 + dz) * 4096 + (H0 + hz) * 64 + (W0 + wz);
  }

  // ---- prefetch registers (T14 async-STAGE: issue early, write late)
  float pre[7];
  auto fetchv = [&](int ci) {
    const uint cio = (uint)(ci * 8 * VOX);
    const int cin8 = ci * 8;
#pragma unroll
    for (int k = 0; k < 7; ++k) {
      if (k < 6 || t < 192) {
        float2 mr = npv2[snidx[k] + cin8];
        float raw = vraw[soff[k] + cio];
        pre[k] = svalid[k] ? fmaxf((raw - mr.x) * mr.y, 0.f) : 0.f;
      }
    }
  };

  fetchv(0);
  for (int ci = 0; ci < 32; ++ci) {
    __syncthreads();   // prior iteration's vs consumers done
#pragma unroll
    for (int k = 0; k < 7; ++k)
      if (k < 6 || t < 192)
        *reinterpret_cast<float*>(vs_raw + sbyte[k]) = pre[k];
    if (ci + 1 < 32) fetchv(ci + 1);   // drains across the 3 compute phases
    __syncthreads();
    // qkv halo
#pragma unroll
    for (int i = 0; i < 4; ++i) {
      int pos = t + i * 256;
      if (pos < 1000) {
        float4 va = *reinterpret_cast<const float4*>(vs_raw + vbyte[i]);
        float4 vb = *reinterpret_cast<const float4*>(vs_raw + (vbyte[i] ^ 16));
        float val = qr[i][0] * va.x;
        val = fmaf(qr[i][1], va.y, val);
        val = fmaf(qr[i][2], va.z, val);
        val = fmaf(qr[i][3], va.w, val);
        val = fmaf(qr[i][4], vb.x, val);
        val = fmaf(qr[i][5], vb.y, val);
        val = fmaf(qr[i][6], vb.z, val);
        val = fmaf(qr[i][7], vb.w, val);
        qkvs[pos] = val;
      }
    }
    __syncthreads();
    // W-pass
#pragma unroll
    for (int i = 0; i < 4; ++i) {
      if (i < 3 || t < 32) {
        int b = wb[i];
        wsum[t + i * 256] = qkvs[b] + qkvs[b + 1] + qkvs[b + 2];
      }
    }
    __syncthreads();
    // H+D gather + store
#pragma unroll
    for (int rep = 0; rep < 2; ++rep) {
      float sum = 0.f;
#pragma unroll
      for (int a = 0; a < 3; ++a)
        sum += wsum[wb2[rep] + a * 80] + wsum[wb2[rep] + a * 80 + 8] +
               wsum[wb2[rep] + a * 80 + 16];
      op[rep][(size_t)ci << 18] = sum * (1.f / 27.f);
    }
  }
}

// ---------------------------------------------------------------------------
extern "C" void kernel_launch(void* const* d_in, const int* in_sizes, int n_in,
                              void* d_out, int out_size, void* d_ws, size_t ws_size,
                              hipStream_t stream)
{
  (void)in_sizes; (void)n_in; (void)out_size; (void)ws_size;
  const float* x   = (const float*)d_in[0];
  const float* q1w = (const float*)d_in[1];
  const float* q1b = (const float*)d_in[2];
  const float* q2w = (const float*)d_in[3];
  const float* q2b = (const float*)d_in[4];
  const float* k1w = (const float*)d_in[5];
  const float* k1b = (const float*)d_in[6];
  const float* k2w = (const float*)d_in[7];
  const float* k2b = (const float*)d_in[8];
  const float* vw  = (const float*)d_in[9];
  const float* vb  = (const float*)d_in[10];
  float* out = (float*)d_out;

  float* p = (float*)d_ws;
  float* vraw  = p; p += (size_t)512 * VOX;
  float* qraw1 = p; p += (size_t)16 * VOX;
  float* qraw2 = p; p += (size_t)64 * VOX;
  float* kraw1 = p; p += (size_t)16 * VOX;
  float* kraw2 = p; p += (size_t)8 * VOX;
  float* qkbuf = p; p += (size_t)8 * 262144;
  float* part_v  = p; p += (size_t)512 * 512 * 2;
  float* part_q1 = p; p += 128 * 16 * 2;
  float* part_q2 = p; p += 128 * 64 * 2;
  float* part_k1 = p; p += 128 * 16 * 2;
  float* part_k2 = p; p += 128 * 8 * 2;
  float* np_q1 = p; p += 2 * 16;
  float* np_q2 = p; p += 2 * 64;
  float* np_k1 = p; p += 2 * 16;
  float* np_k2 = p; p += 2 * 8;
  float* np_v  = p; p += 2 * 512;

  // aliases (dead during conv_v): xT in qkbuf, Wf in qraw2.
  ushort* xT_hi = (ushort*)qkbuf;
  ushort* xT_lo = (ushort*)qkbuf + (size_t)32768 * 64;
  ushort* Wf_hi = (ushort*)qraw2;
  ushort* Wf_lo = (ushort*)qraw2 + (size_t)262144;

  dim3 blk(256);
  wprep_kernel<<<128, blk, 0, stream>>>(vw, Wf_hi, Wf_lo);
  xprep_kernel<<<512, blk, 0, stream>>>(x, xT_hi, xT_lo);
  conv_v_mfma<<<dim3(2, 256), blk, 0, stream>>>(
      xT_hi, xT_lo, Wf_hi, Wf_lo, vb, vraw, part_v);

  conv_small2_kernel<64, false, 2><<<dim3(4, 128), blk, 0, stream>>>(
      x, nullptr, q1w, q1b, qraw1, part_q1, 16,
      x, nullptr, k1w, k1b, kraw1, part_k1, 16);
  finalize3_kernel<<<9, blk, 0, stream>>>(
      part_v, 512, 512, np_v,
      part_q1, 16, 128, np_q1,
      part_k1, 16, 128, np_k1);

  conv_small2_kernel<16, true, 8><<<dim3(9, 128), blk, 0, stream>>>(
      qraw1, np_q1, q2w, q2b, qraw2, part_q2, 64,
      kraw1, np_k1, k2w, k2b, kraw2, part_k2, 8);
  finalize3_kernel<<<2, blk, 0, stream>>>(
      part_q2, 64, 128, np_q2,
      part_k2, 8, 128, np_k2,
      nullptr, 0, 0, nullptr);

  qk_box_kernel<<<dim3(512, 8), blk, 0, stream>>>(
      qraw2, np_q2, kraw2, np_k2, qkbuf);
  einsum_box_kernel<<<dim3(512, 2), blk, 0, stream>>>(
      vraw, np_v, qkbuf, out);
}

// Round 8
// 339.734 us; speedup vs baseline: 5.0134x; 1.0369x over previous
//
#include <hip/hip_runtime.h>
#include <hip/hip_bf16.h>

// QKV upsampling pipeline.
// R8: (a) einsum c-split 4 (8 blocks/CU, half the barriers per block);
// (b) q1+k1 convs folded into the MFMA path (conv_v_mfma<1,32> on same xT);
// (c) finalize #1 absorbs qk1 stats. q2/k2 + qk_box + einsum structure kept.

constexpr int VOX = 32 * 32 * 32;
constexpr float INV_VOX = 1.0f / 32768.0f;
constexpr float EPSF = 1e-5f;

typedef __attribute__((ext_vector_type(8))) short s16x8;
typedef __attribute__((ext_vector_type(4))) float f32x4;

static __device__ __forceinline__ ushort bf16_bits(float v) {
  __hip_bfloat16 h = __float2bfloat16(v);
  return *reinterpret_cast<ushort*>(&h);
}

// ---------------------------------------------------------------------------
// v-weight prepack: vw fp32 [512][64][8] -> fragment order, hi/lo bf16.
// ---------------------------------------------------------------------------
__global__ void wprep_kernel(const float* __restrict__ vw,
                             ushort* __restrict__ wh, ushort* __restrict__ wl)
{
  int tid = blockIdx.x * 256 + threadIdx.x;
  if (tid >= 32768) return;
  int oc = tid & 511;
  int g = (tid >> 9) & 3;
  int khalf = (tid >> 11) & 1;
  int tap = tid >> 12;
  uint h[4], l[4];
#pragma unroll
  for (int p = 0; p < 4; ++p) {
    int ci0 = khalf * 32 + g * 8 + 2 * p;
    float v0 = vw[oc * 512 + ci0 * 8 + tap];
    float v1 = vw[oc * 512 + (ci0 + 1) * 8 + tap];
    ushort h0 = bf16_bits(v0), h1 = bf16_bits(v1);
    float r0 = v0 - __bfloat162float(*reinterpret_cast<__hip_bfloat16*>(&h0));
    float r1 = v1 - __bfloat162float(*reinterpret_cast<__hip_bfloat16*>(&h1));
    h[p] = (uint)h0 | ((uint)h1 << 16);
    l[p] = (uint)bf16_bits(r0) | ((uint)bf16_bits(r1) << 16);
  }
  size_t base = (size_t)tid * 8;
  *reinterpret_cast<uint4*>(wh + base) = make_uint4(h[0], h[1], h[2], h[3]);
  *reinterpret_cast<uint4*>(wl + base) = make_uint4(l[0], l[1], l[2], l[3]);
}

// ---------------------------------------------------------------------------
// q1/k1 weight prepack: 32 rows (16 q1 + 16 k1), stride 32, + combined bias.
// ---------------------------------------------------------------------------
__global__ void wprep_qk_kernel(const float* __restrict__ q1w,
                                const float* __restrict__ q1b,
                                const float* __restrict__ k1w,
                                const float* __restrict__ k1b,
                                ushort* __restrict__ wh, ushort* __restrict__ wl,
                                float* __restrict__ bq)
{
  int tid = blockIdx.x * 256 + threadIdx.x;   // 2048 total
  if (tid < 32) bq[tid] = tid < 16 ? q1b[tid] : k1b[tid - 16];
  if (tid >= 2048) return;
  int oc = tid & 31;
  int g = (tid >> 5) & 3;
  int khalf = (tid >> 7) & 1;
  int tap = tid >> 8;
  const float* src = oc < 16 ? q1w + oc * 512 : k1w + (oc - 16) * 512;
  uint h[4], l[4];
#pragma unroll
  for (int p = 0; p < 4; ++p) {
    int ci0 = khalf * 32 + g * 8 + 2 * p;
    float v0 = src[ci0 * 8 + tap];
    float v1 = src[(ci0 + 1) * 8 + tap];
    ushort h0 = bf16_bits(v0), h1 = bf16_bits(v1);
    float r0 = v0 - __bfloat162float(*reinterpret_cast<__hip_bfloat16*>(&h0));
    float r1 = v1 - __bfloat162float(*reinterpret_cast<__hip_bfloat16*>(&h1));
    h[p] = (uint)h0 | ((uint)h1 << 16);
    l[p] = (uint)bf16_bits(r0) | ((uint)bf16_bits(r1) << 16);
  }
  size_t base = (size_t)tid * 8;
  *reinterpret_cast<uint4*>(wh + base) = make_uint4(h[0], h[1], h[2], h[3]);
  *reinterpret_cast<uint4*>(wl + base) = make_uint4(l[0], l[1], l[2], l[3]);
}

// ---------------------------------------------------------------------------
// x transpose (unchanged).
// ---------------------------------------------------------------------------
__global__ __launch_bounds__(256) void xprep_kernel(
    const float* __restrict__ x, ushort* __restrict__ xh, ushort* __restrict__ xl)
{
  __shared__ float ts[64][65];
  const int t = threadIdx.x;
  const int vox0 = blockIdx.x * 64;
#pragma unroll
  for (int i = 0; i < 16; ++i) {
    int e = i * 256 + t;
    int ci = e >> 6, vl = e & 63;
    ts[ci][vl] = x[(size_t)ci * VOX + vox0 + vl];
  }
  __syncthreads();
  const int vl = t >> 2, cig = t & 3;
  uint h[8], l[8];
#pragma unroll
  for (int p = 0; p < 8; ++p) {
    float v0 = ts[cig * 16 + 2 * p][vl];
    float v1 = ts[cig * 16 + 2 * p + 1][vl];
    ushort h0 = bf16_bits(v0), h1 = bf16_bits(v1);
    float r0 = v0 - __bfloat162float(*reinterpret_cast<__hip_bfloat16*>(&h0));
    float r1 = v1 - __bfloat162float(*reinterpret_cast<__hip_bfloat16*>(&h1));
    h[p] = (uint)h0 | ((uint)h1 << 16);
    l[p] = (uint)bf16_bits(r0) | ((uint)bf16_bits(r1) << 16);
  }
  size_t base = (size_t)(vox0 + vl) * 64 + cig * 16;
  *reinterpret_cast<uint4*>(xh + base)     = make_uint4(h[0], h[1], h[2], h[3]);
  *reinterpret_cast<uint4*>(xh + base + 8) = make_uint4(h[4], h[5], h[6], h[7]);
  *reinterpret_cast<uint4*>(xl + base)     = make_uint4(l[0], l[1], l[2], l[3]);
  *reinterpret_cast<uint4*>(xl + base + 8) = make_uint4(l[4], l[5], l[6], l[7]);
}

// ---------------------------------------------------------------------------
// MFMA conv, templated: NMF = M-fragments per wave (8 -> 128 rows/wave),
// OCS = total output channels (A-matrix row stride).
// main: <8,512> grid (2,256); q1k1: <1,32> grid (1,256).
// ---------------------------------------------------------------------------
template <int NMF, int OCS>
__global__ __launch_bounds__(256) void conv_v_mfma(
    const ushort* __restrict__ xh, const ushort* __restrict__ xl,
    const ushort* __restrict__ wh, const ushort* __restrict__ wl,
    const float* __restrict__ bias, float* __restrict__ y,
    float* __restrict__ part)
{
  __shared__ ushort Bs[2 * 255 * 64];

  const int t = threadIdx.x;
  const int wave = t >> 6, lane = t & 63;
  const int wm = wave >> 1, wn = wave & 1;
  const int g = lane >> 4, ww = lane & 15;
  const int m0 = blockIdx.x * (NMF * 32);
  const int nt = blockIdx.y;
  const int td = nt >> 4, th = (nt >> 1) & 7, tw = nt & 1;
  const int d0 = td * 2, h0 = th * 4, w0 = tw * 16;

  for (int i = 0; i < 16; ++i) {
    int c = i * 256 + t;
    if (c < 4080) {
      int split = (c >= 2040) ? 1 : 0;
      int c2 = c - split * 2040;
      int pos = c2 >> 3, cig = c2 & 7;
      int dz = pos / 85, rem = pos - dz * 85;
      int hz = rem / 17, wz = rem - hz * 17;
      int d = d0 + dz, h = h0 + hz, w = w0 + wz;
      uint4 val = make_uint4(0, 0, 0, 0);
      if (d < 32 && h < 32 && w < 32) {
        const ushort* src = split ? xl : xh;
        val = *reinterpret_cast<const uint4*>(
            src + (size_t)(d * 1024 + h * 32 + w) * 64 + cig * 8);
      }
      int addr = (pos << 7) + cig * 16;
      addr ^= (pos & 7) << 4;
      *reinterpret_cast<uint4*>(
          reinterpret_cast<char*>(Bs) + split * 32640 + addr) = val;
    }
  }
  __syncthreads();

  const int ocl = m0 + wm * (NMF * 16) + ww;
  f32x4 acc[NMF][4];
#pragma unroll
  for (int mf = 0; mf < NMF; ++mf)
#pragma unroll
    for (int hh = 0; hh < 4; ++hh) acc[mf][hh] = (f32x4){0.f, 0.f, 0.f, 0.f};

  for (int tap = 0; tap < 8; ++tap) {
    const int kd = tap >> 2, kh = (tap >> 1) & 1, kw = tap & 1;
#pragma unroll
    for (int khalf = 0; khalf < 2; ++khalf) {
      const size_t abase = ((size_t)((tap * 2 + khalf) * 4 + g) * OCS + ocl) * 8;
      s16x8 Ah[NMF], Al[NMF];
#pragma unroll
      for (int mf = 0; mf < NMF; ++mf) {
        Ah[mf] = *reinterpret_cast<const s16x8*>(wh + abase + mf * 16 * 8);
        Al[mf] = *reinterpret_cast<const s16x8*>(wl + abase + mf * 16 * 8);
      }
      const int srow = ((wn + kd) * 5 + kh) * 17 + kw;
#pragma unroll
      for (int hh = 0; hh < 4; ++hh) {
        int pos = srow + hh * 17 + ww;
        int baddr = (pos << 7) + khalf * 64 + g * 16;
        baddr ^= (pos & 7) << 4;
        const char* bp = reinterpret_cast<const char*>(Bs) + baddr;
        s16x8 Bh = *reinterpret_cast<const s16x8*>(bp);
        s16x8 Bl = *reinterpret_cast<const s16x8*>(bp + 32640);
#pragma unroll
        for (int mf = 0; mf < NMF; ++mf) {
          acc[mf][hh] = __builtin_amdgcn_mfma_f32_16x16x32_bf16(
              Ah[mf], Bh, acc[mf][hh], 0, 0, 0);
          acc[mf][hh] = __builtin_amdgcn_mfma_f32_16x16x32_bf16(
              Al[mf], Bh, acc[mf][hh], 0, 0, 0);
          acc[mf][hh] = __builtin_amdgcn_mfma_f32_16x16x32_bf16(
              Ah[mf], Bl, acc[mf][hh], 0, 0, 0);
        }
      }
    }
  }

  float bs[NMF][4];
#pragma unroll
  for (int mf = 0; mf < NMF; ++mf)
#pragma unroll
    for (int reg = 0; reg < 4; ++reg)
      bs[mf][reg] = bias[m0 + wm * (NMF * 16) + mf * 16 + g * 4 + reg];

  float ssum[NMF][4], ssq[NMF][4];
#pragma unroll
  for (int mf = 0; mf < NMF; ++mf)
#pragma unroll
    for (int reg = 0; reg < 4; ++reg) { ssum[mf][reg] = 0.f; ssq[mf][reg] = 0.f; }

#pragma unroll
  for (int mf = 0; mf < NMF; ++mf) {
#pragma unroll
    for (int hh = 0; hh < 4; ++hh) {
      int vox = (d0 + wn) * 1024 + (h0 + hh) * 32 + w0 + ww;
#pragma unroll
      for (int reg = 0; reg < 4; ++reg) {
        float v = acc[mf][hh][reg] + bs[mf][reg];
        int oc = m0 + wm * (NMF * 16) + mf * 16 + g * 4 + reg;
        y[(size_t)oc * VOX + vox] = v;
        ssum[mf][reg] += v;
        ssq[mf][reg] += v * v;
      }
    }
  }
#pragma unroll
  for (int mf = 0; mf < NMF; ++mf)
#pragma unroll
    for (int reg = 0; reg < 4; ++reg)
#pragma unroll
      for (int off = 1; off < 16; off <<= 1) {
        ssum[mf][reg] += __shfl_xor(ssum[mf][reg], off);
        ssq[mf][reg]  += __shfl_xor(ssq[mf][reg], off);
      }
  if ((lane & 15) == 0) {
    float* pp = part + (size_t)(nt * 2 + wn) * (OCS * 2);
#pragma unroll
    for (int mf = 0; mf < NMF; ++mf)
#pragma unroll
      for (int reg = 0; reg < 4; ++reg) {
        int oc = m0 + wm * (NMF * 16) + mf * 16 + g * 4 + reg;
        pp[oc * 2]     = ssum[mf][reg];
        pp[oc * 2 + 1] = ssq[mf][reg];
      }
  }
}

// ---------------------------------------------------------------------------
// Fused pair of small convs (stage 2: q2 + k2). Unchanged structure.
// ---------------------------------------------------------------------------
template <int CIN, bool NORM_IN, int SPLIT>
__global__ __launch_bounds__(256) void conv_small2_kernel(
    const float* __restrict__ xA, const float* __restrict__ npA,
    const float* __restrict__ wA, const float* __restrict__ bA,
    float* __restrict__ yA, float* __restrict__ pA, int CA,
    const float* __restrict__ xB, const float* __restrict__ npB,
    const float* __restrict__ wB, const float* __restrict__ bB,
    float* __restrict__ yB, float* __restrict__ pB, int CB)
{
  constexpr int OCT = 8;
  __shared__ float xs[2 * 9 * 33];
  __shared__ float wlds[OCT * CIN * 8];
  __shared__ float redsm[4][OCT][2];

  const bool isA = (int)blockIdx.x < SPLIT;
  const float* x    = isA ? xA : xB;
  const float* npar = isA ? npA : npB;
  const float* w    = isA ? wA : wB;
  const float* bias = isA ? bA : bB;
  float* y    = isA ? yA : yB;
  float* part = isA ? pA : pB;
  const int COUT = isA ? CA : CB;
  const int bx = isA ? blockIdx.x : blockIdx.x - SPLIT;

  const int t = threadIdx.x;
  const int oc0 = bx * OCT;
  const int ty = blockIdx.y;
  const int d0 = ty & 31;
  const int h0 = (ty >> 5) * 8;
  const int hh = t >> 5;
  const int ww = t & 31;

  for (int f = t; f < OCT * CIN * 8; f += 256)
    wlds[f] = w[(size_t)oc0 * CIN * 8 + f];

  float acc[OCT];
#pragma unroll
  for (int o = 0; o < OCT; ++o) acc[o] = 0.f;

  float pre[3];
  auto fetch = [&](int ci) {
    float m = 0.f, rs = 1.f;
    if constexpr (NORM_IN) { m = npar[2 * ci]; rs = npar[2 * ci + 1]; }
#pragma unroll
    for (int k = 0; k < 3; ++k) {
      int f = t + k * 256;
      float v = 0.f;
      if (f < 594) {
        int wz = f % 33; int r = f / 33; int hz = r % 9; int dz = r / 9;
        int d = d0 + dz, h = h0 + hz;
        if (d < 32 && h < 32 && wz < 32) {
          v = x[(size_t)ci * VOX + d * 1024 + h * 32 + wz];
          if constexpr (NORM_IN) v = fmaxf((v - m) * rs, 0.f);
        }
      }
      pre[k] = v;
    }
  };

  fetch(0);
  for (int ci = 0; ci < CIN; ++ci) {
    __syncthreads();
#pragma unroll
    for (int k = 0; k < 3; ++k) {
      int f = t + k * 256;
      if (f < 594) xs[f] = pre[k];
    }
    if (ci + 1 < CIN) fetch(ci + 1);
    __syncthreads();

    float xr[2][2][2];
#pragma unroll
    for (int a = 0; a < 2; ++a)
#pragma unroll
      for (int b = 0; b < 2; ++b)
#pragma unroll
        for (int c = 0; c < 2; ++c)
          xr[a][b][c] = xs[(a * 9 + hh + b) * 33 + ww + c];

#pragma unroll
    for (int o = 0; o < OCT; ++o) {
      const float* wp = &wlds[(o * CIN + ci) * 8];
      float a = acc[o];
#pragma unroll
      for (int kd = 0; kd < 2; ++kd)
#pragma unroll
        for (int kh = 0; kh < 2; ++kh)
#pragma unroll
          for (int kw = 0; kw < 2; ++kw)
            a = fmaf(wp[kd * 4 + kh * 2 + kw], xr[kd][kh][kw], a);
      acc[o] = a;
    }
  }

  const int lane = t & 63, wave = t >> 6;
#pragma unroll
  for (int o = 0; o < OCT; ++o) {
    float v0 = acc[o] + bias[oc0 + o];
    y[(size_t)(oc0 + o) * VOX + d0 * 1024 + (h0 + hh) * 32 + ww] = v0;
    float s = v0, ss = v0 * v0;
#pragma unroll
    for (int off = 32; off; off >>= 1) {
      s  += __shfl_down(s, off);
      ss += __shfl_down(ss, off);
    }
    if (lane == 0) { redsm[wave][o][0] = s; redsm[wave][o][1] = ss; }
  }
  __syncthreads();
  if (t < OCT) {
    float s  = redsm[0][t][0] + redsm[1][t][0] + redsm[2][t][0] + redsm[3][t][0];
    float ss = redsm[0][t][1] + redsm[1][t][1] + redsm[2][t][1] + redsm[3][t][1];
    part[((size_t)ty * COUT + oc0 + t) * 2]     = s;
    part[((size_t)ty * COUT + oc0 + t) * 2 + 1] = ss;
  }
}

// ---------------------------------------------------------------------------
// Combined finalize (3 sets), 256 threads, 4-way split + float2.
// ---------------------------------------------------------------------------
__global__ __launch_bounds__(256) void finalize3_kernel(
    const float* __restrict__ p1, int C1, int NT1, float* __restrict__ n1,
    const float* __restrict__ p2, int C2, int NT2, float* __restrict__ n2,
    const float* __restrict__ p3, int C3, int NT3, float* __restrict__ n3)
{
  __shared__ float red[4][64][2];
  const int t = threadIdx.x;
  const int qq = t >> 6, cl = t & 63;
  const int g = blockIdx.x * 64 + cl;

  const float* part = nullptr; float* np = nullptr; int C = 0, NT = 0, c = 0;
  if (g < C1)                { part = p1; np = n1; C = C1; NT = NT1; c = g; }
  else if (g < C1 + C2)      { part = p2; np = n2; C = C2; NT = NT2; c = g - C1; }
  else if (g < C1 + C2 + C3) { part = p3; np = n3; C = C3; NT = NT3; c = g - C1 - C2; }

  float s = 0.f, ss = 0.f;
  if (part)
    for (int tile = qq; tile < NT; tile += 4) {
      float2 v = *reinterpret_cast<const float2*>(&part[((size_t)tile * C + c) * 2]);
      s += v.x; ss += v.y;
    }
  red[qq][cl][0] = s; red[qq][cl][1] = ss;
  __syncthreads();
  if (qq == 0 && part) {
    s  = red[0][cl][0] + red[1][cl][0] + red[2][cl][0] + red[3][cl][0];
    ss = red[0][cl][1] + red[1][cl][1] + red[2][cl][1] + red[3][cl][1];
    float m = s * INV_VOX;
    float var = ss * INV_VOX - m * m;
    np[2 * c]     = m;
    np[2 * c + 1] = rsqrtf(var + EPSF);
  }
}

// ---------------------------------------------------------------------------
// qk_box v2 (unchanged from R7).
// ---------------------------------------------------------------------------
__global__ __launch_bounds__(256) void qk_box_kernel(
    const float* __restrict__ qraw, const float* __restrict__ npq,
    const float* __restrict__ kraw, const float* __restrict__ npk,
    float* __restrict__ qkout)
{
  __shared__ float s[1000];
  __shared__ float ws2[800];
  const int j = blockIdx.y;
  const int tile = blockIdx.x;
  const int W0 = (tile & 7) * 8, H0 = ((tile >> 3) & 7) * 8, D0 = (tile >> 6) * 8;
  const int t = threadIdx.x;
  const int cbD = (D0 >> 1) - 1, cbH = (H0 >> 1) - 1, cbW = (W0 >> 1) - 1;
  const float2* npq2 = reinterpret_cast<const float2*>(npq);
  const float2* npk2 = reinterpret_cast<const float2*>(npk);

#pragma unroll
  for (int kk = 0; kk < 7; ++kk) {
    int f = t + kk * 256;
    if (f < 1728) {
      int par = f / 216, idx = f - par * 216;
      int dz = idx / 36, r2 = idx - dz * 36, hz = r2 / 6, wz = r2 - hz * 6;
      int pd = (par >> 2) & 1, ph = (par >> 1) & 1, pw = par & 1;
      int dzf = 2 * dz + pd - 1, hzf = 2 * hz + ph - 1, wzf = 2 * wz + pw - 1;
      if ((unsigned)dzf < 10u && (unsigned)hzf < 10u && (unsigned)wzf < 10u) {
        int cD = cbD + dz, cH = cbH + hz, cW = cbW + wz;
        float prod = 0.f;
        if ((unsigned)cD < 32u && (unsigned)cH < 32u && (unsigned)cW < 32u) {
          int cidx = cD * 1024 + cH * 32 + cW;
          int qc = j * 8 + par;
          float2 nq = npq2[qc];
          float2 nk = npk2[par];
          float qv = fmaxf((qraw[(size_t)qc * VOX + cidx] - nq.x) * nq.y, 0.f);
          float kv = fmaxf((kraw[(size_t)par * VOX + cidx] - nk.x) * nk.y, 0.f);
          prod = qv * kv;
        }
        s[dzf * 100 + hzf * 10 + wzf] = prod;
      }
    }
  }
  __syncthreads();
#pragma unroll
  for (int i = 0; i < 4; ++i) {
    int e = t + i * 256;
    if (e < 800) {
      int dz = e / 80, r2 = e - dz * 80, hz = r2 >> 3, wz1 = r2 & 7;
      int base = dz * 100 + hz * 10 + wz1;
      ws2[e] = s[base] + s[base + 1] + s[base + 2];
    }
  }
  __syncthreads();
#pragma unroll
  for (int rep = 0; rep < 2; ++rep) {
    int o = t + rep * 256;
    int wz = o & 7, hz = (o >> 3) & 7, dz = o >> 6;
    int wb = dz * 80 + hz * 8 + wz;
    float sum = 0.f;
#pragma unroll
    for (int a = 0; a < 3; ++a)
      sum += ws2[wb + a * 80] + ws2[wb + a * 80 + 8] + ws2[wb + a * 80 + 16];
    qkout[(size_t)j * 262144 + (D0 + dz) * 4096 + (H0 + hz) * 64 + (W0 + wz)] =
        sum * (1.f / 27.f);
  }
}

// ---------------------------------------------------------------------------
// einsum_box v6: R7 structure, c-split 4 -> grid (512, 4), 16 ch/block.
// ---------------------------------------------------------------------------
__global__ __launch_bounds__(256) void einsum_box_kernel(
    const float* __restrict__ vraw, const float* __restrict__ npv,
    const float* __restrict__ qk, float* __restrict__ out)
{
  __shared__ char vs_raw[6912];
  __shared__ float qkvs[1000];
  __shared__ float wsum[800];

  const int tile = blockIdx.x;
  const int c0 = blockIdx.y * 16;
  const int W0 = (tile & 7) * 8, H0 = ((tile >> 3) & 7) * 8, D0 = (tile >> 6) * 8;
  const int t = threadIdx.x;
  const int cbD = (D0 >> 1) - 1, cbH = (H0 >> 1) - 1, cbW = (W0 >> 1) - 1;
  const float2* npv2 = reinterpret_cast<const float2*>(npv);

  uint soff[7]; int sbyte[7]; int snidx[7]; bool svalid[7];
#pragma unroll
  for (int k = 0; k < 7; ++k) {
    int f = t + k * 256;
    int j = f / 216, idx = f - j * 216;
    int dz = idx / 36, r2 = idx - dz * 36, hz = r2 / 6, wz = r2 - hz * 6;
    int cD = cbD + dz, cH = cbH + hz, cW = cbW + wz;
    bool vld = (f < 1728) && (unsigned)cD < 32u && (unsigned)cH < 32u &&
               (unsigned)cW < 32u;
    svalid[k] = vld;
    soff[k] = vld ? (uint)((c0 * 8 + j) * VOX + cD * 1024 + cH * 32 + cW) : 0u;
    snidx[k] = (f < 1728) ? (c0 * 8 + j) : 0;
    int byte = idx * 32 + (j >> 2) * 16 + (j & 3) * 4;
    sbyte[k] = byte ^ (((idx >> 2) & 7) << 4);
  }

  int vbyte[4]; float qr[4][8];
#pragma unroll
  for (int i = 0; i < 4; ++i) {
    int pos = t + i * 256;
    vbyte[i] = 0;
#pragma unroll
    for (int j = 0; j < 8; ++j) qr[i][j] = 0.f;
    if (pos < 1000) {
      int dz = pos / 100, rem = pos - dz * 100, hz = rem / 10, wz = rem - hz * 10;
      int D = D0 - 1 + dz, H = H0 - 1 + hz, W = W0 - 1 + wz;
      if ((unsigned)D < 64u && (unsigned)H < 64u && (unsigned)W < 64u) {
        int fidx = D * 4096 + H * 64 + W;
#pragma unroll
        for (int j = 0; j < 8; ++j)
          qr[i][j] = qk[(size_t)j * 262144 + fidx];
        int vidx = ((D >> 1) - cbD) * 36 + ((H >> 1) - cbH) * 6 + ((W >> 1) - cbW);
        vbyte[i] = (vidx * 32) ^ (((vidx >> 2) & 7) << 4);
      }
    }
  }

  int wb[4];
#pragma unroll
  for (int i = 0; i < 4; ++i) {
    int e = t + i * 256;
    int dz = e / 80, r2 = e - dz * 80, hz = r2 >> 3, wz1 = r2 & 7;
    wb[i] = dz * 100 + hz * 10 + wz1;
  }
  int wb2[2]; float* op[2];
#pragma unroll
  for (int rep = 0; rep < 2; ++rep) {
    int o = t + rep * 256;
    int wz = o & 7, hz = (o >> 3) & 7, dz = o >> 6;
    wb2[rep] = dz * 80 + hz * 8 + wz;
    op[rep] = out + (size_t)c0 * 262144 +
              (D0 + dz) * 4096 + (H0 + hz) * 64 + (W0 + wz);
  }

  float pre[7];
  auto fetchv = [&](int ci) {
    const uint cio = (uint)(ci * 8 * VOX);
    const int cin8 = ci * 8;
#pragma unroll
    for (int k = 0; k < 7; ++k) {
      if (k < 6 || t < 192) {
        float2 mr = npv2[snidx[k] + cin8];
        float raw = vraw[soff[k] + cio];
        pre[k] = svalid[k] ? fmaxf((raw - mr.x) * mr.y, 0.f) : 0.f;
      }
    }
  };

  fetchv(0);
  for (int ci = 0; ci < 16; ++ci) {
    __syncthreads();
#pragma unroll
    for (int k = 0; k < 7; ++k)
      if (k < 6 || t < 192)
        *reinterpret_cast<float*>(vs_raw + sbyte[k]) = pre[k];
    if (ci + 1 < 16) fetchv(ci + 1);
    __syncthreads();
#pragma unroll
    for (int i = 0; i < 4; ++i) {
      int pos = t + i * 256;
      if (pos < 1000) {
        float4 va = *reinterpret_cast<const float4*>(vs_raw + vbyte[i]);
        float4 vb = *reinterpret_cast<const float4*>(vs_raw + (vbyte[i] ^ 16));
        float val = qr[i][0] * va.x;
        val = fmaf(qr[i][1], va.y, val);
        val = fmaf(qr[i][2], va.z, val);
        val = fmaf(qr[i][3], va.w, val);
        val = fmaf(qr[i][4], vb.x, val);
        val = fmaf(qr[i][5], vb.y, val);
        val = fmaf(qr[i][6], vb.z, val);
        val = fmaf(qr[i][7], vb.w, val);
        qkvs[pos] = val;
      }
    }
    __syncthreads();
#pragma unroll
    for (int i = 0; i < 4; ++i) {
      if (i < 3 || t < 32) {
        int b = wb[i];
        wsum[t + i * 256] = qkvs[b] + qkvs[b + 1] + qkvs[b + 2];
      }
    }
    __syncthreads();
#pragma unroll
    for (int rep = 0; rep < 2; ++rep) {
      float sum = 0.f;
#pragma unroll
      for (int a = 0; a < 3; ++a)
        sum += wsum[wb2[rep] + a * 80] + wsum[wb2[rep] + a * 80 + 8] +
               wsum[wb2[rep] + a * 80 + 16];
      op[rep][(size_t)ci << 18] = sum * (1.f / 27.f);
    }
  }
}

// ---------------------------------------------------------------------------
extern "C" void kernel_launch(void* const* d_in, const int* in_sizes, int n_in,
                              void* d_out, int out_size, void* d_ws, size_t ws_size,
                              hipStream_t stream)
{
  (void)in_sizes; (void)n_in; (void)out_size; (void)ws_size;
  const float* x   = (const float*)d_in[0];
  const float* q1w = (const float*)d_in[1];
  const float* q1b = (const float*)d_in[2];
  const float* q2w = (const float*)d_in[3];
  const float* q2b = (const float*)d_in[4];
  const float* k1w = (const float*)d_in[5];
  const float* k1b = (const float*)d_in[6];
  const float* k2w = (const float*)d_in[7];
  const float* k2b = (const float*)d_in[8];
  const float* vw  = (const float*)d_in[9];
  const float* vb  = (const float*)d_in[10];
  float* out = (float*)d_out;

  float* p = (float*)d_ws;
  float* vraw   = p; p += (size_t)512 * VOX;      // 64 MiB
  float* qk1raw = p; p += (size_t)32 * VOX;       // 4 MiB (q1: 0-15, k1: 16-31)
  float* qraw2  = p; p += (size_t)64 * VOX;       // 8 MiB (Wf+Wq alias)
  float* kraw2  = p; p += (size_t)8 * VOX;        // 1 MiB
  float* qkbuf  = p; p += (size_t)8 * 262144;     // 8 MiB (xT alias)
  float* part_v  = p; p += (size_t)512 * 512 * 2; // 2 MiB
  float* part_qk = p; p += (size_t)512 * 32 * 2;  // 128 KiB
  float* part_q2 = p; p += 128 * 64 * 2;
  float* part_k2 = p; p += 128 * 8 * 2;
  float* np_qk1 = p; p += 2 * 32;
  float* np_q2  = p; p += 2 * 64;
  float* np_k2  = p; p += 2 * 8;
  float* np_v   = p; p += 2 * 512;
  float* bqk    = p; p += 32;

  // aliases (dead until consumers finish): xT in qkbuf; Wf + Wq in qraw2.
  ushort* xT_hi = (ushort*)qkbuf;
  ushort* xT_lo = (ushort*)qkbuf + (size_t)32768 * 64;
  ushort* Wf_hi = (ushort*)qraw2;                        // 512 KiB
  ushort* Wf_lo = (ushort*)qraw2 + (size_t)262144;       // 512 KiB
  ushort* Wq_hi = (ushort*)qraw2 + (size_t)524288;       // 32 KiB
  ushort* Wq_lo = (ushort*)qraw2 + (size_t)540672;       // 32 KiB

  dim3 blk(256);
  wprep_kernel<<<128, blk, 0, stream>>>(vw, Wf_hi, Wf_lo);
  wprep_qk_kernel<<<8, blk, 0, stream>>>(q1w, q1b, k1w, k1b, Wq_hi, Wq_lo, bqk);
  xprep_kernel<<<512, blk, 0, stream>>>(x, xT_hi, xT_lo);
  conv_v_mfma<8, 512><<<dim3(2, 256), blk, 0, stream>>>(
      xT_hi, xT_lo, Wf_hi, Wf_lo, vb, vraw, part_v);
  conv_v_mfma<1, 32><<<dim3(1, 256), blk, 0, stream>>>(
      xT_hi, xT_lo, Wq_hi, Wq_lo, bqk, qk1raw, part_qk);
  finalize3_kernel<<<9, blk, 0, stream>>>(
      part_v, 512, 512, np_v,
      part_qk, 32, 512, np_qk1,
      nullptr, 0, 0, nullptr);

  conv_small2_kernel<16, true, 8><<<dim3(9, 128), blk, 0, stream>>>(
      qk1raw, np_qk1, q2w, q2b, qraw2, part_q2, 64,
      qk1raw + (size_t)16 * VOX, np_qk1 + 32, k2w, k2b, kraw2, part_k2, 8);
  finalize3_kernel<<<2, blk, 0, stream>>>(
      part_q2, 64, 128, np_q2,
      part_k2, 8, 128, np_k2,
      nullptr, 0, 0, nullptr);

  qk_box_kernel<<<dim3(512, 8), blk, 0, stream>>>(
      qraw2, np_q2, kraw2, np_k2, qkbuf);
  einsum_box_kernel<<<dim3(512, 4), blk, 0, stream>>>(
      vraw, np_v, qkbuf, out);
}

// Round 9
// 331.508 us; speedup vs baseline: 5.1378x; 1.0248x over previous
//
#include <hip/hip_runtime.h>
#include <hip/hip_bf16.h>

// QKV upsampling pipeline.
// R9: (a) einsum v7: c-split 2, tile-major dispatch (x=c,y=tile), vs double-
// buffered -> 2 barriers/iter with staging overlapped; (b) q2/k2 conv moved to
// MFMA (xprep2 normalizes q1/k1 -> zero-padded [vox][64] bf16, conv_v_mfma
// <3,96> with zero-padded weights); conv_small2 removed.

constexpr int VOX = 32 * 32 * 32;
constexpr float INV_VOX = 1.0f / 32768.0f;
constexpr float EPSF = 1e-5f;

typedef __attribute__((ext_vector_type(8))) short s16x8;
typedef __attribute__((ext_vector_type(4))) float f32x4;

static __device__ __forceinline__ ushort bf16_bits(float v) {
  __hip_bfloat16 h = __float2bfloat16(v);
  return *reinterpret_cast<ushort*>(&h);
}

// ---------------------------------------------------------------------------
// v-weight prepack (unchanged).
// ---------------------------------------------------------------------------
__global__ void wprep_kernel(const float* __restrict__ vw,
                             ushort* __restrict__ wh, ushort* __restrict__ wl)
{
  int tid = blockIdx.x * 256 + threadIdx.x;
  if (tid >= 32768) return;
  int oc = tid & 511;
  int g = (tid >> 9) & 3;
  int khalf = (tid >> 11) & 1;
  int tap = tid >> 12;
  uint h[4], l[4];
#pragma unroll
  for (int p = 0; p < 4; ++p) {
    int ci0 = khalf * 32 + g * 8 + 2 * p;
    float v0 = vw[oc * 512 + ci0 * 8 + tap];
    float v1 = vw[oc * 512 + (ci0 + 1) * 8 + tap];
    ushort h0 = bf16_bits(v0), h1 = bf16_bits(v1);
    float r0 = v0 - __bfloat162float(*reinterpret_cast<__hip_bfloat16*>(&h0));
    float r1 = v1 - __bfloat162float(*reinterpret_cast<__hip_bfloat16*>(&h1));
    h[p] = (uint)h0 | ((uint)h1 << 16);
    l[p] = (uint)bf16_bits(r0) | ((uint)bf16_bits(r1) << 16);
  }
  size_t base = (size_t)tid * 8;
  *reinterpret_cast<uint4*>(wh + base) = make_uint4(h[0], h[1], h[2], h[3]);
  *reinterpret_cast<uint4*>(wl + base) = make_uint4(l[0], l[1], l[2], l[3]);
}

// ---------------------------------------------------------------------------
// q1/k1 weight prepack (unchanged).
// ---------------------------------------------------------------------------
__global__ void wprep_qk_kernel(const float* __restrict__ q1w,
                                const float* __restrict__ q1b,
                                const float* __restrict__ k1w,
                                const float* __restrict__ k1b,
                                ushort* __restrict__ wh, ushort* __restrict__ wl,
                                float* __restrict__ bq)
{
  int tid = blockIdx.x * 256 + threadIdx.x;
  if (tid < 32) bq[tid] = tid < 16 ? q1b[tid] : k1b[tid - 16];
  if (tid >= 2048) return;
  int oc = tid & 31;
  int g = (tid >> 5) & 3;
  int khalf = (tid >> 7) & 1;
  int tap = tid >> 8;
  const float* src = oc < 16 ? q1w + oc * 512 : k1w + (oc - 16) * 512;
  uint h[4], l[4];
#pragma unroll
  for (int p = 0; p < 4; ++p) {
    int ci0 = khalf * 32 + g * 8 + 2 * p;
    float v0 = src[ci0 * 8 + tap];
    float v1 = src[(ci0 + 1) * 8 + tap];
    ushort h0 = bf16_bits(v0), h1 = bf16_bits(v1);
    float r0 = v0 - __bfloat162float(*reinterpret_cast<__hip_bfloat16*>(&h0));
    float r1 = v1 - __bfloat162float(*reinterpret_cast<__hip_bfloat16*>(&h1));
    h[p] = (uint)h0 | ((uint)h1 << 16);
    l[p] = (uint)bf16_bits(r0) | ((uint)bf16_bits(r1) << 16);
  }
  size_t base = (size_t)tid * 8;
  *reinterpret_cast<uint4*>(wh + base) = make_uint4(h[0], h[1], h[2], h[3]);
  *reinterpret_cast<uint4*>(wl + base) = make_uint4(l[0], l[1], l[2], l[3]);
}

// ---------------------------------------------------------------------------
// q2/k2 weight prepack: 96 padded rows (64 q2, 8 k2, 24 zero) over 64 ci
// (0-15 = q1-normalized, 16-31 = k1-normalized, 32-63 = zero). + bias96.
// ---------------------------------------------------------------------------
__global__ void wprep2_kernel(const float* __restrict__ q2w,
                              const float* __restrict__ q2b,
                              const float* __restrict__ k2w,
                              const float* __restrict__ k2b,
                              ushort* __restrict__ wh, ushort* __restrict__ wl,
                              float* __restrict__ b96)
{
  int tid = blockIdx.x * 256 + threadIdx.x;   // 6144 chunks
  if (tid < 96) b96[tid] = tid < 64 ? q2b[tid] : (tid < 72 ? k2b[tid - 64] : 0.f);
  if (tid >= 6144) return;
  int oc = tid % 96;
  int g = (tid / 96) & 3;
  int kslot = tid / 384;
  int khalf = kslot & 1, tap = kslot >> 1;
  uint h[4], l[4];
#pragma unroll
  for (int p = 0; p < 4; ++p) {
    float v[2];
#pragma unroll
    for (int q = 0; q < 2; ++q) {
      int ci = khalf * 32 + g * 8 + 2 * p + q;
      float w = 0.f;
      if (ci < 16) {
        if (oc < 64) w = q2w[(oc * 16 + ci) * 8 + tap];
      } else if (ci < 32) {
        if (oc >= 64 && oc < 72) w = k2w[((oc - 64) * 16 + (ci - 16)) * 8 + tap];
      }
      v[q] = w;
    }
    ushort h0 = bf16_bits(v[0]), h1 = bf16_bits(v[1]);
    float r0 = v[0] - __bfloat162float(*reinterpret_cast<__hip_bfloat16*>(&h0));
    float r1 = v[1] - __bfloat162float(*reinterpret_cast<__hip_bfloat16*>(&h1));
    h[p] = (uint)h0 | ((uint)h1 << 16);
    l[p] = (uint)bf16_bits(r0) | ((uint)bf16_bits(r1) << 16);
  }
  size_t base = (size_t)tid * 8;
  *reinterpret_cast<uint4*>(wh + base) = make_uint4(h[0], h[1], h[2], h[3]);
  *reinterpret_cast<uint4*>(wl + base) = make_uint4(l[0], l[1], l[2], l[3]);
}

// ---------------------------------------------------------------------------
// x transpose (unchanged).
// ---------------------------------------------------------------------------
__global__ __launch_bounds__(256) void xprep_kernel(
    const float* __restrict__ x, ushort* __restrict__ xh, ushort* __restrict__ xl)
{
  __shared__ float ts[64][65];
  const int t = threadIdx.x;
  const int vox0 = blockIdx.x * 64;
#pragma unroll
  for (int i = 0; i < 16; ++i) {
    int e = i * 256 + t;
    int ci = e >> 6, vl = e & 63;
    ts[ci][vl] = x[(size_t)ci * VOX + vox0 + vl];
  }
  __syncthreads();
  const int vl = t >> 2, cig = t & 3;
  uint h[8], l[8];
#pragma unroll
  for (int p = 0; p < 8; ++p) {
    float v0 = ts[cig * 16 + 2 * p][vl];
    float v1 = ts[cig * 16 + 2 * p + 1][vl];
    ushort h0 = bf16_bits(v0), h1 = bf16_bits(v1);
    float r0 = v0 - __bfloat162float(*reinterpret_cast<__hip_bfloat16*>(&h0));
    float r1 = v1 - __bfloat162float(*reinterpret_cast<__hip_bfloat16*>(&h1));
    h[p] = (uint)h0 | ((uint)h1 << 16);
    l[p] = (uint)bf16_bits(r0) | ((uint)bf16_bits(r1) << 16);
  }
  size_t base = (size_t)(vox0 + vl) * 64 + cig * 16;
  *reinterpret_cast<uint4*>(xh + base)     = make_uint4(h[0], h[1], h[2], h[3]);
  *reinterpret_cast<uint4*>(xh + base + 8) = make_uint4(h[4], h[5], h[6], h[7]);
  *reinterpret_cast<uint4*>(xl + base)     = make_uint4(l[0], l[1], l[2], l[3]);
  *reinterpret_cast<uint4*>(xl + base + 8) = make_uint4(l[4], l[5], l[6], l[7]);
}

// ---------------------------------------------------------------------------
// Normalize q1/k1 (32 ch) -> [vox][64] bf16 hi/lo with ci 32..63 zeroed.
// ---------------------------------------------------------------------------
__global__ __launch_bounds__(256) void xprep2_kernel(
    const float* __restrict__ qk1, const float* __restrict__ np,
    ushort* __restrict__ xh, ushort* __restrict__ xl)
{
  __shared__ float ts[32][65];
  const int t = threadIdx.x;
  const int vox0 = blockIdx.x * 64;
#pragma unroll
  for (int i = 0; i < 8; ++i) {
    int e = i * 256 + t;
    int ci = e >> 6, vl = e & 63;
    float m = np[2 * ci], rs = np[2 * ci + 1];
    float v = qk1[(size_t)ci * VOX + vox0 + vl];
    ts[ci][vl] = fmaxf((v - m) * rs, 0.f);
  }
  __syncthreads();
  const int vl = t >> 2, cig = t & 3;
  uint h[8], l[8];
#pragma unroll
  for (int p = 0; p < 8; ++p) {
    if (cig < 2) {
      float v0 = ts[cig * 16 + 2 * p][vl];
      float v1 = ts[cig * 16 + 2 * p + 1][vl];
      ushort h0 = bf16_bits(v0), h1 = bf16_bits(v1);
      float r0 = v0 - __bfloat162float(*reinterpret_cast<__hip_bfloat16*>(&h0));
      float r1 = v1 - __bfloat162float(*reinterpret_cast<__hip_bfloat16*>(&h1));
      h[p] = (uint)h0 | ((uint)h1 << 16);
      l[p] = (uint)bf16_bits(r0) | ((uint)bf16_bits(r1) << 16);
    } else { h[p] = 0u; l[p] = 0u; }
  }
  size_t base = (size_t)(vox0 + vl) * 64 + cig * 16;
  *reinterpret_cast<uint4*>(xh + base)     = make_uint4(h[0], h[1], h[2], h[3]);
  *reinterpret_cast<uint4*>(xh + base + 8) = make_uint4(h[4], h[5], h[6], h[7]);
  *reinterpret_cast<uint4*>(xl + base)     = make_uint4(l[0], l[1], l[2], l[3]);
  *reinterpret_cast<uint4*>(xl + base + 8) = make_uint4(l[4], l[5], l[6], l[7]);
}

// ---------------------------------------------------------------------------
// MFMA conv template (unchanged). NMF M-frags/wave, OCS = A row count.
// ---------------------------------------------------------------------------
template <int NMF, int OCS>
__global__ __launch_bounds__(256) void conv_v_mfma(
    const ushort* __restrict__ xh, const ushort* __restrict__ xl,
    const ushort* __restrict__ wh, const ushort* __restrict__ wl,
    const float* __restrict__ bias, float* __restrict__ y,
    float* __restrict__ part)
{
  __shared__ ushort Bs[2 * 255 * 64];

  const int t = threadIdx.x;
  const int wave = t >> 6, lane = t & 63;
  const int wm = wave >> 1, wn = wave & 1;
  const int g = lane >> 4, ww = lane & 15;
  const int m0 = blockIdx.x * (NMF * 32);
  const int nt = blockIdx.y;
  const int td = nt >> 4, th = (nt >> 1) & 7, tw = nt & 1;
  const int d0 = td * 2, h0 = th * 4, w0 = tw * 16;

  for (int i = 0; i < 16; ++i) {
    int c = i * 256 + t;
    if (c < 4080) {
      int split = (c >= 2040) ? 1 : 0;
      int c2 = c - split * 2040;
      int pos = c2 >> 3, cig = c2 & 7;
      int dz = pos / 85, rem = pos - dz * 85;
      int hz = rem / 17, wz = rem - hz * 17;
      int d = d0 + dz, h = h0 + hz, w = w0 + wz;
      uint4 val = make_uint4(0, 0, 0, 0);
      if (d < 32 && h < 32 && w < 32) {
        const ushort* src = split ? xl : xh;
        val = *reinterpret_cast<const uint4*>(
            src + (size_t)(d * 1024 + h * 32 + w) * 64 + cig * 8);
      }
      int addr = (pos << 7) + cig * 16;
      addr ^= (pos & 7) << 4;
      *reinterpret_cast<uint4*>(
          reinterpret_cast<char*>(Bs) + split * 32640 + addr) = val;
    }
  }
  __syncthreads();

  const int ocl = m0 + wm * (NMF * 16) + ww;
  f32x4 acc[NMF][4];
#pragma unroll
  for (int mf = 0; mf < NMF; ++mf)
#pragma unroll
    for (int hh = 0; hh < 4; ++hh) acc[mf][hh] = (f32x4){0.f, 0.f, 0.f, 0.f};

  for (int tap = 0; tap < 8; ++tap) {
    const int kd = tap >> 2, kh = (tap >> 1) & 1, kw = tap & 1;
#pragma unroll
    for (int khalf = 0; khalf < 2; ++khalf) {
      const size_t abase = ((size_t)((tap * 2 + khalf) * 4 + g) * OCS + ocl) * 8;
      s16x8 Ah[NMF], Al[NMF];
#pragma unroll
      for (int mf = 0; mf < NMF; ++mf) {
        Ah[mf] = *reinterpret_cast<const s16x8*>(wh + abase + mf * 16 * 8);
        Al[mf] = *reinterpret_cast<const s16x8*>(wl + abase + mf * 16 * 8);
      }
      const int srow = ((wn + kd) * 5 + kh) * 17 + kw;
#pragma unroll
      for (int hh = 0; hh < 4; ++hh) {
        int pos = srow + hh * 17 + ww;
        int baddr = (pos << 7) + khalf * 64 + g * 16;
        baddr ^= (pos & 7) << 4;
        const char* bp = reinterpret_cast<const char*>(Bs) + baddr;
        s16x8 Bh = *reinterpret_cast<const s16x8*>(bp);
        s16x8 Bl = *reinterpret_cast<const s16x8*>(bp + 32640);
#pragma unroll
        for (int mf = 0; mf < NMF; ++mf) {
          acc[mf][hh] = __builtin_amdgcn_mfma_f32_16x16x32_bf16(
              Ah[mf], Bh, acc[mf][hh], 0, 0, 0);
          acc[mf][hh] = __builtin_amdgcn_mfma_f32_16x16x32_bf16(
              Al[mf], Bh, acc[mf][hh], 0, 0, 0);
          acc[mf][hh] = __builtin_amdgcn_mfma_f32_16x16x32_bf16(
              Ah[mf], Bl, acc[mf][hh], 0, 0, 0);
        }
      }
    }
  }

  float bs[NMF][4];
#pragma unroll
  for (int mf = 0; mf < NMF; ++mf)
#pragma unroll
    for (int reg = 0; reg < 4; ++reg)
      bs[mf][reg] = bias[m0 + wm * (NMF * 16) + mf * 16 + g * 4 + reg];

  float ssum[NMF][4], ssq[NMF][4];
#pragma unroll
  for (int mf = 0; mf < NMF; ++mf)
#pragma unroll
    for (int reg = 0; reg < 4; ++reg) { ssum[mf][reg] = 0.f; ssq[mf][reg] = 0.f; }

#pragma unroll
  for (int mf = 0; mf < NMF; ++mf) {
#pragma unroll
    for (int hh = 0; hh < 4; ++hh) {
      int vox = (d0 + wn) * 1024 + (h0 + hh) * 32 + w0 + ww;
#pragma unroll
      for (int reg = 0; reg < 4; ++reg) {
        float v = acc[mf][hh][reg] + bs[mf][reg];
        int oc = m0 + wm * (NMF * 16) + mf * 16 + g * 4 + reg;
        y[(size_t)oc * VOX + vox] = v;
        ssum[mf][reg] += v;
        ssq[mf][reg] += v * v;
      }
    }
  }
#pragma unroll
  for (int mf = 0; mf < NMF; ++mf)
#pragma unroll
    for (int reg = 0; reg < 4; ++reg)
#pragma unroll
      for (int off = 1; off < 16; off <<= 1) {
        ssum[mf][reg] += __shfl_xor(ssum[mf][reg], off);
        ssq[mf][reg]  += __shfl_xor(ssq[mf][reg], off);
      }
  if ((lane & 15) == 0) {
    float* pp = part + (size_t)(nt * 2 + wn) * (OCS * 2);
#pragma unroll
    for (int mf = 0; mf < NMF; ++mf)
#pragma unroll
      for (int reg = 0; reg < 4; ++reg) {
        int oc = m0 + wm * (NMF * 16) + mf * 16 + g * 4 + reg;
        pp[oc * 2]     = ssum[mf][reg];
        pp[oc * 2 + 1] = ssq[mf][reg];
      }
  }
}

// ---------------------------------------------------------------------------
// Combined finalize (3 sets), 256 threads, 4-way split + float2.
// ---------------------------------------------------------------------------
__global__ __launch_bounds__(256) void finalize3_kernel(
    const float* __restrict__ p1, int C1, int NT1, float* __restrict__ n1,
    const float* __restrict__ p2, int C2, int NT2, float* __restrict__ n2,
    const float* __restrict__ p3, int C3, int NT3, float* __restrict__ n3)
{
  __shared__ float red[4][64][2];
  const int t = threadIdx.x;
  const int qq = t >> 6, cl = t & 63;
  const int g = blockIdx.x * 64 + cl;

  const float* part = nullptr; float* np = nullptr; int C = 0, NT = 0, c = 0;
  if (g < C1)                { part = p1; np = n1; C = C1; NT = NT1; c = g; }
  else if (g < C1 + C2)      { part = p2; np = n2; C = C2; NT = NT2; c = g - C1; }
  else if (g < C1 + C2 + C3) { part = p3; np = n3; C = C3; NT = NT3; c = g - C1 - C2; }

  float s = 0.f, ss = 0.f;
  if (part)
    for (int tile = qq; tile < NT; tile += 4) {
      float2 v = *reinterpret_cast<const float2*>(&part[((size_t)tile * C + c) * 2]);
      s += v.x; ss += v.y;
    }
  red[qq][cl][0] = s; red[qq][cl][1] = ss;
  __syncthreads();
  if (qq == 0 && part) {
    s  = red[0][cl][0] + red[1][cl][0] + red[2][cl][0] + red[3][cl][0];
    ss = red[0][cl][1] + red[1][cl][1] + red[2][cl][1] + red[3][cl][1];
    float m = s * INV_VOX;
    float var = ss * INV_VOX - m * m;
    np[2 * c]     = m;
    np[2 * c + 1] = rsqrtf(var + EPSF);
  }
}

// ---------------------------------------------------------------------------
// qk_box v2 (unchanged).
// ---------------------------------------------------------------------------
__global__ __launch_bounds__(256) void qk_box_kernel(
    const float* __restrict__ qraw, const float* __restrict__ npq,
    const float* __restrict__ kraw, const float* __restrict__ npk,
    float* __restrict__ qkout)
{
  __shared__ float s[1000];
  __shared__ float ws2[800];
  const int j = blockIdx.y;
  const int tile = blockIdx.x;
  const int W0 = (tile & 7) * 8, H0 = ((tile >> 3) & 7) * 8, D0 = (tile >> 6) * 8;
  const int t = threadIdx.x;
  const int cbD = (D0 >> 1) - 1, cbH = (H0 >> 1) - 1, cbW = (W0 >> 1) - 1;
  const float2* npq2 = reinterpret_cast<const float2*>(npq);
  const float2* npk2 = reinterpret_cast<const float2*>(npk);

#pragma unroll
  for (int kk = 0; kk < 7; ++kk) {
    int f = t + kk * 256;
    if (f < 1728) {
      int par = f / 216, idx = f - par * 216;
      int dz = idx / 36, r2 = idx - dz * 36, hz = r2 / 6, wz = r2 - hz * 6;
      int pd = (par >> 2) & 1, ph = (par >> 1) & 1, pw = par & 1;
      int dzf = 2 * dz + pd - 1, hzf = 2 * hz + ph - 1, wzf = 2 * wz + pw - 1;
      if ((unsigned)dzf < 10u && (unsigned)hzf < 10u && (unsigned)wzf < 10u) {
        int cD = cbD + dz, cH = cbH + hz, cW = cbW + wz;
        float prod = 0.f;
        if ((unsigned)cD < 32u && (unsigned)cH < 32u && (unsigned)cW < 32u) {
          int cidx = cD * 1024 + cH * 32 + cW;
          int qc = j * 8 + par;
          float2 nq = npq2[qc];
          float2 nk = npk2[par];
          float qv = fmaxf((qraw[(size_t)qc * VOX + cidx] - nq.x) * nq.y, 0.f);
          float kv = fmaxf((kraw[(size_t)par * VOX + cidx] - nk.x) * nk.y, 0.f);
          prod = qv * kv;
        }
        s[dzf * 100 + hzf * 10 + wzf] = prod;
      }
    }
  }
  __syncthreads();
#pragma unroll
  for (int i = 0; i < 4; ++i) {
    int e = t + i * 256;
    if (e < 800) {
      int dz = e / 80, r2 = e - dz * 80, hz = r2 >> 3, wz1 = r2 & 7;
      int base = dz * 100 + hz * 10 + wz1;
      ws2[e] = s[base] + s[base + 1] + s[base + 2];
    }
  }
  __syncthreads();
#pragma unroll
  for (int rep = 0; rep < 2; ++rep) {
    int o = t + rep * 256;
    int wz = o & 7, hz = (o >> 3) & 7, dz = o >> 6;
    int wb = dz * 80 + hz * 8 + wz;
    float sum = 0.f;
#pragma unroll
    for (int a = 0; a < 3; ++a)
      sum += ws2[wb + a * 80] + ws2[wb + a * 80 + 8] + ws2[wb + a * 80 + 16];
    qkout[(size_t)j * 262144 + (D0 + dz) * 4096 + (H0 + hz) * 64 + (W0 + wz)] =
        sum * (1.f / 27.f);
  }
}

// ---------------------------------------------------------------------------
// einsum_box v7: c-split 2, tile-major grid (x=c-half, y=tile), vs double-
// buffered -> 2 barriers/iter, staging overlapped with compute.
// ---------------------------------------------------------------------------
__global__ __launch_bounds__(256) void einsum_box_kernel(
    const float* __restrict__ vraw, const float* __restrict__ npv,
    const float* __restrict__ qk, float* __restrict__ out)
{
  __shared__ char vs_raw[2][6912];
  __shared__ float qkvs[1000];
  __shared__ float wsum[800];

  const int c0 = blockIdx.x * 32;
  const int tile = blockIdx.y;
  const int W0 = (tile & 7) * 8, H0 = ((tile >> 3) & 7) * 8, D0 = (tile >> 6) * 8;
  const int t = threadIdx.x;
  const int cbD = (D0 >> 1) - 1, cbH = (H0 >> 1) - 1, cbW = (W0 >> 1) - 1;
  const float2* npv2 = reinterpret_cast<const float2*>(npv);

  // stage-slot precompute
  uint soff[7]; int sbyte[7]; int snidx[7]; bool svalid[7];
#pragma unroll
  for (int k = 0; k < 7; ++k) {
    int f = t + k * 256;
    int j = f / 216, idx = f - j * 216;
    int dz = idx / 36, r2 = idx - dz * 36, hz = r2 / 6, wz = r2 - hz * 6;
    int cD = cbD + dz, cH = cbH + hz, cW = cbW + wz;
    bool vld = (f < 1728) && (unsigned)cD < 32u && (unsigned)cH < 32u &&
               (unsigned)cW < 32u;
    svalid[k] = vld;
    soff[k] = vld ? (uint)((c0 * 8 + j) * VOX + cD * 1024 + cH * 32 + cW) : 0u;
    snidx[k] = (f < 1728) ? (c0 * 8 + j) : 0;
    int byte = idx * 32 + (j >> 2) * 16 + (j & 3) * 4;
    sbyte[k] = byte ^ (((idx >> 2) & 7) << 4);
  }

  // qkv-slot precompute + qk -> registers
  int vbyte[4]; float qr[4][8];
#pragma unroll
  for (int i = 0; i < 4; ++i) {
    int pos = t + i * 256;
    vbyte[i] = 0;
#pragma unroll
    for (int j = 0; j < 8; ++j) qr[i][j] = 0.f;
    if (pos < 1000) {
      int dz = pos / 100, rem = pos - dz * 100, hz = rem / 10, wz = rem - hz * 10;
      int D = D0 - 1 + dz, H = H0 - 1 + hz, W = W0 - 1 + wz;
      if ((unsigned)D < 64u && (unsigned)H < 64u && (unsigned)W < 64u) {
        int fidx = D * 4096 + H * 64 + W;
#pragma unroll
        for (int j = 0; j < 8; ++j)
          qr[i][j] = qk[(size_t)j * 262144 + fidx];
        int vidx = ((D >> 1) - cbD) * 36 + ((H >> 1) - cbH) * 6 + ((W >> 1) - cbW);
        vbyte[i] = (vidx * 32) ^ (((vidx >> 2) & 7) << 4);
      }
    }
  }

  int wb[4];
#pragma unroll
  for (int i = 0; i < 4; ++i) {
    int e = t + i * 256;
    int dz = e / 80, r2 = e - dz * 80, hz = r2 >> 3, wz1 = r2 & 7;
    wb[i] = dz * 100 + hz * 10 + wz1;
  }
  int wb2[2]; float* op[2];
#pragma unroll
  for (int rep = 0; rep < 2; ++rep) {
    int o = t + rep * 256;
    int wz = o & 7, hz = (o >> 3) & 7, dz = o >> 6;
    wb2[rep] = dz * 80 + hz * 8 + wz;
    op[rep] = out + (size_t)c0 * 262144 +
              (D0 + dz) * 4096 + (H0 + hz) * 64 + (W0 + wz);
  }

  float pre[7];
  auto fetchv = [&](int ci) {
    const uint cio = (uint)(ci * 8 * VOX);
    const int cin8 = ci * 8;
#pragma unroll
    for (int k = 0; k < 7; ++k) {
      if (k < 6 || t < 192) {
        float2 mr = npv2[snidx[k] + cin8];
        float raw = vraw[soff[k] + cio];
        pre[k] = svalid[k] ? fmaxf((raw - mr.x) * mr.y, 0.f) : 0.f;
      }
    }
  };

  // prologue: fill buf0, prefetch ci=1
  fetchv(0);
#pragma unroll
  for (int k = 0; k < 7; ++k)
    if (k < 6 || t < 192)
      *reinterpret_cast<float*>(vs_raw[0] + sbyte[k]) = pre[k];
  fetchv(1);
  __syncthreads();

  for (int ci = 0; ci < 32; ++ci) {
    const int cbuf = ci & 1;
    // A: stage next buffer (overlaps with B/C/D compute below)
    if (ci < 31) {
#pragma unroll
      for (int k = 0; k < 7; ++k)
        if (k < 6 || t < 192)
          *reinterpret_cast<float*>(vs_raw[cbuf ^ 1] + sbyte[k]) = pre[k];
      if (ci < 30) fetchv(ci + 2);
    }
    // B: qkv halo from vs[cbuf]
#pragma unroll
    for (int i = 0; i < 4; ++i) {
      int pos = t + i * 256;
      if (pos < 1000) {
        const char* vb0 = vs_raw[cbuf];
        float4 va = *reinterpret_cast<const float4*>(vb0 + vbyte[i]);
        float4 vb = *reinterpret_cast<const float4*>(vb0 + (vbyte[i] ^ 16));
        float val = qr[i][0] * va.x;
        val = fmaf(qr[i][1], va.y, val);
        val = fmaf(qr[i][2], va.z, val);
        val = fmaf(qr[i][3], va.w, val);
        val = fmaf(qr[i][4], vb.x, val);
        val = fmaf(qr[i][5], vb.y, val);
        val = fmaf(qr[i][6], vb.z, val);
        val = fmaf(qr[i][7], vb.w, val);
        qkvs[pos] = val;
      }
    }
    __syncthreads();   // barrier 1: qkvs ready; vs[cbuf^1] writes complete
    // C: W-pass
#pragma unroll
    for (int i = 0; i < 4; ++i) {
      if (i < 3 || t < 32) {
        int b = wb[i];
        wsum[t + i * 256] = qkvs[b] + qkvs[b + 1] + qkvs[b + 2];
      }
    }
    __syncthreads();   // barrier 2: wsum ready
    // D: H+D gather + store
#pragma unroll
    for (int rep = 0; rep < 2; ++rep) {
      float sum = 0.f;
#pragma unroll
      for (int a = 0; a < 3; ++a)
        sum += wsum[wb2[rep] + a * 80] + wsum[wb2[rep] + a * 80 + 8] +
               wsum[wb2[rep] + a * 80 + 16];
      op[rep][(size_t)ci << 18] = sum * (1.f / 27.f);
    }
  }
}

// ---------------------------------------------------------------------------
extern "C" void kernel_launch(void* const* d_in, const int* in_sizes, int n_in,
                              void* d_out, int out_size, void* d_ws, size_t ws_size,
                              hipStream_t stream)
{
  (void)in_sizes; (void)n_in; (void)out_size; (void)ws_size;
  const float* x   = (const float*)d_in[0];
  const float* q1w = (const float*)d_in[1];
  const float* q1b = (const float*)d_in[2];
  const float* q2w = (const float*)d_in[3];
  const float* q2b = (const float*)d_in[4];
  const float* k1w = (const float*)d_in[5];
  const float* k1b = (const float*)d_in[6];
  const float* k2w = (const float*)d_in[7];
  const float* k2b = (const float*)d_in[8];
  const float* vw  = (const float*)d_in[9];
  const float* vb  = (const float*)d_in[10];
  float* out = (float*)d_out;

  float* p = (float*)d_ws;
  float* vraw    = p; p += (size_t)512 * VOX;      // 64 MiB
  float* regionR = p; p += (size_t)96 * VOX;       // 12 MiB: qk1raw then y96
  float* qkbuf   = p; p += (size_t)8 * 262144;     // 8 MiB: xT, then xT2, then qk
  float* part_v  = p; p += (size_t)512 * 512 * 2;  // 2 MiB
  float* part_qk = p; p += (size_t)512 * 32 * 2;   // 128 KiB
  float* part96  = p; p += (size_t)512 * 96 * 2;   // 384 KiB
  float* WfF     = p; p += (size_t)262144;         // 1 MiB (hi+lo ushorts)
  float* WqF     = p; p += (size_t)16384;          // 64 KiB
  float* W2F     = p; p += (size_t)49152;          // 192 KiB
  float* np_qk1  = p; p += 64;
  float* np96    = p; p += 192;
  float* np_v    = p; p += 1024;
  float* bqk     = p; p += 32;
  float* b96     = p; p += 96;

  float* qk1raw = regionR;                     // 32 ch, live until xprep2
  float* y96    = regionR;                     // 96 ch, live after conv96

  ushort* xT_hi = (ushort*)qkbuf;
  ushort* xT_lo = (ushort*)qkbuf + (size_t)32768 * 64;
  ushort* Wf_hi = (ushort*)WfF;
  ushort* Wf_lo = (ushort*)WfF + 262144;
  ushort* Wq_hi = (ushort*)WqF;
  ushort* Wq_lo = (ushort*)WqF + 16384;
  ushort* W2_hi = (ushort*)W2F;
  ushort* W2_lo = (ushort*)W2F + 49152;

  dim3 blk(256);
  wprep_kernel<<<128, blk, 0, stream>>>(vw, Wf_hi, Wf_lo);
  wprep_qk_kernel<<<8, blk, 0, stream>>>(q1w, q1b, k1w, k1b, Wq_hi, Wq_lo, bqk);
  wprep2_kernel<<<24, blk, 0, stream>>>(q2w, q2b, k2w, k2b, W2_hi, W2_lo, b96);
  xprep_kernel<<<512, blk, 0, stream>>>(x, xT_hi, xT_lo);
  conv_v_mfma<8, 512><<<dim3(2, 256), blk, 0, stream>>>(
      xT_hi, xT_lo, Wf_hi, Wf_lo, vb, vraw, part_v);
  conv_v_mfma<1, 32><<<dim3(1, 256), blk, 0, stream>>>(
      xT_hi, xT_lo, Wq_hi, Wq_lo, bqk, qk1raw, part_qk);
  finalize3_kernel<<<9, blk, 0, stream>>>(
      part_v, 512, 512, np_v,
      part_qk, 32, 512, np_qk1,
      nullptr, 0, 0, nullptr);
  // xT dead now -> reuse qkbuf for normalized qk1 operand
  xprep2_kernel<<<512, blk, 0, stream>>>(qk1raw, np_qk1, xT_hi, xT_lo);
  // qk1raw dead now -> y96 overlays regionR
  conv_v_mfma<3, 96><<<dim3(1, 256), blk, 0, stream>>>(
      xT_hi, xT_lo, W2_hi, W2_lo, b96, y96, part96);
  finalize3_kernel<<<2, blk, 0, stream>>>(
      part96, 96, 512, np96,
      nullptr, 0, 0, nullptr,
      nullptr, 0, 0, nullptr);
  // xT2 dead now -> qkbuf holds qk
  qk_box_kernel<<<dim3(512, 8), blk, 0, stream>>>(
      y96, np96, y96 + (size_t)64 * VOX, np96 + 128, qkbuf);
  einsum_box_kernel<<<dim3(2, 512), blk, 0, stream>>>(
      vraw, np_v, qkbuf, out);
}